// Round 1
// baseline (3679.927 us; speedup 1.0000x reference)
//
#include <hip/hip_runtime.h>

// TrajectoryAttention on MI355X (gfx950), chunked pipeline, dtype-adaptive.
// R9: landmarks path parallelized across CUs:
//   landmarksMB_k: 8 blocks per head (192 blocks, all co-resident on 256 CUs),
//   per-head global-memory barrier per greedy step (monotonic counter,
//   release-fetch-add / acquire-spin, agent-scope atomics for cross-XCD
//   coherence, double-buffered candidate slots). Each block keeps its 392 rows'
//   max_sim in registers; winner column re-read from read-only qT by all blocks
//   -> ONE barrier/step. Was: 1 block/head = single-CU L2-BW-bound, 9 us/step.
// R8 (kept): qselT_k f32 GEMM -> transposed qT[bh][d][n]; coalesced reads.
// R7 (kept): partitionable threefry idx0; bf16 MFMA smooth path; chunked k2/v2.

using u16 = unsigned short;
using u32 = unsigned int;
using u64 = unsigned long long;

typedef short bf16x8 __attribute__((ext_vector_type(8)));
typedef float f32x4 __attribute__((ext_vector_type(4)));

#define N_ 3136
#define C_ 768
#define H_ 12
#define F_ 16
#define P_ 196
#define L_ 128
#define SC_ 0.35355339059327373f   // 64^-0.25
#define OUTPART_ ((size_t)2 * N_ * C_)
#define KB_ 8                      // blocks per head in landmarks
#define RPB_ 392                   // rows per block (3136/8)

__device__ __forceinline__ float b2f(u16 u) {
  u32 x = ((u32)u) << 16; float f; __builtin_memcpy(&f, &x, 4); return f;
}
__device__ __forceinline__ float lo16f(u32 u) {
  u32 x = u << 16; float f; __builtin_memcpy(&f, &x, 4); return f;
}
__device__ __forceinline__ float hi16f(u32 u) {
  u32 x = u & 0xFFFF0000u; float f; __builtin_memcpy(&f, &x, 4); return f;
}
__device__ __forceinline__ u16 f2b(float f) {
  u32 u; __builtin_memcpy(&u, &f, 4);
  u32 r = (u + 0x7FFFu + ((u >> 16) & 1u)) >> 16;
  return (u16)r;
}
__device__ __forceinline__ u64 d2u(double d) { u64 u; __builtin_memcpy(&u, &d, 8); return u; }
__device__ __forceinline__ double u2d(u64 u) { double d; __builtin_memcpy(&d, &u, 8); return d; }

// load 16 contiguous logical elements as bf16 uint4 pair, from raw input of either dtype
__device__ __forceinline__ void ld16bf(const void* base, size_t elemOff, int isF32,
                                       uint4& o0, uint4& o1) {
  if (isF32) {
    const float4* p = (const float4*)((const float*)base + elemOff);
    float4 f0 = p[0], f1 = p[1], f2v = p[2], f3 = p[3];
    u16 tmp[16] = { f2b(f0.x), f2b(f0.y), f2b(f0.z), f2b(f0.w),
                    f2b(f1.x), f2b(f1.y), f2b(f1.z), f2b(f1.w),
                    f2b(f2v.x), f2b(f2v.y), f2b(f2v.z), f2b(f2v.w),
                    f2b(f3.x), f2b(f3.y), f2b(f3.z), f2b(f3.w) };
    __builtin_memcpy(&o0, tmp, 16);
    __builtin_memcpy(&o1, tmp + 8, 16);
  } else {
    const uint4* p = (const uint4*)((const u16*)base + elemOff);
    o0 = p[0]; o1 = p[1];
  }
}

// dtype sniffer (bf16 vs f32 inputs) — votes f32 on this dataset (proven R4)
__global__ void detect_k(const u32* __restrict__ w, int* __restrict__ flag) {
  const int t = threadIdx.x;  // 64
  int hits = 0;
  #pragma unroll
  for (int i = 0; i < 16; ++i) {
    u32 word = w[t * 16 + i];
    u32 e = (word >> 7) & 0xFFu;
    if (e >= 110u && e <= 126u) hits++;
  }
  #pragma unroll
  for (int off = 32; off > 0; off >>= 1) hits += __shfl_down(hits, off);
  if (t == 0) flag[0] = (hits >= 512) ? 0 : 1;  // 0=bf16, 1=f32
}

// zero per-head barrier counters (re-run every launch: graph-replay safe)
__global__ void zcnt_k(int* __restrict__ p) { if (threadIdx.x < 24) p[threadIdx.x] = 0; }

// ---- exact JAX threefry2x32-20 core ----
__device__ __forceinline__ void tf2(u32 k0, u32 k1v, u32 c0, u32 c1, u32& o0, u32& o1) {
  u32 ks[3] = {k0, k1v, k0 ^ k1v ^ 0x1BD11BDAu};
  u32 x0 = c0 + ks[0], x1 = c1 + ks[1];
  const u32 rA[4] = {13u, 15u, 26u, 6u}, rB[4] = {17u, 29u, 16u, 24u};
  #pragma unroll
  for (int r = 0; r < 5; ++r) {
    #pragma unroll
    for (int q = 0; q < 4; ++q) {
      u32 rot = (r & 1) ? rB[q] : rA[q];
      x0 += x1; x1 = (x1 << rot) | (x1 >> (32u - rot)); x1 ^= x0;
    }
    x0 += ks[(r + 1) % 3];
    x1 += ks[(r + 2) % 3] + (u32)(r + 1);
  }
  o0 = x0; o1 = x1;
}

// jax.random.randint(key(42), (24,), 0, 3136) under jax_threefry_partitionable=True
// — PROVEN correct on this dataset (R7 passed at smooth-path floor).
__device__ __forceinline__ int tf_idx0(int bh) {
  u32 a0, a1, b0, b1;
  tf2(0u, 42u, 0u, 0u, a0, a1);   // k1 = subkey 0
  tf2(0u, 42u, 0u, 1u, b0, b1);   // k2 = subkey 1
  u32 j = (u32)bh;
  u32 h0, h1, l0, l1;
  tf2(a0, a1, 0u, j, h0, h1);     // higher_bits[j]
  u32 hi = h0 ^ h1;
  tf2(b0, b1, 0u, j, l0, l1);     // lower_bits[j]
  u32 lo = l0 ^ l1;
  return (int)(((hi % 3136u) * 2048u + (lo % 3136u)) % 3136u);
}

// ---------------- selection-grade f32 GEMM -> TRANSPOSED qT[bh][d][n] ----------------
__global__ __launch_bounds__(256) void qselT_k(const void* __restrict__ xr, const void* __restrict__ wr,
                                               const int* __restrict__ flagp, float* __restrict__ qt)
{
  __shared__ float As[64 * 20];
  __shared__ float Bs[16 * 64];
  const int t = threadIdx.x;
  const int m0 = blockIdx.x * 64;
  const int n0 = blockIdx.y * 64;
  const int f32i = flagp[0];
  const int tx = t & 15, ty = t >> 4;
  float acc[4][4];
  #pragma unroll
  for (int i = 0; i < 4; ++i)
    #pragma unroll
    for (int j = 0; j < 4; ++j) acc[i][j] = 0.f;

  const int alr = t >> 2;               // A tile row (0..63)
  const int alk = (t & 3) * 4;          // A k offset
  const int bkr = t >> 4;               // B k row (0..15)
  const int bnc = (t & 15) * 4;         // B col offset

  for (int k0 = 0; k0 < 768; k0 += 16) {
    float4 av, bv;
    if (f32i) {
      av = *(const float4*)((const float*)xr + (size_t)(m0 + alr) * 768 + k0 + alk);
      bv = *(const float4*)((const float*)wr + (size_t)(k0 + bkr) * 2304 + n0 + bnc);
    } else {
      const u16* xa = (const u16*)xr + (size_t)(m0 + alr) * 768 + k0 + alk;
      const u16* wa = (const u16*)wr + (size_t)(k0 + bkr) * 2304 + n0 + bnc;
      av.x = b2f(xa[0]); av.y = b2f(xa[1]); av.z = b2f(xa[2]); av.w = b2f(xa[3]);
      bv.x = b2f(wa[0]); bv.y = b2f(wa[1]); bv.z = b2f(wa[2]); bv.w = b2f(wa[3]);
    }
    As[alr * 20 + alk + 0] = av.x; As[alr * 20 + alk + 1] = av.y;
    As[alr * 20 + alk + 2] = av.z; As[alr * 20 + alk + 3] = av.w;
    *(float4*)(&Bs[bkr * 64 + bnc]) = bv;
    __syncthreads();
    #pragma unroll
    for (int kk = 0; kk < 16; ++kk) {
      float a[4], b[4];
      #pragma unroll
      for (int i = 0; i < 4; ++i) a[i] = As[(ty * 4 + i) * 20 + kk];
      #pragma unroll
      for (int j = 0; j < 4; ++j) b[j] = Bs[kk * 64 + tx * 4 + j];
      #pragma unroll
      for (int i = 0; i < 4; ++i)
        #pragma unroll
        for (int j = 0; j < 4; ++j) acc[i][j] += a[i] * b[j];
    }
    __syncthreads();
  }
  #pragma unroll
  for (int i = 0; i < 4; ++i) {
    const int m = m0 + ty * 4 + i;
    const int b = m / N_, n = m - b * N_;
    #pragma unroll
    for (int j = 0; j < 4; ++j) {
      const int col = n0 + tx * 4 + j;
      const int hh = col >> 6, dd = col & 63;
      qt[((size_t)(b * H_ + hh) * 64 + dd) * N_ + n] = acc[i][j] * SC_;
    }
  }
}

// ---------------- greedy landmarks: 8 blocks/head, per-step global barrier ----------------
// Block kb owns rows [kb*392, kb*392+392). Thread t<392: row r0+t, accumulates its
// d-chunk (dc=t&3 -> d in [16dc,16dc+16)) over its quad's 4 columns, quad-butterfly
// combines -> full f64 dot per owned row. max_sim lives in a register. One global
// barrier per step (monotonic counter, release/acquire agent-scope); candidates
// double-buffered by step parity to avoid race-around. All blocks redundantly pick
// the winner and re-read its column from read-only qT (+ precomputed invNorm).
__global__ __launch_bounds__(512, 1) void landmarksMB_k(
    const float* __restrict__ qt, float* __restrict__ lm,
    u64* __restrict__ invN, u64* __restrict__ candV, int* __restrict__ candI,
    int* __restrict__ cnt)
{
  const int kb = blockIdx.x;
  const int bh = blockIdx.y;
  const float* QT = qt + (size_t)bh * 64 * N_;   // [d][n]
  float* LM = lm + (size_t)bh * L_ * 64;
  u64* iN = invN + (size_t)bh * N_;
  u64* cVb = candV + (size_t)bh * 2 * KB_;
  int* cIb = candI + (size_t)bh * 2 * KB_;
  __shared__ double curD[64];
  __shared__ u64 redV[8];
  __shared__ int redI[8];
  __shared__ int sW;
  const int t = threadIdx.x;
  const bool act = (t < RPB_);                   // 392 active (quad-aligned)
  const int g = t >> 2, dc = t & 3, d0 = dc * 16;
  const int r0 = kb * RPB_;
  const int myRow = r0 + t;                      // owned row (act only)
  const float* base = QT + r0 + 4 * g;

  // norms (f64 from f32 data): quad-split over d, butterfly combine
  double inv_own = 0.0, ms_own = 0.0;
  if (act) {
    double s0 = 0.0, s1 = 0.0, s2 = 0.0, s3 = 0.0;
    #pragma unroll
    for (int i = 0; i < 16; ++i) {
      float4 v = *(const float4*)(base + (size_t)(d0 + i) * N_);
      s0 += (double)v.x * (double)v.x; s1 += (double)v.y * (double)v.y;
      s2 += (double)v.z * (double)v.z; s3 += (double)v.w * (double)v.w;
    }
    s0 += __shfl_xor(s0, 1); s1 += __shfl_xor(s1, 1);
    s2 += __shfl_xor(s2, 1); s3 += __shfl_xor(s3, 1);
    s0 += __shfl_xor(s0, 2); s1 += __shfl_xor(s1, 2);
    s2 += __shfl_xor(s2, 2); s3 += __shfl_xor(s3, 2);
    const double sown = (dc == 0) ? s0 : (dc == 1) ? s1 : (dc == 2) ? s2 : s3;
    inv_own = 1.0 / fmax(sqrt(sown), 1e-12);
    __hip_atomic_store(&iN[myRow], d2u(inv_own), __ATOMIC_RELAXED, __HIP_MEMORY_SCOPE_AGENT);
  }
  const int idx0 = tf_idx0(bh);
  if (act && myRow == idx0) ms_own = 10.0;

  // phase-0 barrier: invN visible everywhere
  __syncthreads();
  if (t == 0) {
    __hip_atomic_fetch_add(cnt + bh, 1, __ATOMIC_RELEASE, __HIP_MEMORY_SCOPE_AGENT);
    while (__hip_atomic_load(cnt + bh, __ATOMIC_ACQUIRE, __HIP_MEMORY_SCOPE_AGENT) < KB_)
      __builtin_amdgcn_s_sleep(1);
  }
  __syncthreads();
  if (t < 64) {
    const float vf = QT[(size_t)t * N_ + idx0];
    const double invW = u2d(__hip_atomic_load(&iN[idx0], __ATOMIC_RELAXED, __HIP_MEMORY_SCOPE_AGENT));
    curD[t] = (double)vf * invW;
    if (kb == 0) LM[t] = vf;
  }
  __syncthreads();

  for (int step = 1; step < 128; ++step) {
    u64 bV = d2u(1e30); int bI = 0x7fffffff;
    if (act) {
      double a0 = 0.0, a1 = 0.0, a2 = 0.0, a3 = 0.0;
      #pragma unroll
      for (int i = 0; i < 16; ++i) {
        float4 v = *(const float4*)(base + (size_t)(d0 + i) * N_);
        const double c = curD[d0 + i];
        a0 += (double)v.x * c; a1 += (double)v.y * c;
        a2 += (double)v.z * c; a3 += (double)v.w * c;
      }
      a0 += __shfl_xor(a0, 1); a1 += __shfl_xor(a1, 1);
      a2 += __shfl_xor(a2, 1); a3 += __shfl_xor(a3, 1);
      a0 += __shfl_xor(a0, 2); a1 += __shfl_xor(a1, 2);
      a2 += __shfl_xor(a2, 2); a3 += __shfl_xor(a3, 2);
      const double aown = (dc == 0) ? a0 : (dc == 1) ? a1 : (dc == 2) ? a2 : a3;
      ms_own = fmax(ms_own, fabs(aown * inv_own));
      bV = d2u(ms_own); bI = myRow;   // nonneg doubles: bit order == numeric order
    }
    // wave argmin (val, then lowest idx)
    #pragma unroll
    for (int off = 32; off; off >>= 1) {
      const u64 ov = __shfl_xor(bV, off);
      const int oi = __shfl_xor(bI, off);
      if (ov < bV || (ov == bV && oi < bI)) { bV = ov; bI = oi; }
    }
    if ((t & 63) == 0) { redV[t >> 6] = bV; redI[t >> 6] = bI; }
    __syncthreads();
    const int par = step & 1;
    if (t == 0) {
      u64 v = redV[0]; int ix = redI[0];
      #pragma unroll
      for (int w2 = 1; w2 < 8; ++w2)
        if (redV[w2] < v || (redV[w2] == v && redI[w2] < ix)) { v = redV[w2]; ix = redI[w2]; }
      __hip_atomic_store(&cVb[par * KB_ + kb], v, __ATOMIC_RELAXED, __HIP_MEMORY_SCOPE_AGENT);
      __hip_atomic_store(&cIb[par * KB_ + kb], ix, __ATOMIC_RELAXED, __HIP_MEMORY_SCOPE_AGENT);
      __hip_atomic_fetch_add(cnt + bh, 1, __ATOMIC_RELEASE, __HIP_MEMORY_SCOPE_AGENT);
      const int target = KB_ * (step + 1);
      while (__hip_atomic_load(cnt + bh, __ATOMIC_ACQUIRE, __HIP_MEMORY_SCOPE_AGENT) < target)
        __builtin_amdgcn_s_sleep(1);
    }
    __syncthreads();
    if (t < KB_) {
      u64 qv = __hip_atomic_load(&cVb[par * KB_ + t], __ATOMIC_RELAXED, __HIP_MEMORY_SCOPE_AGENT);
      int qi = __hip_atomic_load(&cIb[par * KB_ + t], __ATOMIC_RELAXED, __HIP_MEMORY_SCOPE_AGENT);
      #pragma unroll
      for (int off = 1; off < KB_; off <<= 1) {
        const u64 ov = __shfl_xor(qv, off);
        const int oi = __shfl_xor(qi, off);
        if (ov < qv || (ov == qv && oi < qi)) { qv = ov; qi = oi; }
      }
      if (t == 0) sW = qi;
    }
    __syncthreads();
    const int w = sW;
    if (act && myRow == w) ms_own = 10.0;
    if (t < 64) {
      const float vf = QT[(size_t)t * N_ + w];
      const double invW = u2d(__hip_atomic_load(&iN[w], __ATOMIC_RELAXED, __HIP_MEMORY_SCOPE_AGENT));
      curD[t] = (double)vf * invW;
      if (kb == 0) LM[(size_t)step * 64 + t] = vf;
    }
    __syncthreads();
  }
}

// ---------------- generic 128x128 bf16 MFMA GEMM, per-mode epilogues ----------------
template <int MODE>
__global__ __launch_bounds__(256) void gemm_k(
    const void* __restrict__ Ap, const void* __restrict__ Bp,
    int M, int K, int lda, int ldb, int n0c, int cn, const int* __restrict__ flagp,
    float* __restrict__ of0, u16* __restrict__ ob0, u16* __restrict__ ob1, u16* __restrict__ ob2,
    const void* __restrict__ biasRaw, void* __restrict__ outRaw)
{
  constexpr bool A_RAW = (MODE == 0);
  constexpr bool B_RAW = (MODE == 0 || MODE >= 2);
  __shared__ u16 As[128 * 40];
  __shared__ u16 Bs[128 * 40];
  const int t = threadIdx.x;
  const int m0 = blockIdx.x * 128;
  const int n0 = blockIdx.y * 128;
  const int rf = (A_RAW || B_RAW) ? flagp[0] : 0;
  const int aF32 = A_RAW ? rf : 0;
  const int bF32 = B_RAW ? rf : 0;

  size_t aOff = 0, bOff = 0;
  if constexpr (MODE == 1) {
    const int bh = blockIdx.z;
    aOff = (size_t)bh * ((size_t)N_ * 128) + (size_t)n0c * 128;
    bOff = (size_t)bh * (128 * 1024);
  }
  const int lane = t & 63;
  const int w = t >> 6;
  const int mw = (w >> 1) * 64;
  const int nw = (w & 1) * 64;
  const int lr = lane & 15;
  const int lk = lane >> 4;

  f32x4 acc[4][4];
  #pragma unroll
  for (int i = 0; i < 4; ++i)
    #pragma unroll
    for (int j = 0; j < 4; ++j) acc[i][j] = (f32x4){0.f, 0.f, 0.f, 0.f};

  const int ar = t >> 1;
  const int ak = (t & 1) * 16;
  const int bk = t & 31;
  const int bn = (t >> 5) * 16;
  const int agrow = m0 + ar;
  const bool aValid = (agrow < M);

  for (int k0 = 0; k0 < K; k0 += 32) {
    uint4 a0, a1;
    if (aValid) {
      ld16bf(Ap, aOff + (size_t)agrow * lda + k0 + ak, aF32, a0, a1);
    } else {
      a0.x = a0.y = a0.z = a0.w = 0u; a1 = a0;
    }
    uint4 b0, b1;
    ld16bf(Bp, bOff + (size_t)(k0 + bk) * ldb + n0 + bn, bF32, b0, b1);

    *(uint4*)(&As[ar * 40 + ak]) = a0;
    *(uint4*)(&As[ar * 40 + ak + 8]) = a1;
    u16 tmp[16];
    *(uint4*)(tmp) = b0;
    *(uint4*)(tmp + 8) = b1;
    #pragma unroll
    for (int j = 0; j < 16; ++j) Bs[(bn + j) * 40 + bk] = tmp[j];  // Bs[n][k]
    __syncthreads();

    bf16x8 af[4], bfv[4];
    #pragma unroll
    for (int mt = 0; mt < 4; ++mt)
      af[mt] = *(const bf16x8*)(&As[(mw + mt * 16 + lr) * 40 + lk * 8]);
    #pragma unroll
    for (int nt = 0; nt < 4; ++nt)
      bfv[nt] = *(const bf16x8*)(&Bs[(nw + nt * 16 + lr) * 40 + lk * 8]);
    #pragma unroll
    for (int mt = 0; mt < 4; ++mt)
      #pragma unroll
      for (int nt = 0; nt < 4; ++nt)
        acc[mt][nt] = __builtin_amdgcn_mfma_f32_16x16x32_bf16(af[mt], bfv[nt], acc[mt][nt], 0, 0, 0);
    __syncthreads();
  }

  #pragma unroll
  for (int mt = 0; mt < 4; ++mt) {
    #pragma unroll
    for (int nt = 0; nt < 4; ++nt) {
      #pragma unroll
      for (int r = 0; r < 4; ++r) {
        const int grow = m0 + mw + mt * 16 + lk * 4 + r;
        const int gcol = n0 + nw + nt * 16 + lr;
        if (grow >= M) continue;
        float vv = acc[mt][nt][r];
        if constexpr (MODE == 0) {           // qkv -> qb,kb,vb bf16 (bh,N,64)
          int b = (grow >= N_) ? 1 : 0;
          int n = grow - b * N_;
          int t3 = gcol / C_, cc = gcol - t3 * C_;
          int hh = cc >> 6, dd = cc & 63;
          size_t dst = (((size_t)(b * H_ + hh)) * N_ + n) * 64 + dd;
          if (t3 == 0) ob0[dst] = f2b(vv * SC_);
          else if (t3 == 1) ob1[dst] = f2b(vv * SC_);
          else ob2[dst] = f2b(vv);
        } else if constexpr (MODE == 1) {    // xoc (B,cn,F,C) bf16 + xdiag side-write
          const int bh = blockIdx.z;
          int b = bh / H_, hh = bh - b * H_;
          int f = gcol >> 6, dd = gcol & 63;
          u16 wv = f2b(vv);
          ob0[(((size_t)(b * cn + grow)) * F_ + f) * C_ + hh * 64 + dd] = wv;
          int n = n0c + grow;
          if (f == n / P_) ob1[((size_t)(b * cn + grow)) * C_ + hh * 64 + dd] = wv;
        } else if constexpr (MODE == 2) {    // k2c,v2c (B,h,cn,F,d) bf16
          const int cn16 = cn * F_;
          int b = (grow >= cn16) ? 1 : 0;
          int r2 = grow - b * cn16;
          int ln = r2 >> 4, f = r2 & 15;
          int t2 = (gcol >= C_) ? 1 : 0, cc = gcol - t2 * C_;
          int hh = cc >> 6, dd = cc & 63;
          size_t dst = ((((size_t)(b * H_ + hh)) * cn + ln) * F_ + f) * 64 + dd;
          if (t2) ob1[dst] = f2b(vv); else ob0[dst] = f2b(vv);
        } else if constexpr (MODE == 3) {    // q2c (B,h,cn,d) f32, * 0.125
          int b = (grow >= cn) ? 1 : 0;
          int ln = grow - b * cn;
          int hh = gcol >> 6, dd = gcol & 63;
          of0[(((size_t)(b * H_ + hh)) * cn + ln) * 64 + dd] = vv * 0.125f;
        } else {                             // out = o@W_proj + b_proj, flag dtype
          float bvad = bF32 ? ((const float*)biasRaw)[gcol] : b2f(((const u16*)biasRaw)[gcol]);
          float ov = vv + bvad;
          if (bF32) ((float*)outRaw)[(size_t)grow * C_ + gcol] = ov;
          else      ((u16*)outRaw)[(size_t)grow * C_ + gcol] = f2b(ov);
        }
      }
    }
  }
}

// ---------------- kernel_1 = softmax_l(q . lm^T), bf16 out ----------------
__global__ __launch_bounds__(256) void k1_k(const u16* __restrict__ qb,
                                            const float* __restrict__ lm,
                                            u16* __restrict__ k1)
{
  const int bh = blockIdx.y;
  const int r0 = blockIdx.x * 64;
  __shared__ float qT[64][65];
  __shared__ float lmS[128 * 64];
  __shared__ float redA[4][64];
  __shared__ float redB[64];
  const int t = threadIdx.x;
  const u16* Q = qb + ((size_t)bh * N_ + r0) * 64;
  const float* Lm = lm + (size_t)bh * L_ * 64;
  for (int u = t; u < 2048; u += 256) ((float4*)lmS)[u] = ((const float4*)Lm)[u];
  for (int u = t; u < 512; u += 256) {
    int row = u >> 3, j0 = (u & 7) * 8;
    uint4 pk = *(const uint4*)(Q + (size_t)row * 64 + j0);
    const u16* pu = (const u16*)&pk;
    #pragma unroll
    for (int jj = 0; jj < 8; ++jj) qT[j0 + jj][row] = b2f(pu[jj]);
  }
  __syncthreads();
  const int row = t & 63, ch = t >> 6;
  float qr[64];
  #pragma unroll
  for (int j = 0; j < 64; ++j) qr[j] = qT[j][row];
  float s[32];
  for (int li = 0; li < 32; ++li) {
    const float* lp = lmS + (ch * 32 + li) * 64;
    float a = 0.f;
    #pragma unroll
    for (int j = 0; j < 64; ++j) a += lp[j] * qr[j];
    s[li] = a;
  }
  float mx = -1e30f;
  for (int li = 0; li < 32; ++li) mx = fmaxf(mx, s[li]);
  redA[ch][row] = mx;
  __syncthreads();
  if (t < 64) redB[t] = fmaxf(fmaxf(redA[0][t], redA[1][t]), fmaxf(redA[2][t], redA[3][t]));
  __syncthreads();
  mx = redB[row];
  float sum = 0.f;
  for (int li = 0; li < 32; ++li) { float e = __expf(s[li] - mx); s[li] = e; sum += e; }
  __syncthreads();
  redA[ch][row] = sum;
  __syncthreads();
  if (t < 64) redB[t] = 1.0f / (redA[0][t] + redA[1][t] + redA[2][t] + redA[3][t]);
  __syncthreads();
  const float inv = redB[row];
  u16* out = k1 + ((size_t)bh * N_ + r0 + row) * 128 + ch * 32;
  for (int li = 0; li < 32; ++li) out[li] = f2b(s[li] * inv);
}

// ---------------- kernel_2 per frame + x1 = kernel_2 @ v  (LDS-only, 3-pass) ----------------
__global__ __launch_bounds__(256) void k2x1_k(const float* __restrict__ lm,
                                              const u16* __restrict__ kb,
                                              const u16* __restrict__ vb,
                                              u16* __restrict__ x1)
{
  const int bh = blockIdx.x;
  const int f = blockIdx.y;
  __shared__ u16 kS[P_ * 64];
  __shared__ u16 vS[P_ * 64];
  __shared__ float redM[2][128];
  __shared__ float redS[2][128];
  const int t = threadIdx.x;
  const u16* Kf = kb + ((size_t)bh * N_ + f * P_) * 64;
  const u16* Vf = vb + ((size_t)bh * N_ + f * P_) * 64;
  for (int u = t; u < 1568; u += 256) {
    ((uint4*)kS)[u] = ((const uint4*)Kf)[u];
    ((uint4*)vS)[u] = ((const uint4*)Vf)[u];
  }
  __syncthreads();
  const int l = t & 127, half = t >> 7;
  const float* lp = lm + ((size_t)bh * L_ + l) * 64;
  float lr[64];
  #pragma unroll
  for (int j = 0; j < 64; ++j) lr[j] = lp[j];

  const int p0 = half * 98, p1 = p0 + 98;
  float mx = -1e30f;
  for (int p = p0; p < p1; ++p) {
    const uint4* kp = (const uint4*)(kS + p * 64);
    float s = 0.f;
    #pragma unroll
    for (int q4 = 0; q4 < 8; ++q4) {
      uint4 pk = kp[q4];
      const u32* pu = (const u32*)&pk;
      #pragma unroll
      for (int j2 = 0; j2 < 4; ++j2) {
        u32 u = pu[j2];
        s += lr[q4 * 8 + j2 * 2] * lo16f(u) + lr[q4 * 8 + j2 * 2 + 1] * hi16f(u);
      }
    }
    mx = fmaxf(mx, s);
  }
  redM[half][l] = mx;
  __syncthreads();
  mx = fmaxf(redM[0][l], redM[1][l]);

  float sm = 0.f;
  for (int p = p0; p < p1; ++p) {
    const uint4* kp = (const uint4*)(kS + p * 64);
    float s = 0.f;
    #pragma unroll
    for (int q4 = 0; q4 < 8; ++q4) {
      uint4 pk = kp[q4];
      const u32* pu = (const u32*)&pk;
      #pragma unroll
      for (int j2 = 0; j2 < 4; ++j2) {
        u32 u = pu[j2];
        s += lr[q4 * 8 + j2 * 2] * lo16f(u) + lr[q4 * 8 + j2 * 2 + 1] * hi16f(u);
      }
    }
    sm += __expf(s - mx);
  }
  redS[half][l] = sm;
  __syncthreads();
  const float inv = 1.0f / (redS[0][l] + redS[1][l]);

  const int dd0 = half * 32;
  float acc[32];
  #pragma unroll
  for (int u = 0; u < 32; ++u) acc[u] = 0.f;
  for (int p = 0; p < P_; ++p) {
    const uint4* kp = (const uint4*)(kS + p * 64);
    float s = 0.f;
    #pragma unroll
    for (int q4 = 0; q4 < 8; ++q4) {
      uint4 pk = kp[q4];
      const u32* pu = (const u32*)&pk;
      #pragma unroll
      for (int j2 = 0; j2 < 4; ++j2) {
        u32 u = pu[j2];
        s += lr[q4 * 8 + j2 * 2] * lo16f(u) + lr[q4 * 8 + j2 * 2 + 1] * hi16f(u);
      }
    }
    const float e = __expf(s - mx);
    const uint4* vp = (const uint4*)(vS + p * 64 + dd0);
    #pragma unroll
    for (int q4 = 0; q4 < 4; ++q4) {
      uint4 pv = vp[q4];
      const u32* pu = (const u32*)&pv;
      #pragma unroll
      for (int j2 = 0; j2 < 4; ++j2) {
        u32 u = pu[j2];
        acc[q4 * 8 + j2 * 2]     += e * lo16f(u);
        acc[q4 * 8 + j2 * 2 + 1] += e * hi16f(u);
      }
    }
  }
  u16* out = x1 + (((size_t)bh * L_ + l) * F_ + f) * 64 + dd0;
  for (int u = 0; u < 32; ++u) out[u] = f2b(acc[u] * inv);
}

// ---------------- final 16-way frame attention + o = attn @ v2 (chunked) ----------------
__global__ __launch_bounds__(256) void attn_k(const float* __restrict__ q2c,
                                              const u16* __restrict__ k2c,
                                              const u16* __restrict__ v2c,
                                              int n0c, int cn, const int* __restrict__ flagp,
                                              void* __restrict__ outRaw,
                                              u16* __restrict__ o)
{
  const int bh = blockIdx.y;
  const int b = bh / H_, hh = bh - b * H_;
  const int t = threadIdx.x;
  const int f32o = flagp[0];
  __shared__ float aS[64][17];
  const int nl = t >> 2, qi = t & 3;
  const int ln = blockIdx.x * 64 + nl;
  const bool act = ln < cn;
  const int n = n0c + ln;
  float q[64];
  if (act) {
    const float* qr = q2c + ((size_t)bh * cn + ln) * 64;
    #pragma unroll
    for (int j = 0; j < 64; ++j) q[j] = qr[j];
    float lg[4];
    #pragma unroll
    for (int ff = 0; ff < 4; ++ff) {
      const int f = qi * 4 + ff;
      const u16* kp = k2c + (((size_t)bh * cn + ln) * F_ + f) * 64;
      float s = 0.f;
      #pragma unroll
      for (int j8 = 0; j8 < 8; ++j8) {
        uint4 pk = ((const uint4*)kp)[j8];
        const u16* pu = (const u16*)&pk;
        #pragma unroll
        for (int u = 0; u < 8; ++u) s += q[j8 * 8 + u] * b2f(pu[u]);
      }
      lg[ff] = s;
    }
    float mx = fmaxf(fmaxf(lg[0], lg[1]), fmaxf(lg[2], lg[3]));
    mx = fmaxf(mx, __shfl_xor(mx, 1));
    mx = fmaxf(mx, __shfl_xor(mx, 2));
    float e[4], sm = 0.f;
    #pragma unroll
    for (int ff = 0; ff < 4; ++ff) { e[ff] = __expf(lg[ff] - mx); sm += e[ff]; }
    sm += __shfl_xor(sm, 1);
    sm += __shfl_xor(sm, 2);
    const float iv = 1.0f / sm;
    const size_t abase = ((size_t)bh * N_ + n) * F_ + qi * 4;
    #pragma unroll
    for (int ff = 0; ff < 4; ++ff) {
      const float a = e[ff] * iv;
      if (f32o) ((float*)outRaw)[OUTPART_ + abase + ff] = a;
      else      ((u16*)outRaw)[OUTPART_ + abase + ff] = f2b(a);
      aS[nl][qi * 4 + ff] = a;
    }
  }
  __syncthreads();
  if (act) {
    const int dd0 = qi * 16;
    float acc[16];
    #pragma unroll
    for (int u = 0; u < 16; ++u) acc[u] = 0.f;
    for (int f = 0; f < F_; ++f) {
      const float w2 = aS[nl][f];
      const u16* vp = v2c + (((size_t)bh * cn + ln) * F_ + f) * 64 + dd0;
      uint4 pv0 = ((const uint4*)vp)[0], pv1 = ((const uint4*)vp)[1];
      const u16* pu0 = (const u16*)&pv0;
      const u16* pu1 = (const u16*)&pv1;
      #pragma unroll
      for (int u = 0; u < 8; ++u) acc[u] += w2 * b2f(pu0[u]);
      #pragma unroll
      for (int u = 0; u < 8; ++u) acc[8 + u] += w2 * b2f(pu1[u]);
    }
    u16* op = o + ((size_t)(b * N_ + n)) * C_ + hh * 64 + dd0;
    for (int u = 0; u < 16; ++u) op[u] = f2b(acc[u]);
  }
}

extern "C" void kernel_launch(void* const* d_in, const int* in_sizes, int n_in,
                              void* d_out, int out_size, void* d_ws, size_t ws_size,
                              hipStream_t stream)
{
  (void)in_sizes; (void)n_in; (void)out_size;
  const void* x     = d_in[0];
  const void* Wqkv  = d_in[1];
  const void* Wpq   = d_in[2];
  const void* Wpkv  = d_in[3];
  const void* Wproj = d_in[4];
  const void* bproj = d_in[5];

  char* ws = (char*)d_ws;
  size_t off = 0;
  auto alloc = [&](size_t bytes) { void* p = ws + off; off += (bytes + 255) & ~(size_t)255; return p; };
  int*  flagp = (int*)alloc(256);
  u16*  qb  = (u16*)alloc(9633792);     // (bh,N,64) bf16, scaled
  u16*  kb  = (u16*)alloc(9633792);     // scaled
  u16*  vb  = (u16*)alloc(9633792);
  float* lm = (float*)alloc(786432);    // (bh,128,64) f32
  u16*  x1b = (u16*)alloc(6291456);     // (bh,128,16,64) bf16
  u16*  ob  = (u16*)alloc(9633792);     // (B,N,C) bf16
  const size_t k1off = off;             // qT f32 starts here (aliases k1b + chunk region)
  u16*  k1b = (u16*)alloc(19267584);    // (bh,N,128) bf16
  const size_t chunk0 = off;

  // qT (selection f32, transposed [bh][64][N]) needs 19,267,584 B at k1off;
  // dead before k1b & chunk region live
  const size_t qtNeed = k1off + 19267584 + 256;

  int Nc = 0;
  {
    const int cands[5] = {3136, 1568, 784, 392, 196};
    for (int i = 0; i < 5; ++i) {
      size_t need = chunk0 + (size_t)156672 * cands[i] + 1024;
      if (need <= ws_size && qtNeed <= ws_size) { Nc = cands[i]; break; }
    }
  }
  if (Nc == 0) return;  // ws floor ~95.7 MB
  const int nchunks = N_ / Nc;
  u16*  xoc = (u16*)(ws + chunk0);                // (B,Nc,F,C) bf16
  u16*  k2c = xoc + (size_t)24576 * Nc;           // (B,h,Nc,F,d) bf16
  u16*  v2c = k2c + (size_t)24576 * Nc;
  u16*  xdc = v2c + (size_t)24576 * Nc;           // (B,Nc,C) bf16
  float* q2c = (float*)(xdc + (size_t)1536 * Nc); // (B,h,Nc,d) f32
  float* qt  = (float*)(ws + k1off);              // selection-grade f32 qT (dead before k1_k)

  // landmark multi-block scratch: lives in chunk region (dead until chunk loop).
  // min chunk need (Nc=196) is ~30.7 MB >> 0.61 MB used here.
  u64* invN  = (u64*)(ws + chunk0);                       // 24*3136*8  = 602112
  u64* candV = (u64*)(ws + chunk0 + 602112);              // 24*2*8*8   = 3072
  int* candI = (int*)(ws + chunk0 + 602112 + 3072);       // 24*2*8*4   = 1536
  int* cntp  = (int*)(ws + chunk0 + 602112 + 3072 + 1536);// 24*4       = 96

  // dtype sniff on W_qkv; zero landmark barrier counters (every launch)
  detect_k<<<1, 64, 0, stream>>>((const u32*)Wqkv, flagp);
  zcnt_k<<<1, 32, 0, stream>>>(cntp);

  // selection-grade f32 qT (transposed), then multi-block greedy landmarks
  qselT_k<<<dim3(98, 12), 256, 0, stream>>>(x, Wqkv, flagp, qt);
  landmarksMB_k<<<dim3(KB_, 24), 512, 0, stream>>>(qt, lm, invN, candV, candI, cntp);

  // qkv projection -> qb,kb,vb (bf16 smooth path)
  gemm_k<0><<<dim3(49, 18, 1), 256, 0, stream>>>(x, Wqkv, 6272, 768, 768, 2304, 0, 0, flagp,
                                                 nullptr, qb, kb, vb, nullptr, nullptr);
  // kernel_2 + x1 (LDS-only)
  k2x1_k<<<dim3(24, 16), 256, 0, stream>>>(lm, kb, vb, x1b);
  // kernel_1 (overwrites qT region — qT dead)
  k1_k<<<dim3(49, 24), 256, 0, stream>>>(qb, lm, k1b);

  for (int c = 0; c < nchunks; ++c) {
    const int n0c = c * Nc;
    gemm_k<1><<<dim3((Nc + 127) / 128, 8, 24), 256, 0, stream>>>(
        k1b, x1b, Nc, 128, 128, 1024, n0c, Nc, flagp, nullptr, xoc, xdc, nullptr, nullptr, nullptr);
    gemm_k<2><<<dim3((2 * Nc * 16) / 128, 12, 1), 256, 0, stream>>>(
        xoc, Wpkv, 2 * Nc * 16, 768, 768, 1536, n0c, Nc, flagp, nullptr, k2c, v2c, nullptr, nullptr, nullptr);
    gemm_k<3><<<dim3((2 * Nc + 127) / 128, 6, 1), 256, 0, stream>>>(
        xdc, Wpq, 2 * Nc, 768, 768, 768, n0c, Nc, flagp, q2c, nullptr, nullptr, nullptr, nullptr, nullptr);
    attn_k<<<dim3((Nc + 63) / 64, 24), 256, 0, stream>>>(
        q2c, k2c, v2c, n0c, Nc, flagp, d_out, ob);
  }
  // out = o @ W_proj + b_proj
  gemm_k<4><<<dim3(49, 6, 1), 256, 0, stream>>>(ob, Wproj, 6272, 768, 768, 768, 0, 0, flagp,
                                                nullptr, nullptr, nullptr, nullptr, bproj, d_out);
}

// Round 2
// 2452.316 us; speedup vs baseline: 1.5006x; 1.5006x over previous
//
#include <hip/hip_runtime.h>

// TrajectoryAttention on MI355X (gfx950), chunked pipeline, dtype-adaptive.
// R10: landmarks cross-block sync WITHOUT fences. R9's acquire/release agent
//   fences compiled to full L1+L2 invalidates per spin iteration -> qT evicted
//   from L2 every step (FETCH 9MB->214MB, 15.7us/step). R10 communicates ONLY
//   via relaxed agent-scope atomics (cache-bypassing, no buffer_inv):
//   one packed u64 per block per step = [63:19] truncated f64 max_sim |
//   [18:12] step tag | [11:0] row idx. Writer: single atomic store (data rides
//   in the store -> no write fence). Reader: lanes 0-7 poll 8 slots until all
//   tags match, u64-min shuffle reduce (== (value,idx) lexical min). Parity
//   double-buffer (R9-proven) + tag => no counter RMW, no ABA. invN dropped:
//   winner norm recomputed via t<64 butterfly (R8's exact proven math).
// R9 (kept): 8 blocks/head on 8 different XCDs (round-robin), quad-split f64
//   dots (numerics proven: absmax identical to R8).
// R8 (kept): qselT_k f32 GEMM -> transposed qT[bh][d][n]; coalesced reads.
// R7 (kept): partitionable threefry idx0; bf16 MFMA smooth path; chunked k2/v2.

using u16 = unsigned short;
using u32 = unsigned int;
using u64 = unsigned long long;

typedef short bf16x8 __attribute__((ext_vector_type(8)));
typedef float f32x4 __attribute__((ext_vector_type(4)));

#define N_ 3136
#define C_ 768
#define H_ 12
#define F_ 16
#define P_ 196
#define L_ 128
#define SC_ 0.35355339059327373f   // 64^-0.25
#define OUTPART_ ((size_t)2 * N_ * C_)
#define KB_ 8                      // blocks per head in landmarks
#define RPB_ 392                   // rows per block (3136/8)

__device__ __forceinline__ float b2f(u16 u) {
  u32 x = ((u32)u) << 16; float f; __builtin_memcpy(&f, &x, 4); return f;
}
__device__ __forceinline__ float lo16f(u32 u) {
  u32 x = u << 16; float f; __builtin_memcpy(&f, &x, 4); return f;
}
__device__ __forceinline__ float hi16f(u32 u) {
  u32 x = u & 0xFFFF0000u; float f; __builtin_memcpy(&f, &x, 4); return f;
}
__device__ __forceinline__ u16 f2b(float f) {
  u32 u; __builtin_memcpy(&u, &f, 4);
  u32 r = (u + 0x7FFFu + ((u >> 16) & 1u)) >> 16;
  return (u16)r;
}
__device__ __forceinline__ u64 d2u(double d) { u64 u; __builtin_memcpy(&u, &d, 8); return u; }

// load 16 contiguous logical elements as bf16 uint4 pair, from raw input of either dtype
__device__ __forceinline__ void ld16bf(const void* base, size_t elemOff, int isF32,
                                       uint4& o0, uint4& o1) {
  if (isF32) {
    const float4* p = (const float4*)((const float*)base + elemOff);
    float4 f0 = p[0], f1 = p[1], f2v = p[2], f3 = p[3];
    u16 tmp[16] = { f2b(f0.x), f2b(f0.y), f2b(f0.z), f2b(f0.w),
                    f2b(f1.x), f2b(f1.y), f2b(f1.z), f2b(f1.w),
                    f2b(f2v.x), f2b(f2v.y), f2b(f2v.z), f2b(f2v.w),
                    f2b(f3.x), f2b(f3.y), f2b(f3.z), f2b(f3.w) };
    __builtin_memcpy(&o0, tmp, 16);
    __builtin_memcpy(&o1, tmp + 8, 16);
  } else {
    const uint4* p = (const uint4*)((const u16*)base + elemOff);
    o0 = p[0]; o1 = p[1];
  }
}

// dtype sniffer (bf16 vs f32 inputs) — votes f32 on this dataset (proven R4)
__global__ void detect_k(const u32* __restrict__ w, int* __restrict__ flag) {
  const int t = threadIdx.x;  // 64
  int hits = 0;
  #pragma unroll
  for (int i = 0; i < 16; ++i) {
    u32 word = w[t * 16 + i];
    u32 e = (word >> 7) & 0xFFu;
    if (e >= 110u && e <= 126u) hits++;
  }
  #pragma unroll
  for (int off = 32; off > 0; off >>= 1) hits += __shfl_down(hits, off);
  if (t == 0) flag[0] = (hits >= 512) ? 0 : 1;  // 0=bf16, 1=f32
}

// zero candidate slots (24 heads x 2 parity x 8 blocks = 384 u64).
// Re-run every launch: graph-replay safe. tag field 0 != any step (1..127).
__global__ void zcnt_k(u64* __restrict__ p) { if (threadIdx.x < 384) p[threadIdx.x] = 0ull; }

// ---- exact JAX threefry2x32-20 core ----
__device__ __forceinline__ void tf2(u32 k0, u32 k1v, u32 c0, u32 c1, u32& o0, u32& o1) {
  u32 ks[3] = {k0, k1v, k0 ^ k1v ^ 0x1BD11BDAu};
  u32 x0 = c0 + ks[0], x1 = c1 + ks[1];
  const u32 rA[4] = {13u, 15u, 26u, 6u}, rB[4] = {17u, 29u, 16u, 24u};
  #pragma unroll
  for (int r = 0; r < 5; ++r) {
    #pragma unroll
    for (int q = 0; q < 4; ++q) {
      u32 rot = (r & 1) ? rB[q] : rA[q];
      x0 += x1; x1 = (x1 << rot) | (x1 >> (32u - rot)); x1 ^= x0;
    }
    x0 += ks[(r + 1) % 3];
    x1 += ks[(r + 2) % 3] + (u32)(r + 1);
  }
  o0 = x0; o1 = x1;
}

// jax.random.randint(key(42), (24,), 0, 3136) under jax_threefry_partitionable=True
// — PROVEN correct on this dataset (R7 passed at smooth-path floor).
__device__ __forceinline__ int tf_idx0(int bh) {
  u32 a0, a1, b0, b1;
  tf2(0u, 42u, 0u, 0u, a0, a1);   // k1 = subkey 0
  tf2(0u, 42u, 0u, 1u, b0, b1);   // k2 = subkey 1
  u32 j = (u32)bh;
  u32 h0, h1, l0, l1;
  tf2(a0, a1, 0u, j, h0, h1);     // higher_bits[j]
  u32 hi = h0 ^ h1;
  tf2(b0, b1, 0u, j, l0, l1);     // lower_bits[j]
  u32 lo = l0 ^ l1;
  return (int)(((hi % 3136u) * 2048u + (lo % 3136u)) % 3136u);
}

// ---------------- selection-grade f32 GEMM -> TRANSPOSED qT[bh][d][n] ----------------
__global__ __launch_bounds__(256) void qselT_k(const void* __restrict__ xr, const void* __restrict__ wr,
                                               const int* __restrict__ flagp, float* __restrict__ qt)
{
  __shared__ float As[64 * 20];
  __shared__ float Bs[16 * 64];
  const int t = threadIdx.x;
  const int m0 = blockIdx.x * 64;
  const int n0 = blockIdx.y * 64;
  const int f32i = flagp[0];
  const int tx = t & 15, ty = t >> 4;
  float acc[4][4];
  #pragma unroll
  for (int i = 0; i < 4; ++i)
    #pragma unroll
    for (int j = 0; j < 4; ++j) acc[i][j] = 0.f;

  const int alr = t >> 2;               // A tile row (0..63)
  const int alk = (t & 3) * 4;          // A k offset
  const int bkr = t >> 4;               // B k row (0..15)
  const int bnc = (t & 15) * 4;         // B col offset

  for (int k0 = 0; k0 < 768; k0 += 16) {
    float4 av, bv;
    if (f32i) {
      av = *(const float4*)((const float*)xr + (size_t)(m0 + alr) * 768 + k0 + alk);
      bv = *(const float4*)((const float*)wr + (size_t)(k0 + bkr) * 2304 + n0 + bnc);
    } else {
      const u16* xa = (const u16*)xr + (size_t)(m0 + alr) * 768 + k0 + alk;
      const u16* wa = (const u16*)wr + (size_t)(k0 + bkr) * 2304 + n0 + bnc;
      av.x = b2f(xa[0]); av.y = b2f(xa[1]); av.z = b2f(xa[2]); av.w = b2f(xa[3]);
      bv.x = b2f(wa[0]); bv.y = b2f(wa[1]); bv.z = b2f(wa[2]); bv.w = b2f(wa[3]);
    }
    As[alr * 20 + alk + 0] = av.x; As[alr * 20 + alk + 1] = av.y;
    As[alr * 20 + alk + 2] = av.z; As[alr * 20 + alk + 3] = av.w;
    *(float4*)(&Bs[bkr * 64 + bnc]) = bv;
    __syncthreads();
    #pragma unroll
    for (int kk = 0; kk < 16; ++kk) {
      float a[4], b[4];
      #pragma unroll
      for (int i = 0; i < 4; ++i) a[i] = As[(ty * 4 + i) * 20 + kk];
      #pragma unroll
      for (int j = 0; j < 4; ++j) b[j] = Bs[kk * 64 + tx * 4 + j];
      #pragma unroll
      for (int i = 0; i < 4; ++i)
        #pragma unroll
        for (int j = 0; j < 4; ++j) acc[i][j] += a[i] * b[j];
    }
    __syncthreads();
  }
  #pragma unroll
  for (int i = 0; i < 4; ++i) {
    const int m = m0 + ty * 4 + i;
    const int b = m / N_, n = m - b * N_;
    #pragma unroll
    for (int j = 0; j < 4; ++j) {
      const int col = n0 + tx * 4 + j;
      const int hh = col >> 6, dd = col & 63;
      qt[((size_t)(b * H_ + hh) * 64 + dd) * N_ + n] = acc[i][j] * SC_;
    }
  }
}

// ---------------- greedy landmarks: 8 blocks/head, fence-free polling barrier ----------------
// Block kb owns rows [kb*392, kb*392+392). Per step each block computes its local
// argmin candidate, posts ONE packed u64 (relaxed agent atomic store, cache-
// bypassing, no fence), then wave 0 polls all 8 slots until every tag == step.
// qT is read-only -> normal cached loads stay valid (no invalidation ever).
// Packed layout: [63:19] top bits of f64 max_sim (rel. prec 2^-33, far below
// selection margins) | [18:12] step & 127 | [11:0] row idx. u64-min over slots
// with equal tags == lexical (value, idx) min (nonneg doubles order as u64).
__global__ __launch_bounds__(512, 1) void landmarksP_k(
    const float* __restrict__ qt, float* __restrict__ lm, u64* __restrict__ cand)
{
  const int kb = blockIdx.x;
  const int bh = blockIdx.y;
  const float* QT = qt + (size_t)bh * 64 * N_;   // [d][n]
  float* LM = lm + (size_t)bh * L_ * 64;
  u64* cd = cand + (size_t)bh * 16;              // 16 u64 = 128B line per head
  __shared__ double curD[64];
  __shared__ u64 redV[8];
  __shared__ int redI[8];
  __shared__ int sW;
  const int t = threadIdx.x;
  const bool act = (t < RPB_);                   // 392 active (quad-aligned)
  const int g = t >> 2, dc = t & 3, d0 = dc * 16;
  const int r0 = kb * RPB_;
  const int myRow = r0 + t;                      // owned row (act only)
  const float* base = QT + r0 + 4 * g;

  // norms (f64 from f32 data): quad-split over d, butterfly combine (R9-proven)
  double inv_own = 0.0, ms_own = 0.0;
  if (act) {
    double s0 = 0.0, s1 = 0.0, s2 = 0.0, s3 = 0.0;
    #pragma unroll
    for (int i = 0; i < 16; ++i) {
      float4 v = *(const float4*)(base + (size_t)(d0 + i) * N_);
      s0 += (double)v.x * (double)v.x; s1 += (double)v.y * (double)v.y;
      s2 += (double)v.z * (double)v.z; s3 += (double)v.w * (double)v.w;
    }
    s0 += __shfl_xor(s0, 1); s1 += __shfl_xor(s1, 1);
    s2 += __shfl_xor(s2, 1); s3 += __shfl_xor(s3, 1);
    s0 += __shfl_xor(s0, 2); s1 += __shfl_xor(s1, 2);
    s2 += __shfl_xor(s2, 2); s3 += __shfl_xor(s3, 2);
    const double sown = (dc == 0) ? s0 : (dc == 1) ? s1 : (dc == 2) ? s2 : s3;
    inv_own = 1.0 / fmax(sqrt(sown), 1e-12);
  }
  const int idx0 = tf_idx0(bh);
  if (act && myRow == idx0) ms_own = 10.0;

  // initial direction: winner-column norm recomputed locally (R8's exact math)
  if (t < 64) {
    const float vf = QT[(size_t)t * N_ + idx0];
    double v = (double)vf;
    double s = v * v;
    #pragma unroll
    for (int off = 32; off; off >>= 1) s += __shfl_xor(s, off);
    curD[t] = v / fmax(sqrt(s), 1e-12);
    if (kb == 0) LM[t] = vf;
  }
  __syncthreads();

  for (int step = 1; step < 128; ++step) {
    u64 bV = d2u(1e30); int bI = 0x7fffffff;
    if (act) {
      double a0 = 0.0, a1 = 0.0, a2 = 0.0, a3 = 0.0;
      #pragma unroll
      for (int i = 0; i < 16; ++i) {
        float4 v = *(const float4*)(base + (size_t)(d0 + i) * N_);
        const double c = curD[d0 + i];
        a0 += (double)v.x * c; a1 += (double)v.y * c;
        a2 += (double)v.z * c; a3 += (double)v.w * c;
      }
      a0 += __shfl_xor(a0, 1); a1 += __shfl_xor(a1, 1);
      a2 += __shfl_xor(a2, 1); a3 += __shfl_xor(a3, 1);
      a0 += __shfl_xor(a0, 2); a1 += __shfl_xor(a1, 2);
      a2 += __shfl_xor(a2, 2); a3 += __shfl_xor(a3, 2);
      const double aown = (dc == 0) ? a0 : (dc == 1) ? a1 : (dc == 2) ? a2 : a3;
      ms_own = fmax(ms_own, fabs(aown * inv_own));
      bV = d2u(ms_own); bI = myRow;   // nonneg doubles: bit order == numeric order
    }
    // wave argmin (val, then lowest idx)
    #pragma unroll
    for (int off = 32; off; off >>= 1) {
      const u64 ov = __shfl_xor(bV, off);
      const int oi = __shfl_xor(bI, off);
      if (ov < bV || (ov == bV && oi < bI)) { bV = ov; bI = oi; }
    }
    if ((t & 63) == 0) { redV[t >> 6] = bV; redI[t >> 6] = bI; }
    __syncthreads();
    const int par = step & 1;
    if (t == 0) {
      u64 v = redV[0]; int ix = redI[0];
      #pragma unroll
      for (int w2 = 1; w2 < 8; ++w2)
        if (redV[w2] < v || (redV[w2] == v && redI[w2] < ix)) { v = redV[w2]; ix = redI[w2]; }
      const u64 pk = (v & ~((1ull << 19) - 1ull)) | ((u64)(u32)(step & 127) << 12) | (u64)(u32)ix;
      __hip_atomic_store(&cd[par * KB_ + kb], pk, __ATOMIC_RELAXED, __HIP_MEMORY_SCOPE_AGENT);
    }
    // fence-free barrier: wave 0 polls the 8 slots (cache-bypassing loads)
    if (t < 64) {
      u64 pv = ~0ull;
      int ok = 1;
      for (;;) {
        if (t < KB_) {
          pv = __hip_atomic_load(&cd[par * KB_ + t], __ATOMIC_RELAXED, __HIP_MEMORY_SCOPE_AGENT);
          ok = ((int)((pv >> 12) & 127u) == step) ? 1 : 0;
        }
        if (__all(ok)) break;
        __builtin_amdgcn_s_sleep(1);
      }
      u64 m = (t < KB_) ? pv : ~0ull;
      #pragma unroll
      for (int off = 1; off < KB_; off <<= 1) {
        const u64 o = __shfl_xor(m, off);
        if (o < m) m = o;
      }
      if (t == 0) sW = (int)(m & 0xFFFu);
    }
    __syncthreads();
    const int w = sW;
    if (act && myRow == w) ms_own = 10.0;
    if (t < 64) {
      const float vf = QT[(size_t)t * N_ + w];
      double v = (double)vf;
      double s = v * v;
      #pragma unroll
      for (int off = 32; off; off >>= 1) s += __shfl_xor(s, off);
      curD[t] = v / fmax(sqrt(s), 1e-12);
      if (kb == 0) LM[(size_t)step * 64 + t] = vf;
    }
    __syncthreads();
  }
}

// ---------------- generic 128x128 bf16 MFMA GEMM, per-mode epilogues ----------------
template <int MODE>
__global__ __launch_bounds__(256) void gemm_k(
    const void* __restrict__ Ap, const void* __restrict__ Bp,
    int M, int K, int lda, int ldb, int n0c, int cn, const int* __restrict__ flagp,
    float* __restrict__ of0, u16* __restrict__ ob0, u16* __restrict__ ob1, u16* __restrict__ ob2,
    const void* __restrict__ biasRaw, void* __restrict__ outRaw)
{
  constexpr bool A_RAW = (MODE == 0);
  constexpr bool B_RAW = (MODE == 0 || MODE >= 2);
  __shared__ u16 As[128 * 40];
  __shared__ u16 Bs[128 * 40];
  const int t = threadIdx.x;
  const int m0 = blockIdx.x * 128;
  const int n0 = blockIdx.y * 128;
  const int rf = (A_RAW || B_RAW) ? flagp[0] : 0;
  const int aF32 = A_RAW ? rf : 0;
  const int bF32 = B_RAW ? rf : 0;

  size_t aOff = 0, bOff = 0;
  if constexpr (MODE == 1) {
    const int bh = blockIdx.z;
    aOff = (size_t)bh * ((size_t)N_ * 128) + (size_t)n0c * 128;
    bOff = (size_t)bh * (128 * 1024);
  }
  const int lane = t & 63;
  const int w = t >> 6;
  const int mw = (w >> 1) * 64;
  const int nw = (w & 1) * 64;
  const int lr = lane & 15;
  const int lk = lane >> 4;

  f32x4 acc[4][4];
  #pragma unroll
  for (int i = 0; i < 4; ++i)
    #pragma unroll
    for (int j = 0; j < 4; ++j) acc[i][j] = (f32x4){0.f, 0.f, 0.f, 0.f};

  const int ar = t >> 1;
  const int ak = (t & 1) * 16;
  const int bk = t & 31;
  const int bn = (t >> 5) * 16;
  const int agrow = m0 + ar;
  const bool aValid = (agrow < M);

  for (int k0 = 0; k0 < K; k0 += 32) {
    uint4 a0, a1;
    if (aValid) {
      ld16bf(Ap, aOff + (size_t)agrow * lda + k0 + ak, aF32, a0, a1);
    } else {
      a0.x = a0.y = a0.z = a0.w = 0u; a1 = a0;
    }
    uint4 b0, b1;
    ld16bf(Bp, bOff + (size_t)(k0 + bk) * ldb + n0 + bn, bF32, b0, b1);

    *(uint4*)(&As[ar * 40 + ak]) = a0;
    *(uint4*)(&As[ar * 40 + ak + 8]) = a1;
    u16 tmp[16];
    *(uint4*)(tmp) = b0;
    *(uint4*)(tmp + 8) = b1;
    #pragma unroll
    for (int j = 0; j < 16; ++j) Bs[(bn + j) * 40 + bk] = tmp[j];  // Bs[n][k]
    __syncthreads();

    bf16x8 af[4], bfv[4];
    #pragma unroll
    for (int mt = 0; mt < 4; ++mt)
      af[mt] = *(const bf16x8*)(&As[(mw + mt * 16 + lr) * 40 + lk * 8]);
    #pragma unroll
    for (int nt = 0; nt < 4; ++nt)
      bfv[nt] = *(const bf16x8*)(&Bs[(nw + nt * 16 + lr) * 40 + lk * 8]);
    #pragma unroll
    for (int mt = 0; mt < 4; ++mt)
      #pragma unroll
      for (int nt = 0; nt < 4; ++nt)
        acc[mt][nt] = __builtin_amdgcn_mfma_f32_16x16x32_bf16(af[mt], bfv[nt], acc[mt][nt], 0, 0, 0);
    __syncthreads();
  }

  #pragma unroll
  for (int mt = 0; mt < 4; ++mt) {
    #pragma unroll
    for (int nt = 0; nt < 4; ++nt) {
      #pragma unroll
      for (int r = 0; r < 4; ++r) {
        const int grow = m0 + mw + mt * 16 + lk * 4 + r;
        const int gcol = n0 + nw + nt * 16 + lr;
        if (grow >= M) continue;
        float vv = acc[mt][nt][r];
        if constexpr (MODE == 0) {           // qkv -> qb,kb,vb bf16 (bh,N,64)
          int b = (grow >= N_) ? 1 : 0;
          int n = grow - b * N_;
          int t3 = gcol / C_, cc = gcol - t3 * C_;
          int hh = cc >> 6, dd = cc & 63;
          size_t dst = (((size_t)(b * H_ + hh)) * N_ + n) * 64 + dd;
          if (t3 == 0) ob0[dst] = f2b(vv * SC_);
          else if (t3 == 1) ob1[dst] = f2b(vv * SC_);
          else ob2[dst] = f2b(vv);
        } else if constexpr (MODE == 1) {    // xoc (B,cn,F,C) bf16 + xdiag side-write
          const int bh = blockIdx.z;
          int b = bh / H_, hh = bh - b * H_;
          int f = gcol >> 6, dd = gcol & 63;
          u16 wv = f2b(vv);
          ob0[(((size_t)(b * cn + grow)) * F_ + f) * C_ + hh * 64 + dd] = wv;
          int n = n0c + grow;
          if (f == n / P_) ob1[((size_t)(b * cn + grow)) * C_ + hh * 64 + dd] = wv;
        } else if constexpr (MODE == 2) {    // k2c,v2c (B,h,cn,F,d) bf16
          const int cn16 = cn * F_;
          int b = (grow >= cn16) ? 1 : 0;
          int r2 = grow - b * cn16;
          int ln = r2 >> 4, f = r2 & 15;
          int t2 = (gcol >= C_) ? 1 : 0, cc = gcol - t2 * C_;
          int hh = cc >> 6, dd = cc & 63;
          size_t dst = ((((size_t)(b * H_ + hh)) * cn + ln) * F_ + f) * 64 + dd;
          if (t2) ob1[dst] = f2b(vv); else ob0[dst] = f2b(vv);
        } else if constexpr (MODE == 3) {    // q2c (B,h,cn,d) f32, * 0.125
          int b = (grow >= cn) ? 1 : 0;
          int ln = grow - b * cn;
          int hh = gcol >> 6, dd = gcol & 63;
          of0[(((size_t)(b * H_ + hh)) * cn + ln) * 64 + dd] = vv * 0.125f;
        } else {                             // out = o@W_proj + b_proj, flag dtype
          float bvad = bF32 ? ((const float*)biasRaw)[gcol] : b2f(((const u16*)biasRaw)[gcol]);
          float ov = vv + bvad;
          if (bF32) ((float*)outRaw)[(size_t)grow * C_ + gcol] = ov;
          else      ((u16*)outRaw)[(size_t)grow * C_ + gcol] = f2b(ov);
        }
      }
    }
  }
}

// ---------------- kernel_1 = softmax_l(q . lm^T), bf16 out ----------------
__global__ __launch_bounds__(256) void k1_k(const u16* __restrict__ qb,
                                            const float* __restrict__ lm,
                                            u16* __restrict__ k1)
{
  const int bh = blockIdx.y;
  const int r0 = blockIdx.x * 64;
  __shared__ float qT[64][65];
  __shared__ float lmS[128 * 64];
  __shared__ float redA[4][64];
  __shared__ float redB[64];
  const int t = threadIdx.x;
  const u16* Q = qb + ((size_t)bh * N_ + r0) * 64;
  const float* Lm = lm + (size_t)bh * L_ * 64;
  for (int u = t; u < 2048; u += 256) ((float4*)lmS)[u] = ((const float4*)Lm)[u];
  for (int u = t; u < 512; u += 256) {
    int row = u >> 3, j0 = (u & 7) * 8;
    uint4 pk = *(const uint4*)(Q + (size_t)row * 64 + j0);
    const u16* pu = (const u16*)&pk;
    #pragma unroll
    for (int jj = 0; jj < 8; ++jj) qT[j0 + jj][row] = b2f(pu[jj]);
  }
  __syncthreads();
  const int row = t & 63, ch = t >> 6;
  float qr[64];
  #pragma unroll
  for (int j = 0; j < 64; ++j) qr[j] = qT[j][row];
  float s[32];
  for (int li = 0; li < 32; ++li) {
    const float* lp = lmS + (ch * 32 + li) * 64;
    float a = 0.f;
    #pragma unroll
    for (int j = 0; j < 64; ++j) a += lp[j] * qr[j];
    s[li] = a;
  }
  float mx = -1e30f;
  for (int li = 0; li < 32; ++li) mx = fmaxf(mx, s[li]);
  redA[ch][row] = mx;
  __syncthreads();
  if (t < 64) redB[t] = fmaxf(fmaxf(redA[0][t], redA[1][t]), fmaxf(redA[2][t], redA[3][t]));
  __syncthreads();
  mx = redB[row];
  float sum = 0.f;
  for (int li = 0; li < 32; ++li) { float e = __expf(s[li] - mx); s[li] = e; sum += e; }
  __syncthreads();
  redA[ch][row] = sum;
  __syncthreads();
  if (t < 64) redB[t] = 1.0f / (redA[0][t] + redA[1][t] + redA[2][t] + redA[3][t]);
  __syncthreads();
  const float inv = redB[row];
  u16* out = k1 + ((size_t)bh * N_ + r0 + row) * 128 + ch * 32;
  for (int li = 0; li < 32; ++li) out[li] = f2b(s[li] * inv);
}

// ---------------- kernel_2 per frame + x1 = kernel_2 @ v  (LDS-only, 3-pass) ----------------
__global__ __launch_bounds__(256) void k2x1_k(const float* __restrict__ lm,
                                              const u16* __restrict__ kb,
                                              const u16* __restrict__ vb,
                                              u16* __restrict__ x1)
{
  const int bh = blockIdx.x;
  const int f = blockIdx.y;
  __shared__ u16 kS[P_ * 64];
  __shared__ u16 vS[P_ * 64];
  __shared__ float redM[2][128];
  __shared__ float redS[2][128];
  const int t = threadIdx.x;
  const u16* Kf = kb + ((size_t)bh * N_ + f * P_) * 64;
  const u16* Vf = vb + ((size_t)bh * N_ + f * P_) * 64;
  for (int u = t; u < 1568; u += 256) {
    ((uint4*)kS)[u] = ((const uint4*)Kf)[u];
    ((uint4*)vS)[u] = ((const uint4*)Vf)[u];
  }
  __syncthreads();
  const int l = t & 127, half = t >> 7;
  const float* lp = lm + ((size_t)bh * L_ + l) * 64;
  float lr[64];
  #pragma unroll
  for (int j = 0; j < 64; ++j) lr[j] = lp[j];

  const int p0 = half * 98, p1 = p0 + 98;
  float mx = -1e30f;
  for (int p = p0; p < p1; ++p) {
    const uint4* kp = (const uint4*)(kS + p * 64);
    float s = 0.f;
    #pragma unroll
    for (int q4 = 0; q4 < 8; ++q4) {
      uint4 pk = kp[q4];
      const u32* pu = (const u32*)&pk;
      #pragma unroll
      for (int j2 = 0; j2 < 4; ++j2) {
        u32 u = pu[j2];
        s += lr[q4 * 8 + j2 * 2] * lo16f(u) + lr[q4 * 8 + j2 * 2 + 1] * hi16f(u);
      }
    }
    mx = fmaxf(mx, s);
  }
  redM[half][l] = mx;
  __syncthreads();
  mx = fmaxf(redM[0][l], redM[1][l]);

  float sm = 0.f;
  for (int p = p0; p < p1; ++p) {
    const uint4* kp = (const uint4*)(kS + p * 64);
    float s = 0.f;
    #pragma unroll
    for (int q4 = 0; q4 < 8; ++q4) {
      uint4 pk = kp[q4];
      const u32* pu = (const u32*)&pk;
      #pragma unroll
      for (int j2 = 0; j2 < 4; ++j2) {
        u32 u = pu[j2];
        s += lr[q4 * 8 + j2 * 2] * lo16f(u) + lr[q4 * 8 + j2 * 2 + 1] * hi16f(u);
      }
    }
    sm += __expf(s - mx);
  }
  redS[half][l] = sm;
  __syncthreads();
  const float inv = 1.0f / (redS[0][l] + redS[1][l]);

  const int dd0 = half * 32;
  float acc[32];
  #pragma unroll
  for (int u = 0; u < 32; ++u) acc[u] = 0.f;
  for (int p = 0; p < P_; ++p) {
    const uint4* kp = (const uint4*)(kS + p * 64);
    float s = 0.f;
    #pragma unroll
    for (int q4 = 0; q4 < 8; ++q4) {
      uint4 pk = kp[q4];
      const u32* pu = (const u32*)&pk;
      #pragma unroll
      for (int j2 = 0; j2 < 4; ++j2) {
        u32 u = pu[j2];
        s += lr[q4 * 8 + j2 * 2] * lo16f(u) + lr[q4 * 8 + j2 * 2 + 1] * hi16f(u);
      }
    }
    const float e = __expf(s - mx);
    const uint4* vp = (const uint4*)(vS + p * 64 + dd0);
    #pragma unroll
    for (int q4 = 0; q4 < 4; ++q4) {
      uint4 pv = vp[q4];
      const u32* pu = (const u32*)&pv;
      #pragma unroll
      for (int j2 = 0; j2 < 4; ++j2) {
        u32 u = pu[j2];
        acc[q4 * 8 + j2 * 2]     += e * lo16f(u);
        acc[q4 * 8 + j2 * 2 + 1] += e * hi16f(u);
      }
    }
  }
  u16* out = x1 + (((size_t)bh * L_ + l) * F_ + f) * 64 + dd0;
  for (int u = 0; u < 32; ++u) out[u] = f2b(acc[u] * inv);
}

// ---------------- final 16-way frame attention + o = attn @ v2 (chunked) ----------------
__global__ __launch_bounds__(256) void attn_k(const float* __restrict__ q2c,
                                              const u16* __restrict__ k2c,
                                              const u16* __restrict__ v2c,
                                              int n0c, int cn, const int* __restrict__ flagp,
                                              void* __restrict__ outRaw,
                                              u16* __restrict__ o)
{
  const int bh = blockIdx.y;
  const int b = bh / H_, hh = bh - b * H_;
  const int t = threadIdx.x;
  const int f32o = flagp[0];
  __shared__ float aS[64][17];
  const int nl = t >> 2, qi = t & 3;
  const int ln = blockIdx.x * 64 + nl;
  const bool act = ln < cn;
  const int n = n0c + ln;
  float q[64];
  if (act) {
    const float* qr = q2c + ((size_t)bh * cn + ln) * 64;
    #pragma unroll
    for (int j = 0; j < 64; ++j) q[j] = qr[j];
    float lg[4];
    #pragma unroll
    for (int ff = 0; ff < 4; ++ff) {
      const int f = qi * 4 + ff;
      const u16* kp = k2c + (((size_t)bh * cn + ln) * F_ + f) * 64;
      float s = 0.f;
      #pragma unroll
      for (int j8 = 0; j8 < 8; ++j8) {
        uint4 pk = ((const uint4*)kp)[j8];
        const u16* pu = (const u16*)&pk;
        #pragma unroll
        for (int u = 0; u < 8; ++u) s += q[j8 * 8 + u] * b2f(pu[u]);
      }
      lg[ff] = s;
    }
    float mx = fmaxf(fmaxf(lg[0], lg[1]), fmaxf(lg[2], lg[3]));
    mx = fmaxf(mx, __shfl_xor(mx, 1));
    mx = fmaxf(mx, __shfl_xor(mx, 2));
    float e[4], sm = 0.f;
    #pragma unroll
    for (int ff = 0; ff < 4; ++ff) { e[ff] = __expf(lg[ff] - mx); sm += e[ff]; }
    sm += __shfl_xor(sm, 1);
    sm += __shfl_xor(sm, 2);
    const float iv = 1.0f / sm;
    const size_t abase = ((size_t)bh * N_ + n) * F_ + qi * 4;
    #pragma unroll
    for (int ff = 0; ff < 4; ++ff) {
      const float a = e[ff] * iv;
      if (f32o) ((float*)outRaw)[OUTPART_ + abase + ff] = a;
      else      ((u16*)outRaw)[OUTPART_ + abase + ff] = f2b(a);
      aS[nl][qi * 4 + ff] = a;
    }
  }
  __syncthreads();
  if (act) {
    const int dd0 = qi * 16;
    float acc[16];
    #pragma unroll
    for (int u = 0; u < 16; ++u) acc[u] = 0.f;
    for (int f = 0; f < F_; ++f) {
      const float w2 = aS[nl][f];
      const u16* vp = v2c + (((size_t)bh * cn + ln) * F_ + f) * 64 + dd0;
      uint4 pv0 = ((const uint4*)vp)[0], pv1 = ((const uint4*)vp)[1];
      const u16* pu0 = (const u16*)&pv0;
      const u16* pu1 = (const u16*)&pv1;
      #pragma unroll
      for (int u = 0; u < 8; ++u) acc[u] += w2 * b2f(pu0[u]);
      #pragma unroll
      for (int u = 0; u < 8; ++u) acc[8 + u] += w2 * b2f(pu1[u]);
    }
    u16* op = o + ((size_t)(b * N_ + n)) * C_ + hh * 64 + dd0;
    for (int u = 0; u < 16; ++u) op[u] = f2b(acc[u]);
  }
}

extern "C" void kernel_launch(void* const* d_in, const int* in_sizes, int n_in,
                              void* d_out, int out_size, void* d_ws, size_t ws_size,
                              hipStream_t stream)
{
  (void)in_sizes; (void)n_in; (void)out_size;
  const void* x     = d_in[0];
  const void* Wqkv  = d_in[1];
  const void* Wpq   = d_in[2];
  const void* Wpkv  = d_in[3];
  const void* Wproj = d_in[4];
  const void* bproj = d_in[5];
  (void)Wpq;

  char* ws = (char*)d_ws;
  size_t off = 0;
  auto alloc = [&](size_t bytes) { void* p = ws + off; off += (bytes + 255) & ~(size_t)255; return p; };
  int*  flagp = (int*)alloc(256);
  u16*  qb  = (u16*)alloc(9633792);     // (bh,N,64) bf16, scaled
  u16*  kb  = (u16*)alloc(9633792);     // scaled
  u16*  vb  = (u16*)alloc(9633792);
  float* lm = (float*)alloc(786432);    // (bh,128,64) f32
  u16*  x1b = (u16*)alloc(6291456);     // (bh,128,16,64) bf16
  u16*  ob  = (u16*)alloc(9633792);     // (B,N,C) bf16
  const size_t k1off = off;             // qT f32 starts here (aliases k1b + chunk region)
  u16*  k1b = (u16*)alloc(19267584);    // (bh,N,128) bf16
  const size_t chunk0 = off;

  // qT (selection f32, transposed [bh][64][N]) needs 19,267,584 B at k1off;
  // dead before k1b & chunk region live
  const size_t qtNeed = k1off + 19267584 + 256;

  int Nc = 0;
  {
    const int cands[5] = {3136, 1568, 784, 392, 196};
    for (int i = 0; i < 5; ++i) {
      size_t need = chunk0 + (size_t)156672 * cands[i] + 1024;
      if (need <= ws_size && qtNeed <= ws_size) { Nc = cands[i]; break; }
    }
  }
  if (Nc == 0) return;  // ws floor ~95.7 MB
  const int nchunks = N_ / Nc;
  u16*  xoc = (u16*)(ws + chunk0);                // (B,Nc,F,C) bf16
  u16*  k2c = xoc + (size_t)24576 * Nc;           // (B,h,Nc,F,d) bf16
  u16*  v2c = k2c + (size_t)24576 * Nc;
  u16*  xdc = v2c + (size_t)24576 * Nc;           // (B,Nc,C) bf16
  float* q2c = (float*)(xdc + (size_t)1536 * Nc); // (B,h,Nc,d) f32
  float* qt  = (float*)(ws + k1off);              // selection-grade f32 qT (dead before k1_k)

  // landmark candidate slots: 24 heads x 16 u64 (2 parity x 8 blocks) = 3KB,
  // in chunk region (dead until chunk loop); 128B-aligned per head.
  u64* cand = (u64*)(ws + chunk0);

  // dtype sniff on W_qkv; zero candidate slots (every launch, replay-safe)
  detect_k<<<1, 64, 0, stream>>>((const u32*)Wqkv, flagp);
  zcnt_k<<<1, 512, 0, stream>>>(cand);

  // selection-grade f32 qT (transposed), then fence-free multi-block landmarks
  qselT_k<<<dim3(98, 12), 256, 0, stream>>>(x, Wqkv, flagp, qt);
  landmarksP_k<<<dim3(KB_, 24), 512, 0, stream>>>(qt, lm, cand);

  // qkv projection -> qb,kb,vb (bf16 smooth path)
  gemm_k<0><<<dim3(49, 18, 1), 256, 0, stream>>>(x, Wqkv, 6272, 768, 768, 2304, 0, 0, flagp,
                                                 nullptr, qb, kb, vb, nullptr, nullptr);
  // kernel_2 + x1 (LDS-only)
  k2x1_k<<<dim3(24, 16), 256, 0, stream>>>(lm, kb, vb, x1b);
  // kernel_1 (overwrites qT region — qT dead)
  k1_k<<<dim3(49, 24), 256, 0, stream>>>(qb, lm, k1b);

  for (int c = 0; c < nchunks; ++c) {
    const int n0c = c * Nc;
    gemm_k<1><<<dim3((Nc + 127) / 128, 8, 24), 256, 0, stream>>>(
        k1b, x1b, Nc, 128, 128, 1024, n0c, Nc, flagp, nullptr, xoc, xdc, nullptr, nullptr, nullptr);
    gemm_k<2><<<dim3((2 * Nc * 16) / 128, 12, 1), 256, 0, stream>>>(
        xoc, Wpkv, 2 * Nc * 16, 768, 768, 1536, n0c, Nc, flagp, nullptr, k2c, v2c, nullptr, nullptr, nullptr);
    gemm_k<3><<<dim3((2 * Nc + 127) / 128, 6, 1), 256, 0, stream>>>(
        xdc, d_in[2], 2 * Nc, 768, 768, 768, n0c, Nc, flagp, q2c, nullptr, nullptr, nullptr, nullptr, nullptr);
    attn_k<<<dim3((Nc + 63) / 64, 24), 256, 0, stream>>>(
        q2c, k2c, v2c, n0c, Nc, flagp, d_out, ob);
  }
  // out = o @ W_proj + b_proj
  gemm_k<4><<<dim3(49, 6, 1), 256, 0, stream>>>(ob, Wproj, 6272, 768, 768, 768, 0, 0, flagp,
                                                nullptr, nullptr, nullptr, nullptr, bproj, d_out);
}

// Round 3
// 2122.191 us; speedup vs baseline: 1.7340x; 1.1556x over previous
//
#include <hip/hip_runtime.h>

// TrajectoryAttention on MI355X (gfx950), chunked pipeline, dtype-adaptive.
// R11: landmarks qT slice pinned in REGISTERS. R10's counters showed 6.2us/step
//   = per-step re-stream of each block's 100KB qT slice from L3/HBM (FETCH
//   224MB, eff. 290GB/s, latency-bound at 1 block/CU) -- L2 does not retain
//   the slice across steps. Fix: each thread loads its 16 float4 (64 floats)
//   ONCE into qreg[16] (fully unrolled -> VGPRs, ~130 total, still 8 waves/CU).
//   Norms + per-step dots run from registers, bit-identical arithmetic/order.
//   Remaining per-step traffic: 1 packed-u64 candidate store + 8-slot poll +
//   64-lane winner-column gather (qT 19.3MB = L3-resident).
// R10 (kept): fence-free cross-block sync via relaxed agent-scope atomics;
//   packed u64 = [63:19] f64 max_sim | [18:12] step tag | [11:0] row idx;
//   parity double-buffer; winner norm recomputed via t<64 butterfly.
// R9 (kept): 8 blocks/head, quad-split f64 dots (numerics proven).
// R8 (kept): qselT_k f32 GEMM -> transposed qT[bh][d][n]; coalesced reads.
// R7 (kept): partitionable threefry idx0; bf16 MFMA smooth path; chunked k2/v2.

using u16 = unsigned short;
using u32 = unsigned int;
using u64 = unsigned long long;

typedef short bf16x8 __attribute__((ext_vector_type(8)));
typedef float f32x4 __attribute__((ext_vector_type(4)));

#define N_ 3136
#define C_ 768
#define H_ 12
#define F_ 16
#define P_ 196
#define L_ 128
#define SC_ 0.35355339059327373f   // 64^-0.25
#define OUTPART_ ((size_t)2 * N_ * C_)
#define KB_ 8                      // blocks per head in landmarks
#define RPB_ 392                   // rows per block (3136/8)

__device__ __forceinline__ float b2f(u16 u) {
  u32 x = ((u32)u) << 16; float f; __builtin_memcpy(&f, &x, 4); return f;
}
__device__ __forceinline__ float lo16f(u32 u) {
  u32 x = u << 16; float f; __builtin_memcpy(&f, &x, 4); return f;
}
__device__ __forceinline__ float hi16f(u32 u) {
  u32 x = u & 0xFFFF0000u; float f; __builtin_memcpy(&f, &x, 4); return f;
}
__device__ __forceinline__ u16 f2b(float f) {
  u32 u; __builtin_memcpy(&u, &f, 4);
  u32 r = (u + 0x7FFFu + ((u >> 16) & 1u)) >> 16;
  return (u16)r;
}
__device__ __forceinline__ u64 d2u(double d) { u64 u; __builtin_memcpy(&u, &d, 8); return u; }

// load 16 contiguous logical elements as bf16 uint4 pair, from raw input of either dtype
__device__ __forceinline__ void ld16bf(const void* base, size_t elemOff, int isF32,
                                       uint4& o0, uint4& o1) {
  if (isF32) {
    const float4* p = (const float4*)((const float*)base + elemOff);
    float4 f0 = p[0], f1 = p[1], f2v = p[2], f3 = p[3];
    u16 tmp[16] = { f2b(f0.x), f2b(f0.y), f2b(f0.z), f2b(f0.w),
                    f2b(f1.x), f2b(f1.y), f2b(f1.z), f2b(f1.w),
                    f2b(f2v.x), f2b(f2v.y), f2b(f2v.z), f2b(f2v.w),
                    f2b(f3.x), f2b(f3.y), f2b(f3.z), f2b(f3.w) };
    __builtin_memcpy(&o0, tmp, 16);
    __builtin_memcpy(&o1, tmp + 8, 16);
  } else {
    const uint4* p = (const uint4*)((const u16*)base + elemOff);
    o0 = p[0]; o1 = p[1];
  }
}

// dtype sniffer (bf16 vs f32 inputs) — votes f32 on this dataset (proven R4)
__global__ void detect_k(const u32* __restrict__ w, int* __restrict__ flag) {
  const int t = threadIdx.x;  // 64
  int hits = 0;
  #pragma unroll
  for (int i = 0; i < 16; ++i) {
    u32 word = w[t * 16 + i];
    u32 e = (word >> 7) & 0xFFu;
    if (e >= 110u && e <= 126u) hits++;
  }
  #pragma unroll
  for (int off = 32; off > 0; off >>= 1) hits += __shfl_down(hits, off);
  if (t == 0) flag[0] = (hits >= 512) ? 0 : 1;  // 0=bf16, 1=f32
}

// zero candidate slots (24 heads x 2 parity x 8 blocks = 384 u64).
// Re-run every launch: graph-replay safe. tag field 0 != any step (1..127).
__global__ void zcnt_k(u64* __restrict__ p) { if (threadIdx.x < 384) p[threadIdx.x] = 0ull; }

// ---- exact JAX threefry2x32-20 core ----
__device__ __forceinline__ void tf2(u32 k0, u32 k1v, u32 c0, u32 c1, u32& o0, u32& o1) {
  u32 ks[3] = {k0, k1v, k0 ^ k1v ^ 0x1BD11BDAu};
  u32 x0 = c0 + ks[0], x1 = c1 + ks[1];
  const u32 rA[4] = {13u, 15u, 26u, 6u}, rB[4] = {17u, 29u, 16u, 24u};
  #pragma unroll
  for (int r = 0; r < 5; ++r) {
    #pragma unroll
    for (int q = 0; q < 4; ++q) {
      u32 rot = (r & 1) ? rB[q] : rA[q];
      x0 += x1; x1 = (x1 << rot) | (x1 >> (32u - rot)); x1 ^= x0;
    }
    x0 += ks[(r + 1) % 3];
    x1 += ks[(r + 2) % 3] + (u32)(r + 1);
  }
  o0 = x0; o1 = x1;
}

// jax.random.randint(key(42), (24,), 0, 3136) under jax_threefry_partitionable=True
// — PROVEN correct on this dataset (R7 passed at smooth-path floor).
__device__ __forceinline__ int tf_idx0(int bh) {
  u32 a0, a1, b0, b1;
  tf2(0u, 42u, 0u, 0u, a0, a1);   // k1 = subkey 0
  tf2(0u, 42u, 0u, 1u, b0, b1);   // k2 = subkey 1
  u32 j = (u32)bh;
  u32 h0, h1, l0, l1;
  tf2(a0, a1, 0u, j, h0, h1);     // higher_bits[j]
  u32 hi = h0 ^ h1;
  tf2(b0, b1, 0u, j, l0, l1);     // lower_bits[j]
  u32 lo = l0 ^ l1;
  return (int)(((hi % 3136u) * 2048u + (lo % 3136u)) % 3136u);
}

// ---------------- selection-grade f32 GEMM -> TRANSPOSED qT[bh][d][n] ----------------
__global__ __launch_bounds__(256) void qselT_k(const void* __restrict__ xr, const void* __restrict__ wr,
                                               const int* __restrict__ flagp, float* __restrict__ qt)
{
  __shared__ float As[64 * 20];
  __shared__ float Bs[16 * 64];
  const int t = threadIdx.x;
  const int m0 = blockIdx.x * 64;
  const int n0 = blockIdx.y * 64;
  const int f32i = flagp[0];
  const int tx = t & 15, ty = t >> 4;
  float acc[4][4];
  #pragma unroll
  for (int i = 0; i < 4; ++i)
    #pragma unroll
    for (int j = 0; j < 4; ++j) acc[i][j] = 0.f;

  const int alr = t >> 2;               // A tile row (0..63)
  const int alk = (t & 3) * 4;          // A k offset
  const int bkr = t >> 4;               // B k row (0..15)
  const int bnc = (t & 15) * 4;         // B col offset

  for (int k0 = 0; k0 < 768; k0 += 16) {
    float4 av, bv;
    if (f32i) {
      av = *(const float4*)((const float*)xr + (size_t)(m0 + alr) * 768 + k0 + alk);
      bv = *(const float4*)((const float*)wr + (size_t)(k0 + bkr) * 2304 + n0 + bnc);
    } else {
      const u16* xa = (const u16*)xr + (size_t)(m0 + alr) * 768 + k0 + alk;
      const u16* wa = (const u16*)wr + (size_t)(k0 + bkr) * 2304 + n0 + bnc;
      av.x = b2f(xa[0]); av.y = b2f(xa[1]); av.z = b2f(xa[2]); av.w = b2f(xa[3]);
      bv.x = b2f(wa[0]); bv.y = b2f(wa[1]); bv.z = b2f(wa[2]); bv.w = b2f(wa[3]);
    }
    As[alr * 20 + alk + 0] = av.x; As[alr * 20 + alk + 1] = av.y;
    As[alr * 20 + alk + 2] = av.z; As[alr * 20 + alk + 3] = av.w;
    *(float4*)(&Bs[bkr * 64 + bnc]) = bv;
    __syncthreads();
    #pragma unroll
    for (int kk = 0; kk < 16; ++kk) {
      float a[4], b[4];
      #pragma unroll
      for (int i = 0; i < 4; ++i) a[i] = As[(ty * 4 + i) * 20 + kk];
      #pragma unroll
      for (int j = 0; j < 4; ++j) b[j] = Bs[kk * 64 + tx * 4 + j];
      #pragma unroll
      for (int i = 0; i < 4; ++i)
        #pragma unroll
        for (int j = 0; j < 4; ++j) acc[i][j] += a[i] * b[j];
    }
    __syncthreads();
  }
  #pragma unroll
  for (int i = 0; i < 4; ++i) {
    const int m = m0 + ty * 4 + i;
    const int b = m / N_, n = m - b * N_;
    #pragma unroll
    for (int j = 0; j < 4; ++j) {
      const int col = n0 + tx * 4 + j;
      const int hh = col >> 6, dd = col & 63;
      qt[((size_t)(b * H_ + hh) * 64 + dd) * N_ + n] = acc[i][j] * SC_;
    }
  }
}

// ---------------- greedy landmarks: 8 blocks/head, register-resident slice ----------------
// Block kb owns rows [kb*392, kb*392+392). Thread t<392 holds its 16 float4
// (cols 4g..4g+3, d-plane dc*16..dc*16+15) in qreg[16] -- loaded ONCE, all
// per-step dots run from VGPRs (bit-identical to the R9/R10 memory path).
// Cross-block sync (R10-proven): packed u64 relaxed agent atomics, no fences;
// wave 0 polls the 8 parity-buffered slots until all tags == step.
__global__ __launch_bounds__(512, 1) void landmarksR_k(
    const float* __restrict__ qt, float* __restrict__ lm, u64* __restrict__ cand)
{
  const int kb = blockIdx.x;
  const int bh = blockIdx.y;
  const float* QT = qt + (size_t)bh * 64 * N_;   // [d][n]
  float* LM = lm + (size_t)bh * L_ * 64;
  u64* cd = cand + (size_t)bh * 16;              // 16 u64 = 128B line per head
  __shared__ double curD[64];
  __shared__ u64 redV[8];
  __shared__ int redI[8];
  __shared__ int sW;
  const int t = threadIdx.x;
  const bool act = (t < RPB_);                   // 392 active (quad-aligned)
  const int g = t >> 2, dc = t & 3, d0 = dc * 16;
  const int r0 = kb * RPB_;
  const int myRow = r0 + t;                      // owned row (act only)
  const float* base = QT + r0 + 4 * g;

  // pin the slice: 16 float4 per thread, loaded once (same addresses as R10)
  float4 qreg[16];
  #pragma unroll
  for (int i = 0; i < 16; ++i) qreg[i] = (float4){0.f, 0.f, 0.f, 0.f};
  if (act) {
    #pragma unroll
    for (int i = 0; i < 16; ++i) qreg[i] = *(const float4*)(base + (size_t)(d0 + i) * N_);
  }

  // norms (f64 from f32 data): quad-split over d, butterfly combine (R9-proven order)
  double inv_own = 0.0, ms_own = 0.0;
  if (act) {
    double s0 = 0.0, s1 = 0.0, s2 = 0.0, s3 = 0.0;
    #pragma unroll
    for (int i = 0; i < 16; ++i) {
      const float4 v = qreg[i];
      s0 += (double)v.x * (double)v.x; s1 += (double)v.y * (double)v.y;
      s2 += (double)v.z * (double)v.z; s3 += (double)v.w * (double)v.w;
    }
    s0 += __shfl_xor(s0, 1); s1 += __shfl_xor(s1, 1);
    s2 += __shfl_xor(s2, 1); s3 += __shfl_xor(s3, 1);
    s0 += __shfl_xor(s0, 2); s1 += __shfl_xor(s1, 2);
    s2 += __shfl_xor(s2, 2); s3 += __shfl_xor(s3, 2);
    const double sown = (dc == 0) ? s0 : (dc == 1) ? s1 : (dc == 2) ? s2 : s3;
    inv_own = 1.0 / fmax(sqrt(sown), 1e-12);
  }
  const int idx0 = tf_idx0(bh);
  if (act && myRow == idx0) ms_own = 10.0;

  // initial direction: winner-column norm recomputed locally (R8's exact math)
  if (t < 64) {
    const float vf = QT[(size_t)t * N_ + idx0];
    double v = (double)vf;
    double s = v * v;
    #pragma unroll
    for (int off = 32; off; off >>= 1) s += __shfl_xor(s, off);
    curD[t] = v / fmax(sqrt(s), 1e-12);
    if (kb == 0) LM[t] = vf;
  }
  __syncthreads();

  for (int step = 1; step < 128; ++step) {
    u64 bV = d2u(1e30); int bI = 0x7fffffff;
    if (act) {
      double a0 = 0.0, a1 = 0.0, a2 = 0.0, a3 = 0.0;
      #pragma unroll
      for (int i = 0; i < 16; ++i) {
        const float4 v = qreg[i];
        const double c = curD[d0 + i];
        a0 += (double)v.x * c; a1 += (double)v.y * c;
        a2 += (double)v.z * c; a3 += (double)v.w * c;
      }
      a0 += __shfl_xor(a0, 1); a1 += __shfl_xor(a1, 1);
      a2 += __shfl_xor(a2, 1); a3 += __shfl_xor(a3, 1);
      a0 += __shfl_xor(a0, 2); a1 += __shfl_xor(a1, 2);
      a2 += __shfl_xor(a2, 2); a3 += __shfl_xor(a3, 2);
      const double aown = (dc == 0) ? a0 : (dc == 1) ? a1 : (dc == 2) ? a2 : a3;
      ms_own = fmax(ms_own, fabs(aown * inv_own));
      bV = d2u(ms_own); bI = myRow;   // nonneg doubles: bit order == numeric order
    }
    // wave argmin (val, then lowest idx)
    #pragma unroll
    for (int off = 32; off; off >>= 1) {
      const u64 ov = __shfl_xor(bV, off);
      const int oi = __shfl_xor(bI, off);
      if (ov < bV || (ov == bV && oi < bI)) { bV = ov; bI = oi; }
    }
    if ((t & 63) == 0) { redV[t >> 6] = bV; redI[t >> 6] = bI; }
    __syncthreads();
    const int par = step & 1;
    if (t == 0) {
      u64 v = redV[0]; int ix = redI[0];
      #pragma unroll
      for (int w2 = 1; w2 < 8; ++w2)
        if (redV[w2] < v || (redV[w2] == v && redI[w2] < ix)) { v = redV[w2]; ix = redI[w2]; }
      const u64 pk = (v & ~((1ull << 19) - 1ull)) | ((u64)(u32)(step & 127) << 12) | (u64)(u32)ix;
      __hip_atomic_store(&cd[par * KB_ + kb], pk, __ATOMIC_RELAXED, __HIP_MEMORY_SCOPE_AGENT);
    }
    // fence-free barrier: wave 0 polls the 8 slots (cache-bypassing loads)
    if (t < 64) {
      u64 pv = ~0ull;
      int ok = 1;
      for (;;) {
        if (t < KB_) {
          pv = __hip_atomic_load(&cd[par * KB_ + t], __ATOMIC_RELAXED, __HIP_MEMORY_SCOPE_AGENT);
          ok = ((int)((pv >> 12) & 127u) == step) ? 1 : 0;
        }
        if (__all(ok)) break;
        __builtin_amdgcn_s_sleep(1);
      }
      u64 m = (t < KB_) ? pv : ~0ull;
      #pragma unroll
      for (int off = 1; off < KB_; off <<= 1) {
        const u64 o = __shfl_xor(m, off);
        if (o < m) m = o;
      }
      if (t == 0) sW = (int)(m & 0xFFFu);
    }
    __syncthreads();
    const int w = sW;
    if (act && myRow == w) ms_own = 10.0;
    if (t < 64) {
      const float vf = QT[(size_t)t * N_ + w];
      double v = (double)vf;
      double s = v * v;
      #pragma unroll
      for (int off = 32; off; off >>= 1) s += __shfl_xor(s, off);
      curD[t] = v / fmax(sqrt(s), 1e-12);
      if (kb == 0) LM[(size_t)step * 64 + t] = vf;
    }
    __syncthreads();
  }
}

// ---------------- generic 128x128 bf16 MFMA GEMM, per-mode epilogues ----------------
template <int MODE>
__global__ __launch_bounds__(256) void gemm_k(
    const void* __restrict__ Ap, const void* __restrict__ Bp,
    int M, int K, int lda, int ldb, int n0c, int cn, const int* __restrict__ flagp,
    float* __restrict__ of0, u16* __restrict__ ob0, u16* __restrict__ ob1, u16* __restrict__ ob2,
    const void* __restrict__ biasRaw, void* __restrict__ outRaw)
{
  constexpr bool A_RAW = (MODE == 0);
  constexpr bool B_RAW = (MODE == 0 || MODE >= 2);
  __shared__ u16 As[128 * 40];
  __shared__ u16 Bs[128 * 40];
  const int t = threadIdx.x;
  const int m0 = blockIdx.x * 128;
  const int n0 = blockIdx.y * 128;
  const int rf = (A_RAW || B_RAW) ? flagp[0] : 0;
  const int aF32 = A_RAW ? rf : 0;
  const int bF32 = B_RAW ? rf : 0;

  size_t aOff = 0, bOff = 0;
  if constexpr (MODE == 1) {
    const int bh = blockIdx.z;
    aOff = (size_t)bh * ((size_t)N_ * 128) + (size_t)n0c * 128;
    bOff = (size_t)bh * (128 * 1024);
  }
  const int lane = t & 63;
  const int w = t >> 6;
  const int mw = (w >> 1) * 64;
  const int nw = (w & 1) * 64;
  const int lr = lane & 15;
  const int lk = lane >> 4;

  f32x4 acc[4][4];
  #pragma unroll
  for (int i = 0; i < 4; ++i)
    #pragma unroll
    for (int j = 0; j < 4; ++j) acc[i][j] = (f32x4){0.f, 0.f, 0.f, 0.f};

  const int ar = t >> 1;
  const int ak = (t & 1) * 16;
  const int bk = t & 31;
  const int bn = (t >> 5) * 16;
  const int agrow = m0 + ar;
  const bool aValid = (agrow < M);

  for (int k0 = 0; k0 < K; k0 += 32) {
    uint4 a0, a1;
    if (aValid) {
      ld16bf(Ap, aOff + (size_t)agrow * lda + k0 + ak, aF32, a0, a1);
    } else {
      a0.x = a0.y = a0.z = a0.w = 0u; a1 = a0;
    }
    uint4 b0, b1;
    ld16bf(Bp, bOff + (size_t)(k0 + bk) * ldb + n0 + bn, bF32, b0, b1);

    *(uint4*)(&As[ar * 40 + ak]) = a0;
    *(uint4*)(&As[ar * 40 + ak + 8]) = a1;
    u16 tmp[16];
    *(uint4*)(tmp) = b0;
    *(uint4*)(tmp + 8) = b1;
    #pragma unroll
    for (int j = 0; j < 16; ++j) Bs[(bn + j) * 40 + bk] = tmp[j];  // Bs[n][k]
    __syncthreads();

    bf16x8 af[4], bfv[4];
    #pragma unroll
    for (int mt = 0; mt < 4; ++mt)
      af[mt] = *(const bf16x8*)(&As[(mw + mt * 16 + lr) * 40 + lk * 8]);
    #pragma unroll
    for (int nt = 0; nt < 4; ++nt)
      bfv[nt] = *(const bf16x8*)(&Bs[(nw + nt * 16 + lr) * 40 + lk * 8]);
    #pragma unroll
    for (int mt = 0; mt < 4; ++mt)
      #pragma unroll
      for (int nt = 0; nt < 4; ++nt)
        acc[mt][nt] = __builtin_amdgcn_mfma_f32_16x16x32_bf16(af[mt], bfv[nt], acc[mt][nt], 0, 0, 0);
    __syncthreads();
  }

  #pragma unroll
  for (int mt = 0; mt < 4; ++mt) {
    #pragma unroll
    for (int nt = 0; nt < 4; ++nt) {
      #pragma unroll
      for (int r = 0; r < 4; ++r) {
        const int grow = m0 + mw + mt * 16 + lk * 4 + r;
        const int gcol = n0 + nw + nt * 16 + lr;
        if (grow >= M) continue;
        float vv = acc[mt][nt][r];
        if constexpr (MODE == 0) {           // qkv -> qb,kb,vb bf16 (bh,N,64)
          int b = (grow >= N_) ? 1 : 0;
          int n = grow - b * N_;
          int t3 = gcol / C_, cc = gcol - t3 * C_;
          int hh = cc >> 6, dd = cc & 63;
          size_t dst = (((size_t)(b * H_ + hh)) * N_ + n) * 64 + dd;
          if (t3 == 0) ob0[dst] = f2b(vv * SC_);
          else if (t3 == 1) ob1[dst] = f2b(vv * SC_);
          else ob2[dst] = f2b(vv);
        } else if constexpr (MODE == 1) {    // xoc (B,cn,F,C) bf16 + xdiag side-write
          const int bh = blockIdx.z;
          int b = bh / H_, hh = bh - b * H_;
          int f = gcol >> 6, dd = gcol & 63;
          u16 wv = f2b(vv);
          ob0[(((size_t)(b * cn + grow)) * F_ + f) * C_ + hh * 64 + dd] = wv;
          int n = n0c + grow;
          if (f == n / P_) ob1[((size_t)(b * cn + grow)) * C_ + hh * 64 + dd] = wv;
        } else if constexpr (MODE == 2) {    // k2c,v2c (B,h,cn,F,d) bf16
          const int cn16 = cn * F_;
          int b = (grow >= cn16) ? 1 : 0;
          int r2 = grow - b * cn16;
          int ln = r2 >> 4, f = r2 & 15;
          int t2 = (gcol >= C_) ? 1 : 0, cc = gcol - t2 * C_;
          int hh = cc >> 6, dd = cc & 63;
          size_t dst = ((((size_t)(b * H_ + hh)) * cn + ln) * F_ + f) * 64 + dd;
          if (t2) ob1[dst] = f2b(vv); else ob0[dst] = f2b(vv);
        } else if constexpr (MODE == 3) {    // q2c (B,h,cn,d) f32, * 0.125
          int b = (grow >= cn) ? 1 : 0;
          int ln = grow - b * cn;
          int hh = gcol >> 6, dd = gcol & 63;
          of0[(((size_t)(b * H_ + hh)) * cn + ln) * 64 + dd] = vv * 0.125f;
        } else {                             // out = o@W_proj + b_proj, flag dtype
          float bvad = bF32 ? ((const float*)biasRaw)[gcol] : b2f(((const u16*)biasRaw)[gcol]);
          float ov = vv + bvad;
          if (bF32) ((float*)outRaw)[(size_t)grow * C_ + gcol] = ov;
          else      ((u16*)outRaw)[(size_t)grow * C_ + gcol] = f2b(ov);
        }
      }
    }
  }
}

// ---------------- kernel_1 = softmax_l(q . lm^T), bf16 out ----------------
__global__ __launch_bounds__(256) void k1_k(const u16* __restrict__ qb,
                                            const float* __restrict__ lm,
                                            u16* __restrict__ k1)
{
  const int bh = blockIdx.y;
  const int r0 = blockIdx.x * 64;
  __shared__ float qT[64][65];
  __shared__ float lmS[128 * 64];
  __shared__ float redA[4][64];
  __shared__ float redB[64];
  const int t = threadIdx.x;
  const u16* Q = qb + ((size_t)bh * N_ + r0) * 64;
  const float* Lm = lm + (size_t)bh * L_ * 64;
  for (int u = t; u < 2048; u += 256) ((float4*)lmS)[u] = ((const float4*)Lm)[u];
  for (int u = t; u < 512; u += 256) {
    int row = u >> 3, j0 = (u & 7) * 8;
    uint4 pk = *(const uint4*)(Q + (size_t)row * 64 + j0);
    const u16* pu = (const u16*)&pk;
    #pragma unroll
    for (int jj = 0; jj < 8; ++jj) qT[j0 + jj][row] = b2f(pu[jj]);
  }
  __syncthreads();
  const int row = t & 63, ch = t >> 6;
  float qr[64];
  #pragma unroll
  for (int j = 0; j < 64; ++j) qr[j] = qT[j][row];
  float s[32];
  for (int li = 0; li < 32; ++li) {
    const float* lp = lmS + (ch * 32 + li) * 64;
    float a = 0.f;
    #pragma unroll
    for (int j = 0; j < 64; ++j) a += lp[j] * qr[j];
    s[li] = a;
  }
  float mx = -1e30f;
  for (int li = 0; li < 32; ++li) mx = fmaxf(mx, s[li]);
  redA[ch][row] = mx;
  __syncthreads();
  if (t < 64) redB[t] = fmaxf(fmaxf(redA[0][t], redA[1][t]), fmaxf(redA[2][t], redA[3][t]));
  __syncthreads();
  mx = redB[row];
  float sum = 0.f;
  for (int li = 0; li < 32; ++li) { float e = __expf(s[li] - mx); s[li] = e; sum += e; }
  __syncthreads();
  redA[ch][row] = sum;
  __syncthreads();
  if (t < 64) redB[t] = 1.0f / (redA[0][t] + redA[1][t] + redA[2][t] + redA[3][t]);
  __syncthreads();
  const float inv = redB[row];
  u16* out = k1 + ((size_t)bh * N_ + r0 + row) * 128 + ch * 32;
  for (int li = 0; li < 32; ++li) out[li] = f2b(s[li] * inv);
}

// ---------------- kernel_2 per frame + x1 = kernel_2 @ v  (LDS-only, 3-pass) ----------------
__global__ __launch_bounds__(256) void k2x1_k(const float* __restrict__ lm,
                                              const u16* __restrict__ kb,
                                              const u16* __restrict__ vb,
                                              u16* __restrict__ x1)
{
  const int bh = blockIdx.x;
  const int f = blockIdx.y;
  __shared__ u16 kS[P_ * 64];
  __shared__ u16 vS[P_ * 64];
  __shared__ float redM[2][128];
  __shared__ float redS[2][128];
  const int t = threadIdx.x;
  const u16* Kf = kb + ((size_t)bh * N_ + f * P_) * 64;
  const u16* Vf = vb + ((size_t)bh * N_ + f * P_) * 64;
  for (int u = t; u < 1568; u += 256) {
    ((uint4*)kS)[u] = ((const uint4*)Kf)[u];
    ((uint4*)vS)[u] = ((const uint4*)Vf)[u];
  }
  __syncthreads();
  const int l = t & 127, half = t >> 7;
  const float* lp = lm + ((size_t)bh * L_ + l) * 64;
  float lr[64];
  #pragma unroll
  for (int j = 0; j < 64; ++j) lr[j] = lp[j];

  const int p0 = half * 98, p1 = p0 + 98;
  float mx = -1e30f;
  for (int p = p0; p < p1; ++p) {
    const uint4* kp = (const uint4*)(kS + p * 64);
    float s = 0.f;
    #pragma unroll
    for (int q4 = 0; q4 < 8; ++q4) {
      uint4 pk = kp[q4];
      const u32* pu = (const u32*)&pk;
      #pragma unroll
      for (int j2 = 0; j2 < 4; ++j2) {
        u32 u = pu[j2];
        s += lr[q4 * 8 + j2 * 2] * lo16f(u) + lr[q4 * 8 + j2 * 2 + 1] * hi16f(u);
      }
    }
    mx = fmaxf(mx, s);
  }
  redM[half][l] = mx;
  __syncthreads();
  mx = fmaxf(redM[0][l], redM[1][l]);

  float sm = 0.f;
  for (int p = p0; p < p1; ++p) {
    const uint4* kp = (const uint4*)(kS + p * 64);
    float s = 0.f;
    #pragma unroll
    for (int q4 = 0; q4 < 8; ++q4) {
      uint4 pk = kp[q4];
      const u32* pu = (const u32*)&pk;
      #pragma unroll
      for (int j2 = 0; j2 < 4; ++j2) {
        u32 u = pu[j2];
        s += lr[q4 * 8 + j2 * 2] * lo16f(u) + lr[q4 * 8 + j2 * 2 + 1] * hi16f(u);
      }
    }
    sm += __expf(s - mx);
  }
  redS[half][l] = sm;
  __syncthreads();
  const float inv = 1.0f / (redS[0][l] + redS[1][l]);

  const int dd0 = half * 32;
  float acc[32];
  #pragma unroll
  for (int u = 0; u < 32; ++u) acc[u] = 0.f;
  for (int p = 0; p < P_; ++p) {
    const uint4* kp = (const uint4*)(kS + p * 64);
    float s = 0.f;
    #pragma unroll
    for (int q4 = 0; q4 < 8; ++q4) {
      uint4 pk = kp[q4];
      const u32* pu = (const u32*)&pk;
      #pragma unroll
      for (int j2 = 0; j2 < 4; ++j2) {
        u32 u = pu[j2];
        s += lr[q4 * 8 + j2 * 2] * lo16f(u) + lr[q4 * 8 + j2 * 2 + 1] * hi16f(u);
      }
    }
    const float e = __expf(s - mx);
    const uint4* vp = (const uint4*)(vS + p * 64 + dd0);
    #pragma unroll
    for (int q4 = 0; q4 < 4; ++q4) {
      uint4 pv = vp[q4];
      const u32* pu = (const u32*)&pv;
      #pragma unroll
      for (int j2 = 0; j2 < 4; ++j2) {
        u32 u = pu[j2];
        acc[q4 * 8 + j2 * 2]     += e * lo16f(u);
        acc[q4 * 8 + j2 * 2 + 1] += e * hi16f(u);
      }
    }
  }
  u16* out = x1 + (((size_t)bh * L_ + l) * F_ + f) * 64 + dd0;
  for (int u = 0; u < 32; ++u) out[u] = f2b(acc[u] * inv);
}

// ---------------- final 16-way frame attention + o = attn @ v2 (chunked) ----------------
__global__ __launch_bounds__(256) void attn_k(const float* __restrict__ q2c,
                                              const u16* __restrict__ k2c,
                                              const u16* __restrict__ v2c,
                                              int n0c, int cn, const int* __restrict__ flagp,
                                              void* __restrict__ outRaw,
                                              u16* __restrict__ o)
{
  const int bh = blockIdx.y;
  const int b = bh / H_, hh = bh - b * H_;
  const int t = threadIdx.x;
  const int f32o = flagp[0];
  __shared__ float aS[64][17];
  const int nl = t >> 2, qi = t & 3;
  const int ln = blockIdx.x * 64 + nl;
  const bool act = ln < cn;
  const int n = n0c + ln;
  float q[64];
  if (act) {
    const float* qr = q2c + ((size_t)bh * cn + ln) * 64;
    #pragma unroll
    for (int j = 0; j < 64; ++j) q[j] = qr[j];
    float lg[4];
    #pragma unroll
    for (int ff = 0; ff < 4; ++ff) {
      const int f = qi * 4 + ff;
      const u16* kp = k2c + (((size_t)bh * cn + ln) * F_ + f) * 64;
      float s = 0.f;
      #pragma unroll
      for (int j8 = 0; j8 < 8; ++j8) {
        uint4 pk = ((const uint4*)kp)[j8];
        const u16* pu = (const u16*)&pk;
        #pragma unroll
        for (int u = 0; u < 8; ++u) s += q[j8 * 8 + u] * b2f(pu[u]);
      }
      lg[ff] = s;
    }
    float mx = fmaxf(fmaxf(lg[0], lg[1]), fmaxf(lg[2], lg[3]));
    mx = fmaxf(mx, __shfl_xor(mx, 1));
    mx = fmaxf(mx, __shfl_xor(mx, 2));
    float e[4], sm = 0.f;
    #pragma unroll
    for (int ff = 0; ff < 4; ++ff) { e[ff] = __expf(lg[ff] - mx); sm += e[ff]; }
    sm += __shfl_xor(sm, 1);
    sm += __shfl_xor(sm, 2);
    const float iv = 1.0f / sm;
    const size_t abase = ((size_t)bh * N_ + n) * F_ + qi * 4;
    #pragma unroll
    for (int ff = 0; ff < 4; ++ff) {
      const float a = e[ff] * iv;
      if (f32o) ((float*)outRaw)[OUTPART_ + abase + ff] = a;
      else      ((u16*)outRaw)[OUTPART_ + abase + ff] = f2b(a);
      aS[nl][qi * 4 + ff] = a;
    }
  }
  __syncthreads();
  if (act) {
    const int dd0 = qi * 16;
    float acc[16];
    #pragma unroll
    for (int u = 0; u < 16; ++u) acc[u] = 0.f;
    for (int f = 0; f < F_; ++f) {
      const float w2 = aS[nl][f];
      const u16* vp = v2c + (((size_t)bh * cn + ln) * F_ + f) * 64 + dd0;
      uint4 pv0 = ((const uint4*)vp)[0], pv1 = ((const uint4*)vp)[1];
      const u16* pu0 = (const u16*)&pv0;
      const u16* pu1 = (const u16*)&pv1;
      #pragma unroll
      for (int u = 0; u < 8; ++u) acc[u] += w2 * b2f(pu0[u]);
      #pragma unroll
      for (int u = 0; u < 8; ++u) acc[8 + u] += w2 * b2f(pu1[u]);
    }
    u16* op = o + ((size_t)(b * N_ + n)) * C_ + hh * 64 + dd0;
    for (int u = 0; u < 16; ++u) op[u] = f2b(acc[u]);
  }
}

extern "C" void kernel_launch(void* const* d_in, const int* in_sizes, int n_in,
                              void* d_out, int out_size, void* d_ws, size_t ws_size,
                              hipStream_t stream)
{
  (void)in_sizes; (void)n_in; (void)out_size;
  const void* x     = d_in[0];
  const void* Wqkv  = d_in[1];
  const void* Wpq   = d_in[2];
  const void* Wpkv  = d_in[3];
  const void* Wproj = d_in[4];
  const void* bproj = d_in[5];
  (void)Wpq;

  char* ws = (char*)d_ws;
  size_t off = 0;
  auto alloc = [&](size_t bytes) { void* p = ws + off; off += (bytes + 255) & ~(size_t)255; return p; };
  int*  flagp = (int*)alloc(256);
  u16*  qb  = (u16*)alloc(9633792);     // (bh,N,64) bf16, scaled
  u16*  kb  = (u16*)alloc(9633792);     // scaled
  u16*  vb  = (u16*)alloc(9633792);
  float* lm = (float*)alloc(786432);    // (bh,128,64) f32
  u16*  x1b = (u16*)alloc(6291456);     // (bh,128,16,64) bf16
  u16*  ob  = (u16*)alloc(9633792);     // (B,N,C) bf16
  const size_t k1off = off;             // qT f32 starts here (aliases k1b + chunk region)
  u16*  k1b = (u16*)alloc(19267584);    // (bh,N,128) bf16
  const size_t chunk0 = off;

  // qT (selection f32, transposed [bh][64][N]) needs 19,267,584 B at k1off;
  // dead before k1b & chunk region live
  const size_t qtNeed = k1off + 19267584 + 256;

  int Nc = 0;
  {
    const int cands[5] = {3136, 1568, 784, 392, 196};
    for (int i = 0; i < 5; ++i) {
      size_t need = chunk0 + (size_t)156672 * cands[i] + 1024;
      if (need <= ws_size && qtNeed <= ws_size) { Nc = cands[i]; break; }
    }
  }
  if (Nc == 0) return;  // ws floor ~95.7 MB
  const int nchunks = N_ / Nc;
  u16*  xoc = (u16*)(ws + chunk0);                // (B,Nc,F,C) bf16
  u16*  k2c = xoc + (size_t)24576 * Nc;           // (B,h,Nc,F,d) bf16
  u16*  v2c = k2c + (size_t)24576 * Nc;
  u16*  xdc = v2c + (size_t)24576 * Nc;           // (B,Nc,C) bf16
  float* q2c = (float*)(xdc + (size_t)1536 * Nc); // (B,h,Nc,d) f32
  float* qt  = (float*)(ws + k1off);              // selection-grade f32 qT (dead before k1_k)

  // landmark candidate slots: 24 heads x 16 u64 (2 parity x 8 blocks) = 3KB,
  // in chunk region (dead until chunk loop); 128B-aligned per head.
  u64* cand = (u64*)(ws + chunk0);

  // dtype sniff on W_qkv; zero candidate slots (every launch, replay-safe)
  detect_k<<<1, 64, 0, stream>>>((const u32*)Wqkv, flagp);
  zcnt_k<<<1, 512, 0, stream>>>(cand);

  // selection-grade f32 qT (transposed), then register-resident landmarks
  qselT_k<<<dim3(98, 12), 256, 0, stream>>>(x, Wqkv, flagp, qt);
  landmarksR_k<<<dim3(KB_, 24), 512, 0, stream>>>(qt, lm, cand);

  // qkv projection -> qb,kb,vb (bf16 smooth path)
  gemm_k<0><<<dim3(49, 18, 1), 256, 0, stream>>>(x, Wqkv, 6272, 768, 768, 2304, 0, 0, flagp,
                                                 nullptr, qb, kb, vb, nullptr, nullptr);
  // kernel_2 + x1 (LDS-only)
  k2x1_k<<<dim3(24, 16), 256, 0, stream>>>(lm, kb, vb, x1b);
  // kernel_1 (overwrites qT region — qT dead)
  k1_k<<<dim3(49, 24), 256, 0, stream>>>(qb, lm, k1b);

  for (int c = 0; c < nchunks; ++c) {
    const int n0c = c * Nc;
    gemm_k<1><<<dim3((Nc + 127) / 128, 8, 24), 256, 0, stream>>>(
        k1b, x1b, Nc, 128, 128, 1024, n0c, Nc, flagp, nullptr, xoc, xdc, nullptr, nullptr, nullptr);
    gemm_k<2><<<dim3((2 * Nc * 16) / 128, 12, 1), 256, 0, stream>>>(
        xoc, Wpkv, 2 * Nc * 16, 768, 768, 1536, n0c, Nc, flagp, nullptr, k2c, v2c, nullptr, nullptr, nullptr);
    gemm_k<3><<<dim3((2 * Nc + 127) / 128, 6, 1), 256, 0, stream>>>(
        xdc, d_in[2], 2 * Nc, 768, 768, 768, n0c, Nc, flagp, q2c, nullptr, nullptr, nullptr, nullptr, nullptr);
    attn_k<<<dim3((Nc + 63) / 64, 24), 256, 0, stream>>>(
        q2c, k2c, v2c, n0c, Nc, flagp, d_out, ob);
  }
  // out = o @ W_proj + b_proj
  gemm_k<4><<<dim3(49, 6, 1), 256, 0, stream>>>(ob, Wproj, 6272, 768, 768, 768, 0, 0, flagp,
                                                nullptr, nullptr, nullptr, nullptr, bproj, d_out);
}

// Round 4
// 1782.240 us; speedup vs baseline: 2.0648x; 1.1907x over previous
//
#include <hip/hip_runtime.h>

// TrajectoryAttention on MI355X (gfx950), chunked pipeline, dtype-adaptive.
// R12: GEMM staging overhaul. R11 counters: landmarks now 450us (cross-XCD sync
//   RTT floor ~3.5us/step); remaining ~1670us is the MFMA GEMM family (~294
//   GFLOP, 80% in MODE2 xoc@Wpkv). Old staging: raw-f32 B = 4 float4 loads +
//   16 f2b + 16 scalar u16 LDS stores per thread per K-step (VALU-bound).
//   Fix: pre-transpose ALL weights to bf16 [n][k] ONCE (twT_k, LDS tile);
//   pre-convert x to bf16 (xcvt_k); k2x1_k writes x1b TRANSPOSED [bh][n][l]
//   (coalesced store reorder). gemm_k now stages A and B as uint4 pairs, all
//   modes. Bit-identical numerics (same f2b rounding, hoisted out of K-loop).
//   No ws growth: WqkvT+xb in dead qt region; WpkvT/WpqT/WprojT in dead kb.
// R11 (kept): landmarks qT slice pinned in registers (qreg[16]).
// R10 (kept): fence-free cross-block sync, packed u64 relaxed agent atomics.
// R9  (kept): 8 blocks/head, quad-split f64 dots. R8: transposed qT.
// R7  (kept): partitionable threefry idx0; chunked k2/v2.

using u16 = unsigned short;
using u32 = unsigned int;
using u64 = unsigned long long;

typedef short bf16x8 __attribute__((ext_vector_type(8)));
typedef float f32x4 __attribute__((ext_vector_type(4)));

#define N_ 3136
#define C_ 768
#define H_ 12
#define F_ 16
#define P_ 196
#define L_ 128
#define SC_ 0.35355339059327373f   // 64^-0.25
#define OUTPART_ ((size_t)2 * N_ * C_)
#define KB_ 8                      // blocks per head in landmarks
#define RPB_ 392                   // rows per block (3136/8)

__device__ __forceinline__ float b2f(u16 u) {
  u32 x = ((u32)u) << 16; float f; __builtin_memcpy(&f, &x, 4); return f;
}
__device__ __forceinline__ float lo16f(u32 u) {
  u32 x = u << 16; float f; __builtin_memcpy(&f, &x, 4); return f;
}
__device__ __forceinline__ float hi16f(u32 u) {
  u32 x = u & 0xFFFF0000u; float f; __builtin_memcpy(&f, &x, 4); return f;
}
__device__ __forceinline__ u16 f2b(float f) {
  u32 u; __builtin_memcpy(&u, &f, 4);
  u32 r = (u + 0x7FFFu + ((u >> 16) & 1u)) >> 16;
  return (u16)r;
}
__device__ __forceinline__ u64 d2u(double d) { u64 u; __builtin_memcpy(&u, &d, 8); return u; }

// dtype sniffer (bf16 vs f32 inputs) — votes f32 on this dataset (proven R4)
__global__ void detect_k(const u32* __restrict__ w, int* __restrict__ flag) {
  const int t = threadIdx.x;  // 64
  int hits = 0;
  #pragma unroll
  for (int i = 0; i < 16; ++i) {
    u32 word = w[t * 16 + i];
    u32 e = (word >> 7) & 0xFFu;
    if (e >= 110u && e <= 126u) hits++;
  }
  #pragma unroll
  for (int off = 32; off > 0; off >>= 1) hits += __shfl_down(hits, off);
  if (t == 0) flag[0] = (hits >= 512) ? 0 : 1;  // 0=bf16, 1=f32
}

// zero candidate slots (24 heads x 2 parity x 8 blocks = 384 u64).
__global__ void zcnt_k(u64* __restrict__ p) { if (threadIdx.x < 384) p[threadIdx.x] = 0ull; }

// ---- exact JAX threefry2x32-20 core ----
__device__ __forceinline__ void tf2(u32 k0, u32 k1v, u32 c0, u32 c1, u32& o0, u32& o1) {
  u32 ks[3] = {k0, k1v, k0 ^ k1v ^ 0x1BD11BDAu};
  u32 x0 = c0 + ks[0], x1 = c1 + ks[1];
  const u32 rA[4] = {13u, 15u, 26u, 6u}, rB[4] = {17u, 29u, 16u, 24u};
  #pragma unroll
  for (int r = 0; r < 5; ++r) {
    #pragma unroll
    for (int q = 0; q < 4; ++q) {
      u32 rot = (r & 1) ? rB[q] : rA[q];
      x0 += x1; x1 = (x1 << rot) | (x1 >> (32u - rot)); x1 ^= x0;
    }
    x0 += ks[(r + 1) % 3];
    x1 += ks[(r + 2) % 3] + (u32)(r + 1);
  }
  o0 = x0; o1 = x1;
}

// jax.random.randint(key(42), (24,), 0, 3136), partitionable — PROVEN (R7).
__device__ __forceinline__ int tf_idx0(int bh) {
  u32 a0, a1, b0, b1;
  tf2(0u, 42u, 0u, 0u, a0, a1);
  tf2(0u, 42u, 0u, 1u, b0, b1);
  u32 j = (u32)bh;
  u32 h0, h1, l0, l1;
  tf2(a0, a1, 0u, j, h0, h1);
  u32 hi = h0 ^ h1;
  tf2(b0, b1, 0u, j, l0, l1);
  u32 lo = l0 ^ l1;
  return (int)(((hi % 3136u) * 2048u + (lo % 3136u)) % 3136u);
}

// ---------------- selection-grade f32 GEMM -> TRANSPOSED qT[bh][d][n] ----------------
__global__ __launch_bounds__(256) void qselT_k(const void* __restrict__ xr, const void* __restrict__ wr,
                                               const int* __restrict__ flagp, float* __restrict__ qt)
{
  __shared__ float As[64 * 20];
  __shared__ float Bs[16 * 64];
  const int t = threadIdx.x;
  const int m0 = blockIdx.x * 64;
  const int n0 = blockIdx.y * 64;
  const int f32i = flagp[0];
  const int tx = t & 15, ty = t >> 4;
  float acc[4][4];
  #pragma unroll
  for (int i = 0; i < 4; ++i)
    #pragma unroll
    for (int j = 0; j < 4; ++j) acc[i][j] = 0.f;

  const int alr = t >> 2;
  const int alk = (t & 3) * 4;
  const int bkr = t >> 4;
  const int bnc = (t & 15) * 4;

  for (int k0 = 0; k0 < 768; k0 += 16) {
    float4 av, bv;
    if (f32i) {
      av = *(const float4*)((const float*)xr + (size_t)(m0 + alr) * 768 + k0 + alk);
      bv = *(const float4*)((const float*)wr + (size_t)(k0 + bkr) * 2304 + n0 + bnc);
    } else {
      const u16* xa = (const u16*)xr + (size_t)(m0 + alr) * 768 + k0 + alk;
      const u16* wa = (const u16*)wr + (size_t)(k0 + bkr) * 2304 + n0 + bnc;
      av.x = b2f(xa[0]); av.y = b2f(xa[1]); av.z = b2f(xa[2]); av.w = b2f(xa[3]);
      bv.x = b2f(wa[0]); bv.y = b2f(wa[1]); bv.z = b2f(wa[2]); bv.w = b2f(wa[3]);
    }
    As[alr * 20 + alk + 0] = av.x; As[alr * 20 + alk + 1] = av.y;
    As[alr * 20 + alk + 2] = av.z; As[alr * 20 + alk + 3] = av.w;
    *(float4*)(&Bs[bkr * 64 + bnc]) = bv;
    __syncthreads();
    #pragma unroll
    for (int kk = 0; kk < 16; ++kk) {
      float a[4], b[4];
      #pragma unroll
      for (int i = 0; i < 4; ++i) a[i] = As[(ty * 4 + i) * 20 + kk];
      #pragma unroll
      for (int j = 0; j < 4; ++j) b[j] = Bs[kk * 64 + tx * 4 + j];
      #pragma unroll
      for (int i = 0; i < 4; ++i)
        #pragma unroll
        for (int j = 0; j < 4; ++j) acc[i][j] += a[i] * b[j];
    }
    __syncthreads();
  }
  #pragma unroll
  for (int i = 0; i < 4; ++i) {
    const int m = m0 + ty * 4 + i;
    const int b = m / N_, n = m - b * N_;
    #pragma unroll
    for (int j = 0; j < 4; ++j) {
      const int col = n0 + tx * 4 + j;
      const int hh = col >> 6, dd = col & 63;
      qt[((size_t)(b * H_ + hh) * 64 + dd) * N_ + n] = acc[i][j] * SC_;
    }
  }
}

// ---------------- greedy landmarks: 8 blocks/head, register-resident slice ----------------
__global__ __launch_bounds__(512, 1) void landmarksR_k(
    const float* __restrict__ qt, float* __restrict__ lm, u64* __restrict__ cand)
{
  const int kb = blockIdx.x;
  const int bh = blockIdx.y;
  const float* QT = qt + (size_t)bh * 64 * N_;   // [d][n]
  float* LM = lm + (size_t)bh * L_ * 64;
  u64* cd = cand + (size_t)bh * 16;
  __shared__ double curD[64];
  __shared__ u64 redV[8];
  __shared__ int redI[8];
  __shared__ int sW;
  const int t = threadIdx.x;
  const bool act = (t < RPB_);
  const int g = t >> 2, dc = t & 3, d0 = dc * 16;
  const int r0 = kb * RPB_;
  const int myRow = r0 + t;
  const float* base = QT + r0 + 4 * g;

  float4 qreg[16];
  #pragma unroll
  for (int i = 0; i < 16; ++i) qreg[i] = (float4){0.f, 0.f, 0.f, 0.f};
  if (act) {
    #pragma unroll
    for (int i = 0; i < 16; ++i) qreg[i] = *(const float4*)(base + (size_t)(d0 + i) * N_);
  }

  double inv_own = 0.0, ms_own = 0.0;
  if (act) {
    double s0 = 0.0, s1 = 0.0, s2 = 0.0, s3 = 0.0;
    #pragma unroll
    for (int i = 0; i < 16; ++i) {
      const float4 v = qreg[i];
      s0 += (double)v.x * (double)v.x; s1 += (double)v.y * (double)v.y;
      s2 += (double)v.z * (double)v.z; s3 += (double)v.w * (double)v.w;
    }
    s0 += __shfl_xor(s0, 1); s1 += __shfl_xor(s1, 1);
    s2 += __shfl_xor(s2, 1); s3 += __shfl_xor(s3, 1);
    s0 += __shfl_xor(s0, 2); s1 += __shfl_xor(s1, 2);
    s2 += __shfl_xor(s2, 2); s3 += __shfl_xor(s3, 2);
    const double sown = (dc == 0) ? s0 : (dc == 1) ? s1 : (dc == 2) ? s2 : s3;
    inv_own = 1.0 / fmax(sqrt(sown), 1e-12);
  }
  const int idx0 = tf_idx0(bh);
  if (act && myRow == idx0) ms_own = 10.0;

  if (t < 64) {
    const float vf = QT[(size_t)t * N_ + idx0];
    double v = (double)vf;
    double s = v * v;
    #pragma unroll
    for (int off = 32; off; off >>= 1) s += __shfl_xor(s, off);
    curD[t] = v / fmax(sqrt(s), 1e-12);
    if (kb == 0) LM[t] = vf;
  }
  __syncthreads();

  for (int step = 1; step < 128; ++step) {
    u64 bV = d2u(1e30); int bI = 0x7fffffff;
    if (act) {
      double a0 = 0.0, a1 = 0.0, a2 = 0.0, a3 = 0.0;
      #pragma unroll
      for (int i = 0; i < 16; ++i) {
        const float4 v = qreg[i];
        const double c = curD[d0 + i];
        a0 += (double)v.x * c; a1 += (double)v.y * c;
        a2 += (double)v.z * c; a3 += (double)v.w * c;
      }
      a0 += __shfl_xor(a0, 1); a1 += __shfl_xor(a1, 1);
      a2 += __shfl_xor(a2, 1); a3 += __shfl_xor(a3, 1);
      a0 += __shfl_xor(a0, 2); a1 += __shfl_xor(a1, 2);
      a2 += __shfl_xor(a2, 2); a3 += __shfl_xor(a3, 2);
      const double aown = (dc == 0) ? a0 : (dc == 1) ? a1 : (dc == 2) ? a2 : a3;
      ms_own = fmax(ms_own, fabs(aown * inv_own));
      bV = d2u(ms_own); bI = myRow;
    }
    #pragma unroll
    for (int off = 32; off; off >>= 1) {
      const u64 ov = __shfl_xor(bV, off);
      const int oi = __shfl_xor(bI, off);
      if (ov < bV || (ov == bV && oi < bI)) { bV = ov; bI = oi; }
    }
    if ((t & 63) == 0) { redV[t >> 6] = bV; redI[t >> 6] = bI; }
    __syncthreads();
    const int par = step & 1;
    if (t == 0) {
      u64 v = redV[0]; int ix = redI[0];
      #pragma unroll
      for (int w2 = 1; w2 < 8; ++w2)
        if (redV[w2] < v || (redV[w2] == v && redI[w2] < ix)) { v = redV[w2]; ix = redI[w2]; }
      const u64 pk = (v & ~((1ull << 19) - 1ull)) | ((u64)(u32)(step & 127) << 12) | (u64)(u32)ix;
      __hip_atomic_store(&cd[par * KB_ + kb], pk, __ATOMIC_RELAXED, __HIP_MEMORY_SCOPE_AGENT);
    }
    if (t < 64) {
      u64 pv = ~0ull;
      int ok = 1;
      for (;;) {
        if (t < KB_) {
          pv = __hip_atomic_load(&cd[par * KB_ + t], __ATOMIC_RELAXED, __HIP_MEMORY_SCOPE_AGENT);
          ok = ((int)((pv >> 12) & 127u) == step) ? 1 : 0;
        }
        if (__all(ok)) break;
        __builtin_amdgcn_s_sleep(1);
      }
      u64 m = (t < KB_) ? pv : ~0ull;
      #pragma unroll
      for (int off = 1; off < KB_; off <<= 1) {
        const u64 o = __shfl_xor(m, off);
        if (o < m) m = o;
      }
      if (t == 0) sW = (int)(m & 0xFFFu);
    }
    __syncthreads();
    const int w = sW;
    if (act && myRow == w) ms_own = 10.0;
    if (t < 64) {
      const float vf = QT[(size_t)t * N_ + w];
      double v = (double)vf;
      double s = v * v;
      #pragma unroll
      for (int off = 32; off; off >>= 1) s += __shfl_xor(s, off);
      curD[t] = v / fmax(sqrt(s), 1e-12);
      if (kb == 0) LM[(size_t)step * 64 + t] = vf;
    }
    __syncthreads();
  }
}

// ---------------- weight transpose + bf16-ify: W[K][Nn] raw -> WT[Nn][K] bf16 ----------------
__global__ __launch_bounds__(256) void twT_k(const void* __restrict__ W, int K, int Nn,
                                             const int* __restrict__ flagp, u16* __restrict__ WT)
{
  __shared__ u16 Ts[64][80];   // [k][n] padded
  const int t = threadIdx.x;
  const int k0 = blockIdx.x * 64, n0 = blockIdx.y * 64;
  const int f32i = flagp[0];
  const int kr = t >> 2, nc = (t & 3) * 16;
  u16 tmp[16];
  if (f32i) {
    const float* p = (const float*)W + (size_t)(k0 + kr) * Nn + n0 + nc;
    #pragma unroll
    for (int j = 0; j < 16; ++j) tmp[j] = f2b(p[j]);
  } else {
    const u16* p = (const u16*)W + (size_t)(k0 + kr) * Nn + n0 + nc;
    #pragma unroll
    for (int j = 0; j < 16; ++j) tmp[j] = p[j];
  }
  #pragma unroll
  for (int j = 0; j < 16; ++j) Ts[kr][nc + j] = tmp[j];
  __syncthreads();
  const int nr = t >> 2, kc = (t & 3) * 16;
  u16 o[16];
  #pragma unroll
  for (int j = 0; j < 16; ++j) o[j] = Ts[kc + j][nr];
  u16* dst = WT + (size_t)(n0 + nr) * K + k0 + kc;
  *(uint4*)(dst) = *(uint4*)(o);
  *(uint4*)(dst + 8) = *(uint4*)(o + 8);
}

// ---------------- x -> bf16 (elementwise, 8/thread, 4816896 elems) ----------------
__global__ __launch_bounds__(256) void xcvt_k(const void* __restrict__ x,
                                              const int* __restrict__ flagp, u16* __restrict__ xb)
{
  const int i = blockIdx.x * 256 + threadIdx.x;  // 602112 threads exactly
  if (flagp[0]) {
    const float4* p = (const float4*)x + (size_t)i * 2;
    float4 f0 = p[0], f1 = p[1];
    u16 tmp[8] = { f2b(f0.x), f2b(f0.y), f2b(f0.z), f2b(f0.w),
                   f2b(f1.x), f2b(f1.y), f2b(f1.z), f2b(f1.w) };
    *(uint4*)(xb + (size_t)i * 8) = *(uint4*)tmp;
  } else {
    ((uint4*)xb)[i] = ((const uint4*)x)[i];
  }
}

// ---------------- generic 128x128 bf16 MFMA GEMM, vectorized staging, per-mode epilogues ----
// A: bf16 [m][k] (lda), B: bf16 [n][k] (ldb) -- ALL operands pre-converted/transposed.
template <int MODE>
__global__ __launch_bounds__(256) void gemm_k(
    const void* __restrict__ Ap, const void* __restrict__ Bp,
    int M, int K, int lda, int ldb, int n0c, int cn, const int* __restrict__ flagp,
    float* __restrict__ of0, u16* __restrict__ ob0, u16* __restrict__ ob1, u16* __restrict__ ob2,
    const void* __restrict__ biasRaw, void* __restrict__ outRaw)
{
  __shared__ u16 As[128 * 40];
  __shared__ u16 Bs[128 * 40];
  const int t = threadIdx.x;
  const int m0 = blockIdx.x * 128;
  const int n0 = blockIdx.y * 128;
  const int rf = (MODE == 4) ? flagp[0] : 0;

  size_t aOff = 0, bOff = 0;
  if constexpr (MODE == 1) {
    const int bh = blockIdx.z;
    aOff = (size_t)bh * ((size_t)N_ * 128) + (size_t)n0c * 128;
    bOff = (size_t)bh * (1024 * 128);
  }
  const int lane = t & 63;
  const int w = t >> 6;
  const int mw = (w >> 1) * 64;
  const int nw = (w & 1) * 64;
  const int lr = lane & 15;
  const int lk = lane >> 4;

  f32x4 acc[4][4];
  #pragma unroll
  for (int i = 0; i < 4; ++i)
    #pragma unroll
    for (int j = 0; j < 4; ++j) acc[i][j] = (f32x4){0.f, 0.f, 0.f, 0.f};

  const int ar = t >> 1;
  const int ak = (t & 1) * 16;
  const int agrow = m0 + ar;
  const bool aValid = (agrow < M);
  const u16* A16 = (const u16*)Ap;
  const u16* B16 = (const u16*)Bp;

  for (int k0 = 0; k0 < K; k0 += 32) {
    uint4 a0, a1;
    if (aValid) {
      const uint4* ap = (const uint4*)(A16 + aOff + (size_t)agrow * lda + k0 + ak);
      a0 = ap[0]; a1 = ap[1];
    } else {
      a0.x = a0.y = a0.z = a0.w = 0u; a1 = a0;
    }
    const uint4* bp = (const uint4*)(B16 + bOff + (size_t)(n0 + ar) * ldb + k0 + ak);
    uint4 b0 = bp[0], b1 = bp[1];

    *(uint4*)(&As[ar * 40 + ak]) = a0;
    *(uint4*)(&As[ar * 40 + ak + 8]) = a1;
    *(uint4*)(&Bs[ar * 40 + ak]) = b0;
    *(uint4*)(&Bs[ar * 40 + ak + 8]) = b1;
    __syncthreads();

    bf16x8 af[4], bfv[4];
    #pragma unroll
    for (int mt = 0; mt < 4; ++mt)
      af[mt] = *(const bf16x8*)(&As[(mw + mt * 16 + lr) * 40 + lk * 8]);
    #pragma unroll
    for (int nt = 0; nt < 4; ++nt)
      bfv[nt] = *(const bf16x8*)(&Bs[(nw + nt * 16 + lr) * 40 + lk * 8]);
    #pragma unroll
    for (int mt = 0; mt < 4; ++mt)
      #pragma unroll
      for (int nt = 0; nt < 4; ++nt)
        acc[mt][nt] = __builtin_amdgcn_mfma_f32_16x16x32_bf16(af[mt], bfv[nt], acc[mt][nt], 0, 0, 0);
    __syncthreads();
  }

  #pragma unroll
  for (int mt = 0; mt < 4; ++mt) {
    #pragma unroll
    for (int nt = 0; nt < 4; ++nt) {
      #pragma unroll
      for (int r = 0; r < 4; ++r) {
        const int grow = m0 + mw + mt * 16 + lk * 4 + r;
        const int gcol = n0 + nw + nt * 16 + lr;
        if (grow >= M) continue;
        float vv = acc[mt][nt][r];
        if constexpr (MODE == 0) {           // qkv -> qb,kb,vb bf16 (bh,N,64)
          int b = (grow >= N_) ? 1 : 0;
          int n = grow - b * N_;
          int t3 = gcol / C_, cc = gcol - t3 * C_;
          int hh = cc >> 6, dd = cc & 63;
          size_t dst = (((size_t)(b * H_ + hh)) * N_ + n) * 64 + dd;
          if (t3 == 0) ob0[dst] = f2b(vv * SC_);
          else if (t3 == 1) ob1[dst] = f2b(vv * SC_);
          else ob2[dst] = f2b(vv);
        } else if constexpr (MODE == 1) {    // xoc (B,cn,F,C) bf16 + xdiag side-write
          const int bh = blockIdx.z;
          int b = bh / H_, hh = bh - b * H_;
          int f = gcol >> 6, dd = gcol & 63;
          u16 wv = f2b(vv);
          ob0[(((size_t)(b * cn + grow)) * F_ + f) * C_ + hh * 64 + dd] = wv;
          int n = n0c + grow;
          if (f == n / P_) ob1[((size_t)(b * cn + grow)) * C_ + hh * 64 + dd] = wv;
        } else if constexpr (MODE == 2) {    // k2c,v2c (B,h,cn,F,d) bf16
          const int cn16 = cn * F_;
          int b = (grow >= cn16) ? 1 : 0;
          int r2 = grow - b * cn16;
          int ln = r2 >> 4, f = r2 & 15;
          int t2 = (gcol >= C_) ? 1 : 0, cc = gcol - t2 * C_;
          int hh = cc >> 6, dd = cc & 63;
          size_t dst = ((((size_t)(b * H_ + hh)) * cn + ln) * F_ + f) * 64 + dd;
          if (t2) ob1[dst] = f2b(vv); else ob0[dst] = f2b(vv);
        } else if constexpr (MODE == 3) {    // q2c (B,h,cn,d) f32, * 0.125
          int b = (grow >= cn) ? 1 : 0;
          int ln = grow - b * cn;
          int hh = gcol >> 6, dd = gcol & 63;
          of0[(((size_t)(b * H_ + hh)) * cn + ln) * 64 + dd] = vv * 0.125f;
        } else {                             // out = o@W_proj + b_proj, flag dtype
          float bvad = rf ? ((const float*)biasRaw)[gcol] : b2f(((const u16*)biasRaw)[gcol]);
          float ov = vv + bvad;
          if (rf) ((float*)outRaw)[(size_t)grow * C_ + gcol] = ov;
          else    ((u16*)outRaw)[(size_t)grow * C_ + gcol] = f2b(ov);
        }
      }
    }
  }
}

// ---------------- kernel_1 = softmax_l(q . lm^T), bf16 out ----------------
__global__ __launch_bounds__(256) void k1_k(const u16* __restrict__ qb,
                                            const float* __restrict__ lm,
                                            u16* __restrict__ k1)
{
  const int bh = blockIdx.y;
  const int r0 = blockIdx.x * 64;
  __shared__ float qT[64][65];
  __shared__ float lmS[128 * 64];
  __shared__ float redA[4][64];
  __shared__ float redB[64];
  const int t = threadIdx.x;
  const u16* Q = qb + ((size_t)bh * N_ + r0) * 64;
  const float* Lm = lm + (size_t)bh * L_ * 64;
  for (int u = t; u < 2048; u += 256) ((float4*)lmS)[u] = ((const float4*)Lm)[u];
  for (int u = t; u < 512; u += 256) {
    int row = u >> 3, j0 = (u & 7) * 8;
    uint4 pk = *(const uint4*)(Q + (size_t)row * 64 + j0);
    const u16* pu = (const u16*)&pk;
    #pragma unroll
    for (int jj = 0; jj < 8; ++jj) qT[j0 + jj][row] = b2f(pu[jj]);
  }
  __syncthreads();
  const int row = t & 63, ch = t >> 6;
  float qr[64];
  #pragma unroll
  for (int j = 0; j < 64; ++j) qr[j] = qT[j][row];
  float s[32];
  for (int li = 0; li < 32; ++li) {
    const float* lp = lmS + (ch * 32 + li) * 64;
    float a = 0.f;
    #pragma unroll
    for (int j = 0; j < 64; ++j) a += lp[j] * qr[j];
    s[li] = a;
  }
  float mx = -1e30f;
  for (int li = 0; li < 32; ++li) mx = fmaxf(mx, s[li]);
  redA[ch][row] = mx;
  __syncthreads();
  if (t < 64) redB[t] = fmaxf(fmaxf(redA[0][t], redA[1][t]), fmaxf(redA[2][t], redA[3][t]));
  __syncthreads();
  mx = redB[row];
  float sum = 0.f;
  for (int li = 0; li < 32; ++li) { float e = __expf(s[li] - mx); s[li] = e; sum += e; }
  __syncthreads();
  redA[ch][row] = sum;
  __syncthreads();
  if (t < 64) redB[t] = 1.0f / (redA[0][t] + redA[1][t] + redA[2][t] + redA[3][t]);
  __syncthreads();
  const float inv = redB[row];
  u16* out = k1 + ((size_t)bh * N_ + r0 + row) * 128 + ch * 32;
  for (int li = 0; li < 32; ++li) out[li] = f2b(s[li] * inv);
}

// ---------------- kernel_2 per frame + x1 = kernel_2 @ v  (LDS-only, 3-pass) ----------------
// R12: x1 written TRANSPOSED: x1T[bh][n = f*64+dd][l], coalesced per-u across lanes.
__global__ __launch_bounds__(256) void k2x1_k(const float* __restrict__ lm,
                                              const u16* __restrict__ kb,
                                              const u16* __restrict__ vb,
                                              u16* __restrict__ x1)
{
  const int bh = blockIdx.x;
  const int f = blockIdx.y;
  __shared__ u16 kS[P_ * 64];
  __shared__ u16 vS[P_ * 64];
  __shared__ float redM[2][128];
  __shared__ float redS[2][128];
  const int t = threadIdx.x;
  const u16* Kf = kb + ((size_t)bh * N_ + f * P_) * 64;
  const u16* Vf = vb + ((size_t)bh * N_ + f * P_) * 64;
  for (int u = t; u < 1568; u += 256) {
    ((uint4*)kS)[u] = ((const uint4*)Kf)[u];
    ((uint4*)vS)[u] = ((const uint4*)Vf)[u];
  }
  __syncthreads();
  const int l = t & 127, half = t >> 7;
  const float* lp = lm + ((size_t)bh * L_ + l) * 64;
  float lr[64];
  #pragma unroll
  for (int j = 0; j < 64; ++j) lr[j] = lp[j];

  const int p0 = half * 98, p1 = p0 + 98;
  float mx = -1e30f;
  for (int p = p0; p < p1; ++p) {
    const uint4* kp = (const uint4*)(kS + p * 64);
    float s = 0.f;
    #pragma unroll
    for (int q4 = 0; q4 < 8; ++q4) {
      uint4 pk = kp[q4];
      const u32* pu = (const u32*)&pk;
      #pragma unroll
      for (int j2 = 0; j2 < 4; ++j2) {
        u32 u = pu[j2];
        s += lr[q4 * 8 + j2 * 2] * lo16f(u) + lr[q4 * 8 + j2 * 2 + 1] * hi16f(u);
      }
    }
    mx = fmaxf(mx, s);
  }
  redM[half][l] = mx;
  __syncthreads();
  mx = fmaxf(redM[0][l], redM[1][l]);

  float sm = 0.f;
  for (int p = p0; p < p1; ++p) {
    const uint4* kp = (const uint4*)(kS + p * 64);
    float s = 0.f;
    #pragma unroll
    for (int q4 = 0; q4 < 8; ++q4) {
      uint4 pk = kp[q4];
      const u32* pu = (const u32*)&pk;
      #pragma unroll
      for (int j2 = 0; j2 < 4; ++j2) {
        u32 u = pu[j2];
        s += lr[q4 * 8 + j2 * 2] * lo16f(u) + lr[q4 * 8 + j2 * 2 + 1] * hi16f(u);
      }
    }
    sm += __expf(s - mx);
  }
  redS[half][l] = sm;
  __syncthreads();
  const float inv = 1.0f / (redS[0][l] + redS[1][l]);

  const int dd0 = half * 32;
  float acc[32];
  #pragma unroll
  for (int u = 0; u < 32; ++u) acc[u] = 0.f;
  for (int p = 0; p < P_; ++p) {
    const uint4* kp = (const uint4*)(kS + p * 64);
    float s = 0.f;
    #pragma unroll
    for (int q4 = 0; q4 < 8; ++q4) {
      uint4 pk = kp[q4];
      const u32* pu = (const u32*)&pk;
      #pragma unroll
      for (int j2 = 0; j2 < 4; ++j2) {
        u32 u = pu[j2];
        s += lr[q4 * 8 + j2 * 2] * lo16f(u) + lr[q4 * 8 + j2 * 2 + 1] * hi16f(u);
      }
    }
    const float e = __expf(s - mx);
    const uint4* vp = (const uint4*)(vS + p * 64 + dd0);
    #pragma unroll
    for (int q4 = 0; q4 < 4; ++q4) {
      uint4 pv = vp[q4];
      const u32* pu = (const u32*)&pv;
      #pragma unroll
      for (int j2 = 0; j2 < 4; ++j2) {
        u32 u = pu[j2];
        acc[q4 * 8 + j2 * 2]     += e * lo16f(u);
        acc[q4 * 8 + j2 * 2 + 1] += e * hi16f(u);
      }
    }
  }
  // transposed store: x1T[bh][f*64 + dd][l]; per-u the 128 l-lanes are contiguous
  u16* outT = x1 + (size_t)bh * (1024 * 128) + (size_t)(f * 64 + dd0) * 128 + l;
  for (int u = 0; u < 32; ++u) outT[(size_t)u * 128] = f2b(acc[u] * inv);
}

// ---------------- final 16-way frame attention + o = attn @ v2 (chunked) ----------------
__global__ __launch_bounds__(256) void attn_k(const float* __restrict__ q2c,
                                              const u16* __restrict__ k2c,
                                              const u16* __restrict__ v2c,
                                              int n0c, int cn, const int* __restrict__ flagp,
                                              void* __restrict__ outRaw,
                                              u16* __restrict__ o)
{
  const int bh = blockIdx.y;
  const int b = bh / H_, hh = bh - b * H_;
  const int t = threadIdx.x;
  const int f32o = flagp[0];
  __shared__ float aS[64][17];
  const int nl = t >> 2, qi = t & 3;
  const int ln = blockIdx.x * 64 + nl;
  const bool act = ln < cn;
  const int n = n0c + ln;
  float q[64];
  if (act) {
    const float* qr = q2c + ((size_t)bh * cn + ln) * 64;
    #pragma unroll
    for (int j = 0; j < 64; ++j) q[j] = qr[j];
    float lg[4];
    #pragma unroll
    for (int ff = 0; ff < 4; ++ff) {
      const int f = qi * 4 + ff;
      const u16* kp = k2c + (((size_t)bh * cn + ln) * F_ + f) * 64;
      float s = 0.f;
      #pragma unroll
      for (int j8 = 0; j8 < 8; ++j8) {
        uint4 pk = ((const uint4*)kp)[j8];
        const u16* pu = (const u16*)&pk;
        #pragma unroll
        for (int u = 0; u < 8; ++u) s += q[j8 * 8 + u] * b2f(pu[u]);
      }
      lg[ff] = s;
    }
    float mx = fmaxf(fmaxf(lg[0], lg[1]), fmaxf(lg[2], lg[3]));
    mx = fmaxf(mx, __shfl_xor(mx, 1));
    mx = fmaxf(mx, __shfl_xor(mx, 2));
    float e[4], sm = 0.f;
    #pragma unroll
    for (int ff = 0; ff < 4; ++ff) { e[ff] = __expf(lg[ff] - mx); sm += e[ff]; }
    sm += __shfl_xor(sm, 1);
    sm += __shfl_xor(sm, 2);
    const float iv = 1.0f / sm;
    const size_t abase = ((size_t)bh * N_ + n) * F_ + qi * 4;
    #pragma unroll
    for (int ff = 0; ff < 4; ++ff) {
      const float a = e[ff] * iv;
      if (f32o) ((float*)outRaw)[OUTPART_ + abase + ff] = a;
      else      ((u16*)outRaw)[OUTPART_ + abase + ff] = f2b(a);
      aS[nl][qi * 4 + ff] = a;
    }
  }
  __syncthreads();
  if (act) {
    const int dd0 = qi * 16;
    float acc[16];
    #pragma unroll
    for (int u = 0; u < 16; ++u) acc[u] = 0.f;
    for (int f = 0; f < F_; ++f) {
      const float w2 = aS[nl][f];
      const u16* vp = v2c + (((size_t)bh * cn + ln) * F_ + f) * 64 + dd0;
      uint4 pv0 = ((const uint4*)vp)[0], pv1 = ((const uint4*)vp)[1];
      const u16* pu0 = (const u16*)&pv0;
      const u16* pu1 = (const u16*)&pv1;
      #pragma unroll
      for (int u = 0; u < 8; ++u) acc[u] += w2 * b2f(pu0[u]);
      #pragma unroll
      for (int u = 0; u < 8; ++u) acc[8 + u] += w2 * b2f(pu1[u]);
    }
    u16* op = o + ((size_t)(b * N_ + n)) * C_ + hh * 64 + dd0;
    for (int u = 0; u < 16; ++u) op[u] = f2b(acc[u]);
  }
}

extern "C" void kernel_launch(void* const* d_in, const int* in_sizes, int n_in,
                              void* d_out, int out_size, void* d_ws, size_t ws_size,
                              hipStream_t stream)
{
  (void)in_sizes; (void)n_in; (void)out_size;
  const void* x     = d_in[0];
  const void* Wqkv  = d_in[1];
  const void* Wpq   = d_in[2];
  const void* Wpkv  = d_in[3];
  const void* Wproj = d_in[4];
  const void* bproj = d_in[5];

  char* ws = (char*)d_ws;
  size_t off = 0;
  auto alloc = [&](size_t bytes) { void* p = ws + off; off += (bytes + 255) & ~(size_t)255; return p; };
  int*  flagp = (int*)alloc(256);
  u16*  qb  = (u16*)alloc(9633792);     // (bh,N,64) bf16, scaled
  u16*  kb  = (u16*)alloc(9633792);     // scaled; hosts WpkvT/WpqT/WprojT after k2x1
  u16*  vb  = (u16*)alloc(9633792);
  float* lm = (float*)alloc(786432);    // (bh,128,64) f32
  u16*  x1b = (u16*)alloc(6291456);     // (bh,1024,128) bf16 TRANSPOSED
  u16*  ob  = (u16*)alloc(9633792);     // (B,N,C) bf16
  const size_t k1off = off;             // qT f32 starts here (aliases k1b + chunk region)
  u16*  k1b = (u16*)alloc(19267584);    // (bh,N,128) bf16
  const size_t chunk0 = off;

  // qt region (19.27 MB at k1off): qselT/landmarks use it as f32 qT; after
  // landmarks it hosts WqkvT (3.54 MB) + xb (9.63 MB); k1b overwrites later.
  const size_t qtNeed = k1off + 19267584 + 256;

  int Nc = 0;
  {
    const int cands[5] = {3136, 1568, 784, 392, 196};
    for (int i = 0; i < 5; ++i) {
      size_t need = chunk0 + (size_t)156672 * cands[i] + 1024;
      if (need <= ws_size && qtNeed <= ws_size) { Nc = cands[i]; break; }
    }
  }
  if (Nc == 0) return;  // ws floor ~95.7 MB
  const int nchunks = N_ / Nc;
  u16*  xoc = (u16*)(ws + chunk0);                // (B,Nc,F,C) bf16
  u16*  k2c = xoc + (size_t)24576 * Nc;           // (B,h,Nc,F,d) bf16
  u16*  v2c = k2c + (size_t)24576 * Nc;
  u16*  xdc = v2c + (size_t)24576 * Nc;           // (B,Nc,C) bf16
  float* q2c = (float*)(xdc + (size_t)1536 * Nc); // (B,h,Nc,d) f32
  float* qt  = (float*)(ws + k1off);              // selection-grade f32 qT

  // bf16 staging buffers (zero ws growth):
  u16* WqkvT = (u16*)(ws + k1off);                 // [2304][768] bf16, 3538944 B
  u16* xb    = (u16*)(ws + k1off + 3538944);       // [6272][768] bf16, 9633792 B
  u16* WpkvT = kb;                                 // [1536][768] bf16 (kb dead post-k2x1)
  u16* WpqT  = kb + 1179648;                       // [768][768]
  u16* WprojT= kb + 1179648 + 589824;              // [768][768]

  // landmark candidate slots: 24 heads x 16 u64 = 3KB in chunk region (dead until loop)
  u64* cand = (u64*)(ws + chunk0);

  detect_k<<<1, 64, 0, stream>>>((const u32*)Wqkv, flagp);
  zcnt_k<<<1, 512, 0, stream>>>(cand);

  // selection-grade f32 qT (transposed), then register-resident landmarks
  qselT_k<<<dim3(98, 12), 256, 0, stream>>>(x, Wqkv, flagp, qt);
  landmarksR_k<<<dim3(KB_, 24), 512, 0, stream>>>(qt, lm, cand);

  // qt now dead: build bf16 operands in its place
  twT_k<<<dim3(12, 36), 256, 0, stream>>>(Wqkv, 768, 2304, flagp, WqkvT);
  xcvt_k<<<2352, 256, 0, stream>>>(x, flagp, xb);

  // qkv projection -> qb,kb,vb (vectorized bf16 staging)
  gemm_k<0><<<dim3(49, 18, 1), 256, 0, stream>>>(xb, WqkvT, 6272, 768, 768, 768, 0, 0, flagp,
                                                 nullptr, qb, kb, vb, nullptr, nullptr);
  // kernel_2 + x1 (LDS-only, transposed x1 out)
  k2x1_k<<<dim3(24, 16), 256, 0, stream>>>(lm, kb, vb, x1b);
  // kernel_1 (overwrites qt region — WqkvT/xb dead)
  k1_k<<<dim3(49, 24), 256, 0, stream>>>(qb, lm, k1b);

  // kb dead: build remaining transposed weights in its place
  twT_k<<<dim3(12, 24), 256, 0, stream>>>(Wpkv, 768, 1536, flagp, WpkvT);
  twT_k<<<dim3(12, 12), 256, 0, stream>>>(Wpq, 768, 768, flagp, WpqT);
  twT_k<<<dim3(12, 12), 256, 0, stream>>>(Wproj, 768, 768, flagp, WprojT);

  for (int c = 0; c < nchunks; ++c) {
    const int n0c = c * Nc;
    gemm_k<1><<<dim3((Nc + 127) / 128, 8, 24), 256, 0, stream>>>(
        k1b, x1b, Nc, 128, 128, 128, n0c, Nc, flagp, nullptr, xoc, xdc, nullptr, nullptr, nullptr);
    gemm_k<2><<<dim3((2 * Nc * 16) / 128, 12, 1), 256, 0, stream>>>(
        xoc, WpkvT, 2 * Nc * 16, 768, 768, 768, n0c, Nc, flagp, nullptr, k2c, v2c, nullptr, nullptr, nullptr);
    gemm_k<3><<<dim3((2 * Nc + 127) / 128, 6, 1), 256, 0, stream>>>(
        xdc, WpqT, 2 * Nc, 768, 768, 768, n0c, Nc, flagp, q2c, nullptr, nullptr, nullptr, nullptr, nullptr);
    attn_k<<<dim3((Nc + 63) / 64, 24), 256, 0, stream>>>(
        q2c, k2c, v2c, n0c, Nc, flagp, d_out, ob);
  }
  // out = o @ W_proj + b_proj
  gemm_k<4><<<dim3(49, 6, 1), 256, 0, stream>>>(ob, WprojT, 6272, 768, 768, 768, 0, 0, flagp,
                                                nullptr, nullptr, nullptr, nullptr, bproj, d_out);
}

// Round 5
// 1769.587 us; speedup vs baseline: 2.0795x; 1.0072x over previous
//
#include <hip/hip_runtime.h>

// TrajectoryAttention on MI355X (gfx950), chunked pipeline, dtype-adaptive.
// R13: gemm_k staging -> global_load_lds (direct HBM->LDS DMA). R12 was
//   reg-staged (global->VGPR->LDS) 2-barrier 128^2 = the ~650TF structure;
//   global_load_lds width=16 is the known +35-65% lever (guide m151/m193).
//   LDS tiles now LINEAR [128][32] u16 (gll writes wave-uniform base +
//   lane*16); bank conflicts fixed by both-sides XOR swizzle (T2/rule #21):
//   k-slot ^= (row ^ row>>2)&3 applied to the GLOBAL source addr at stage
//   time and to the ds_read offset. 16 rows x fixed lk -> every 4-bank span
//   hit exactly 2x = conflict-free. M-tail rows clamp source to M-1 (epilogue
//   already skips). Bit-identical numerics (same bf16 values, same MFMA order).
// R12 (kept): all GEMM operands pre-converted bf16 [n][k] (twT_k/xcvt_k);
//   x1b transposed; vectorized staging.
// R11 (kept): landmarks qT slice pinned in registers. R10: fence-free packed
//   u64 cross-block sync. R9: 8 blocks/head f64 dots. R8: transposed qT.
// R7  (kept): partitionable threefry idx0; chunked k2/v2.

using u16 = unsigned short;
using u32 = unsigned int;
using u64 = unsigned long long;

typedef short bf16x8 __attribute__((ext_vector_type(8)));
typedef float f32x4 __attribute__((ext_vector_type(4)));

#define N_ 3136
#define C_ 768
#define H_ 12
#define F_ 16
#define P_ 196
#define L_ 128
#define SC_ 0.35355339059327373f   // 64^-0.25
#define OUTPART_ ((size_t)2 * N_ * C_)
#define KB_ 8                      // blocks per head in landmarks
#define RPB_ 392                   // rows per block (3136/8)

__device__ __forceinline__ float b2f(u16 u) {
  u32 x = ((u32)u) << 16; float f; __builtin_memcpy(&f, &x, 4); return f;
}
__device__ __forceinline__ float lo16f(u32 u) {
  u32 x = u << 16; float f; __builtin_memcpy(&f, &x, 4); return f;
}
__device__ __forceinline__ float hi16f(u32 u) {
  u32 x = u & 0xFFFF0000u; float f; __builtin_memcpy(&f, &x, 4); return f;
}
__device__ __forceinline__ u16 f2b(float f) {
  u32 u; __builtin_memcpy(&u, &f, 4);
  u32 r = (u + 0x7FFFu + ((u >> 16) & 1u)) >> 16;
  return (u16)r;
}
__device__ __forceinline__ u64 d2u(double d) { u64 u; __builtin_memcpy(&u, &d, 8); return u; }

// direct global->LDS DMA, 16B per lane; lds base must be wave-uniform.
__device__ __forceinline__ void gll16(const void* g, void* l) {
  __builtin_amdgcn_global_load_lds(
      (__attribute__((address_space(1))) void*)g,
      (__attribute__((address_space(3))) void*)l, 16, 0, 0);
}

// dtype sniffer (bf16 vs f32 inputs) — votes f32 on this dataset (proven R4)
__global__ void detect_k(const u32* __restrict__ w, int* __restrict__ flag) {
  const int t = threadIdx.x;  // 64
  int hits = 0;
  #pragma unroll
  for (int i = 0; i < 16; ++i) {
    u32 word = w[t * 16 + i];
    u32 e = (word >> 7) & 0xFFu;
    if (e >= 110u && e <= 126u) hits++;
  }
  #pragma unroll
  for (int off = 32; off > 0; off >>= 1) hits += __shfl_down(hits, off);
  if (t == 0) flag[0] = (hits >= 512) ? 0 : 1;  // 0=bf16, 1=f32
}

// zero candidate slots (24 heads x 2 parity x 8 blocks = 384 u64).
__global__ void zcnt_k(u64* __restrict__ p) { if (threadIdx.x < 384) p[threadIdx.x] = 0ull; }

// ---- exact JAX threefry2x32-20 core ----
__device__ __forceinline__ void tf2(u32 k0, u32 k1v, u32 c0, u32 c1, u32& o0, u32& o1) {
  u32 ks[3] = {k0, k1v, k0 ^ k1v ^ 0x1BD11BDAu};
  u32 x0 = c0 + ks[0], x1 = c1 + ks[1];
  const u32 rA[4] = {13u, 15u, 26u, 6u}, rB[4] = {17u, 29u, 16u, 24u};
  #pragma unroll
  for (int r = 0; r < 5; ++r) {
    #pragma unroll
    for (int q = 0; q < 4; ++q) {
      u32 rot = (r & 1) ? rB[q] : rA[q];
      x0 += x1; x1 = (x1 << rot) | (x1 >> (32u - rot)); x1 ^= x0;
    }
    x0 += ks[(r + 1) % 3];
    x1 += ks[(r + 2) % 3] + (u32)(r + 1);
  }
  o0 = x0; o1 = x1;
}

// jax.random.randint(key(42), (24,), 0, 3136), partitionable — PROVEN (R7).
__device__ __forceinline__ int tf_idx0(int bh) {
  u32 a0, a1, b0, b1;
  tf2(0u, 42u, 0u, 0u, a0, a1);
  tf2(0u, 42u, 0u, 1u, b0, b1);
  u32 j = (u32)bh;
  u32 h0, h1, l0, l1;
  tf2(a0, a1, 0u, j, h0, h1);
  u32 hi = h0 ^ h1;
  tf2(b0, b1, 0u, j, l0, l1);
  u32 lo = l0 ^ l1;
  return (int)(((hi % 3136u) * 2048u + (lo % 3136u)) % 3136u);
}

// ---------------- selection-grade f32 GEMM -> TRANSPOSED qT[bh][d][n] ----------------
__global__ __launch_bounds__(256) void qselT_k(const void* __restrict__ xr, const void* __restrict__ wr,
                                               const int* __restrict__ flagp, float* __restrict__ qt)
{
  __shared__ float As[64 * 20];
  __shared__ float Bs[16 * 64];
  const int t = threadIdx.x;
  const int m0 = blockIdx.x * 64;
  const int n0 = blockIdx.y * 64;
  const int f32i = flagp[0];
  const int tx = t & 15, ty = t >> 4;
  float acc[4][4];
  #pragma unroll
  for (int i = 0; i < 4; ++i)
    #pragma unroll
    for (int j = 0; j < 4; ++j) acc[i][j] = 0.f;

  const int alr = t >> 2;
  const int alk = (t & 3) * 4;
  const int bkr = t >> 4;
  const int bnc = (t & 15) * 4;

  for (int k0 = 0; k0 < 768; k0 += 16) {
    float4 av, bv;
    if (f32i) {
      av = *(const float4*)((const float*)xr + (size_t)(m0 + alr) * 768 + k0 + alk);
      bv = *(const float4*)((const float*)wr + (size_t)(k0 + bkr) * 2304 + n0 + bnc);
    } else {
      const u16* xa = (const u16*)xr + (size_t)(m0 + alr) * 768 + k0 + alk;
      const u16* wa = (const u16*)wr + (size_t)(k0 + bkr) * 2304 + n0 + bnc;
      av.x = b2f(xa[0]); av.y = b2f(xa[1]); av.z = b2f(xa[2]); av.w = b2f(xa[3]);
      bv.x = b2f(wa[0]); bv.y = b2f(wa[1]); bv.z = b2f(wa[2]); bv.w = b2f(wa[3]);
    }
    As[alr * 20 + alk + 0] = av.x; As[alr * 20 + alk + 1] = av.y;
    As[alr * 20 + alk + 2] = av.z; As[alr * 20 + alk + 3] = av.w;
    *(float4*)(&Bs[bkr * 64 + bnc]) = bv;
    __syncthreads();
    #pragma unroll
    for (int kk = 0; kk < 16; ++kk) {
      float a[4], b[4];
      #pragma unroll
      for (int i = 0; i < 4; ++i) a[i] = As[(ty * 4 + i) * 20 + kk];
      #pragma unroll
      for (int j = 0; j < 4; ++j) b[j] = Bs[kk * 64 + tx * 4 + j];
      #pragma unroll
      for (int i = 0; i < 4; ++i)
        #pragma unroll
        for (int j = 0; j < 4; ++j) acc[i][j] += a[i] * b[j];
    }
    __syncthreads();
  }
  #pragma unroll
  for (int i = 0; i < 4; ++i) {
    const int m = m0 + ty * 4 + i;
    const int b = m / N_, n = m - b * N_;
    #pragma unroll
    for (int j = 0; j < 4; ++j) {
      const int col = n0 + tx * 4 + j;
      const int hh = col >> 6, dd = col & 63;
      qt[((size_t)(b * H_ + hh) * 64 + dd) * N_ + n] = acc[i][j] * SC_;
    }
  }
}

// ---------------- greedy landmarks: 8 blocks/head, register-resident slice ----------------
__global__ __launch_bounds__(512, 1) void landmarksR_k(
    const float* __restrict__ qt, float* __restrict__ lm, u64* __restrict__ cand)
{
  const int kb = blockIdx.x;
  const int bh = blockIdx.y;
  const float* QT = qt + (size_t)bh * 64 * N_;   // [d][n]
  float* LM = lm + (size_t)bh * L_ * 64;
  u64* cd = cand + (size_t)bh * 16;
  __shared__ double curD[64];
  __shared__ u64 redV[8];
  __shared__ int redI[8];
  __shared__ int sW;
  const int t = threadIdx.x;
  const bool act = (t < RPB_);
  const int g = t >> 2, dc = t & 3, d0 = dc * 16;
  const int r0 = kb * RPB_;
  const int myRow = r0 + t;
  const float* base = QT + r0 + 4 * g;

  float4 qreg[16];
  #pragma unroll
  for (int i = 0; i < 16; ++i) qreg[i] = (float4){0.f, 0.f, 0.f, 0.f};
  if (act) {
    #pragma unroll
    for (int i = 0; i < 16; ++i) qreg[i] = *(const float4*)(base + (size_t)(d0 + i) * N_);
  }

  double inv_own = 0.0, ms_own = 0.0;
  if (act) {
    double s0 = 0.0, s1 = 0.0, s2 = 0.0, s3 = 0.0;
    #pragma unroll
    for (int i = 0; i < 16; ++i) {
      const float4 v = qreg[i];
      s0 += (double)v.x * (double)v.x; s1 += (double)v.y * (double)v.y;
      s2 += (double)v.z * (double)v.z; s3 += (double)v.w * (double)v.w;
    }
    s0 += __shfl_xor(s0, 1); s1 += __shfl_xor(s1, 1);
    s2 += __shfl_xor(s2, 1); s3 += __shfl_xor(s3, 1);
    s0 += __shfl_xor(s0, 2); s1 += __shfl_xor(s1, 2);
    s2 += __shfl_xor(s2, 2); s3 += __shfl_xor(s3, 2);
    const double sown = (dc == 0) ? s0 : (dc == 1) ? s1 : (dc == 2) ? s2 : s3;
    inv_own = 1.0 / fmax(sqrt(sown), 1e-12);
  }
  const int idx0 = tf_idx0(bh);
  if (act && myRow == idx0) ms_own = 10.0;

  if (t < 64) {
    const float vf = QT[(size_t)t * N_ + idx0];
    double v = (double)vf;
    double s = v * v;
    #pragma unroll
    for (int off = 32; off; off >>= 1) s += __shfl_xor(s, off);
    curD[t] = v / fmax(sqrt(s), 1e-12);
    if (kb == 0) LM[t] = vf;
  }
  __syncthreads();

  for (int step = 1; step < 128; ++step) {
    u64 bV = d2u(1e30); int bI = 0x7fffffff;
    if (act) {
      double a0 = 0.0, a1 = 0.0, a2 = 0.0, a3 = 0.0;
      #pragma unroll
      for (int i = 0; i < 16; ++i) {
        const float4 v = qreg[i];
        const double c = curD[d0 + i];
        a0 += (double)v.x * c; a1 += (double)v.y * c;
        a2 += (double)v.z * c; a3 += (double)v.w * c;
      }
      a0 += __shfl_xor(a0, 1); a1 += __shfl_xor(a1, 1);
      a2 += __shfl_xor(a2, 1); a3 += __shfl_xor(a3, 1);
      a0 += __shfl_xor(a0, 2); a1 += __shfl_xor(a1, 2);
      a2 += __shfl_xor(a2, 2); a3 += __shfl_xor(a3, 2);
      const double aown = (dc == 0) ? a0 : (dc == 1) ? a1 : (dc == 2) ? a2 : a3;
      ms_own = fmax(ms_own, fabs(aown * inv_own));
      bV = d2u(ms_own); bI = myRow;
    }
    #pragma unroll
    for (int off = 32; off; off >>= 1) {
      const u64 ov = __shfl_xor(bV, off);
      const int oi = __shfl_xor(bI, off);
      if (ov < bV || (ov == bV && oi < bI)) { bV = ov; bI = oi; }
    }
    if ((t & 63) == 0) { redV[t >> 6] = bV; redI[t >> 6] = bI; }
    __syncthreads();
    const int par = step & 1;
    if (t == 0) {
      u64 v = redV[0]; int ix = redI[0];
      #pragma unroll
      for (int w2 = 1; w2 < 8; ++w2)
        if (redV[w2] < v || (redV[w2] == v && redI[w2] < ix)) { v = redV[w2]; ix = redI[w2]; }
      const u64 pk = (v & ~((1ull << 19) - 1ull)) | ((u64)(u32)(step & 127) << 12) | (u64)(u32)ix;
      __hip_atomic_store(&cd[par * KB_ + kb], pk, __ATOMIC_RELAXED, __HIP_MEMORY_SCOPE_AGENT);
    }
    if (t < 64) {
      u64 pv = ~0ull;
      int ok = 1;
      for (;;) {
        if (t < KB_) {
          pv = __hip_atomic_load(&cd[par * KB_ + t], __ATOMIC_RELAXED, __HIP_MEMORY_SCOPE_AGENT);
          ok = ((int)((pv >> 12) & 127u) == step) ? 1 : 0;
        }
        if (__all(ok)) break;
        __builtin_amdgcn_s_sleep(1);
      }
      u64 m = (t < KB_) ? pv : ~0ull;
      #pragma unroll
      for (int off = 1; off < KB_; off <<= 1) {
        const u64 o = __shfl_xor(m, off);
        if (o < m) m = o;
      }
      if (t == 0) sW = (int)(m & 0xFFFu);
    }
    __syncthreads();
    const int w = sW;
    if (act && myRow == w) ms_own = 10.0;
    if (t < 64) {
      const float vf = QT[(size_t)t * N_ + w];
      double v = (double)vf;
      double s = v * v;
      #pragma unroll
      for (int off = 32; off; off >>= 1) s += __shfl_xor(s, off);
      curD[t] = v / fmax(sqrt(s), 1e-12);
      if (kb == 0) LM[(size_t)step * 64 + t] = vf;
    }
    __syncthreads();
  }
}

// ---------------- weight transpose + bf16-ify: W[K][Nn] raw -> WT[Nn][K] bf16 ----------------
__global__ __launch_bounds__(256) void twT_k(const void* __restrict__ W, int K, int Nn,
                                             const int* __restrict__ flagp, u16* __restrict__ WT)
{
  __shared__ u16 Ts[64][80];   // [k][n] padded
  const int t = threadIdx.x;
  const int k0 = blockIdx.x * 64, n0 = blockIdx.y * 64;
  const int f32i = flagp[0];
  const int kr = t >> 2, nc = (t & 3) * 16;
  u16 tmp[16];
  if (f32i) {
    const float* p = (const float*)W + (size_t)(k0 + kr) * Nn + n0 + nc;
    #pragma unroll
    for (int j = 0; j < 16; ++j) tmp[j] = f2b(p[j]);
  } else {
    const u16* p = (const u16*)W + (size_t)(k0 + kr) * Nn + n0 + nc;
    #pragma unroll
    for (int j = 0; j < 16; ++j) tmp[j] = p[j];
  }
  #pragma unroll
  for (int j = 0; j < 16; ++j) Ts[kr][nc + j] = tmp[j];
  __syncthreads();
  const int nr = t >> 2, kc = (t & 3) * 16;
  u16 o[16];
  #pragma unroll
  for (int j = 0; j < 16; ++j) o[j] = Ts[kc + j][nr];
  u16* dst = WT + (size_t)(n0 + nr) * K + k0 + kc;
  *(uint4*)(dst) = *(uint4*)(o);
  *(uint4*)(dst + 8) = *(uint4*)(o + 8);
}

// ---------------- x -> bf16 (elementwise, 8/thread, 4816896 elems) ----------------
__global__ __launch_bounds__(256) void xcvt_k(const void* __restrict__ x,
                                              const int* __restrict__ flagp, u16* __restrict__ xb)
{
  const int i = blockIdx.x * 256 + threadIdx.x;  // 602112 threads exactly
  if (flagp[0]) {
    const float4* p = (const float4*)x + (size_t)i * 2;
    float4 f0 = p[0], f1 = p[1];
    u16 tmp[8] = { f2b(f0.x), f2b(f0.y), f2b(f0.z), f2b(f0.w),
                   f2b(f1.x), f2b(f1.y), f2b(f1.z), f2b(f1.w) };
    *(uint4*)(xb + (size_t)i * 8) = *(uint4*)tmp;
  } else {
    ((uint4*)xb)[i] = ((const uint4*)x)[i];
  }
}

// ---------------- generic 128x128 bf16 MFMA GEMM, global_load_lds staging ----
// A: bf16 [m][k] (lda), B: bf16 [n][k] (ldb). LDS linear [128][32] u16 with
// k-slot XOR swizzle swz(row)=(row^(row>>2))&3 applied to BOTH the global
// source address (stage) and the ds_read offset (both-sides-or-neither).
template <int MODE>
__global__ __launch_bounds__(256) void gemm_k(
    const void* __restrict__ Ap, const void* __restrict__ Bp,
    int M, int K, int lda, int ldb, int n0c, int cn, const int* __restrict__ flagp,
    float* __restrict__ of0, u16* __restrict__ ob0, u16* __restrict__ ob1, u16* __restrict__ ob2,
    const void* __restrict__ biasRaw, void* __restrict__ outRaw)
{
  __shared__ u16 As[128 * 32];
  __shared__ u16 Bs[128 * 32];
  const int t = threadIdx.x;
  const int m0 = blockIdx.x * 128;
  const int n0 = blockIdx.y * 128;
  const int rf = (MODE == 4) ? flagp[0] : 0;

  size_t aOff = 0, bOff = 0;
  if constexpr (MODE == 1) {
    const int bh = blockIdx.z;
    aOff = (size_t)bh * ((size_t)N_ * 128) + (size_t)n0c * 128;
    bOff = (size_t)bh * (1024 * 128);
  }
  const int lane = t & 63;
  const int w = t >> 6;
  const int mw = (w >> 1) * 64;
  const int nw = (w & 1) * 64;
  const int lr = lane & 15;
  const int lk = lane >> 4;

  f32x4 acc[4][4];
  #pragma unroll
  for (int i = 0; i < 4; ++i)
    #pragma unroll
    for (int j = 0; j < 4; ++j) acc[i][j] = (f32x4){0.f, 0.f, 0.f, 0.f};

  // ---- staging geometry: wave w fills 1KB chunks c0=(2w), c1=(2w+1) of each tile.
  // chunk c covers rows c*16..c*16+15 (64B/row); lane l -> row c*16 + (l>>2),
  // linear 16B slot (l&3). Source k-segment = slot ^ swz(row)  (pre-swizzle).
  const int c0 = w * 2, c1 = c0 + 1;
  const int rl = lane >> 2, sl = lane & 3;
  const int rowA0 = c0 * 16 + rl, rowA1 = c1 * 16 + rl;
  const int segA0 = (sl ^ ((rowA0 ^ (rowA0 >> 2)) & 3)) * 8;
  const int segA1 = (sl ^ ((rowA1 ^ (rowA1 >> 2)) & 3)) * 8;
  int ga0 = m0 + rowA0; if (ga0 >= M) ga0 = M - 1;   // tail clamp (epilogue skips)
  int ga1 = m0 + rowA1; if (ga1 >= M) ga1 = M - 1;
  const u16* A16 = (const u16*)Ap;
  const u16* B16 = (const u16*)Bp;
  const u16* aP0 = A16 + aOff + (size_t)ga0 * lda + segA0;
  const u16* aP1 = A16 + aOff + (size_t)ga1 * lda + segA1;
  const u16* bP0 = B16 + bOff + (size_t)(n0 + rowA0) * ldb + segA0;
  const u16* bP1 = B16 + bOff + (size_t)(n0 + rowA1) * ldb + segA1;
  u16* lA0 = &As[c0 * 512]; u16* lA1 = &As[c1 * 512];
  u16* lB0 = &Bs[c0 * 512]; u16* lB1 = &Bs[c1 * 512];

  // ---- swizzled ds_read offsets (u16 index): row*32 + (lk ^ swz(row))*8
  int roA[4], roB[4];
  #pragma unroll
  for (int q = 0; q < 4; ++q) {
    const int ra = mw + q * 16 + lr;
    roA[q] = ra * 32 + ((lk ^ ((ra ^ (ra >> 2)) & 3)) * 8);
    const int rb = nw + q * 16 + lr;
    roB[q] = rb * 32 + ((lk ^ ((rb ^ (rb >> 2)) & 3)) * 8);
  }

  for (int k0 = 0; k0 < K; k0 += 32) {
    gll16(aP0 + k0, lA0);
    gll16(aP1 + k0, lA1);
    gll16(bP0 + k0, lB0);
    gll16(bP1 + k0, lB1);
    __syncthreads();   // compiler drains vmcnt before s_barrier

    bf16x8 af[4], bfv[4];
    #pragma unroll
    for (int mt = 0; mt < 4; ++mt) af[mt] = *(const bf16x8*)(&As[roA[mt]]);
    #pragma unroll
    for (int nt = 0; nt < 4; ++nt) bfv[nt] = *(const bf16x8*)(&Bs[roB[nt]]);
    #pragma unroll
    for (int mt = 0; mt < 4; ++mt)
      #pragma unroll
      for (int nt = 0; nt < 4; ++nt)
        acc[mt][nt] = __builtin_amdgcn_mfma_f32_16x16x32_bf16(af[mt], bfv[nt], acc[mt][nt], 0, 0, 0);
    __syncthreads();
  }

  #pragma unroll
  for (int mt = 0; mt < 4; ++mt) {
    #pragma unroll
    for (int nt = 0; nt < 4; ++nt) {
      #pragma unroll
      for (int r = 0; r < 4; ++r) {
        const int grow = m0 + mw + mt * 16 + lk * 4 + r;
        const int gcol = n0 + nw + nt * 16 + lr;
        if (grow >= M) continue;
        float vv = acc[mt][nt][r];
        if constexpr (MODE == 0) {           // qkv -> qb,kb,vb bf16 (bh,N,64)
          int b = (grow >= N_) ? 1 : 0;
          int n = grow - b * N_;
          int t3 = gcol / C_, cc = gcol - t3 * C_;
          int hh = cc >> 6, dd = cc & 63;
          size_t dst = (((size_t)(b * H_ + hh)) * N_ + n) * 64 + dd;
          if (t3 == 0) ob0[dst] = f2b(vv * SC_);
          else if (t3 == 1) ob1[dst] = f2b(vv * SC_);
          else ob2[dst] = f2b(vv);
        } else if constexpr (MODE == 1) {    // xoc (B,cn,F,C) bf16 + xdiag side-write
          const int bh = blockIdx.z;
          int b = bh / H_, hh = bh - b * H_;
          int f = gcol >> 6, dd = gcol & 63;
          u16 wv = f2b(vv);
          ob0[(((size_t)(b * cn + grow)) * F_ + f) * C_ + hh * 64 + dd] = wv;
          int n = n0c + grow;
          if (f == n / P_) ob1[((size_t)(b * cn + grow)) * C_ + hh * 64 + dd] = wv;
        } else if constexpr (MODE == 2) {    // k2c,v2c (B,h,cn,F,d) bf16
          const int cn16 = cn * F_;
          int b = (grow >= cn16) ? 1 : 0;
          int r2 = grow - b * cn16;
          int ln = r2 >> 4, f = r2 & 15;
          int t2 = (gcol >= C_) ? 1 : 0, cc = gcol - t2 * C_;
          int hh = cc >> 6, dd = cc & 63;
          size_t dst = ((((size_t)(b * H_ + hh)) * cn + ln) * F_ + f) * 64 + dd;
          if (t2) ob1[dst] = f2b(vv); else ob0[dst] = f2b(vv);
        } else if constexpr (MODE == 3) {    // q2c (B,h,cn,d) f32, * 0.125
          int b = (grow >= cn) ? 1 : 0;
          int ln = grow - b * cn;
          int hh = gcol >> 6, dd = gcol & 63;
          of0[(((size_t)(b * H_ + hh)) * cn + ln) * 64 + dd] = vv * 0.125f;
        } else {                             // out = o@W_proj + b_proj, flag dtype
          float bvad = rf ? ((const float*)biasRaw)[gcol] : b2f(((const u16*)biasRaw)[gcol]);
          float ov = vv + bvad;
          if (rf) ((float*)outRaw)[(size_t)grow * C_ + gcol] = ov;
          else    ((u16*)outRaw)[(size_t)grow * C_ + gcol] = f2b(ov);
        }
      }
    }
  }
}

// ---------------- kernel_1 = softmax_l(q . lm^T), bf16 out ----------------
__global__ __launch_bounds__(256) void k1_k(const u16* __restrict__ qb,
                                            const float* __restrict__ lm,
                                            u16* __restrict__ k1)
{
  const int bh = blockIdx.y;
  const int r0 = blockIdx.x * 64;
  __shared__ float qT[64][65];
  __shared__ float lmS[128 * 64];
  __shared__ float redA[4][64];
  __shared__ float redB[64];
  const int t = threadIdx.x;
  const u16* Q = qb + ((size_t)bh * N_ + r0) * 64;
  const float* Lm = lm + (size_t)bh * L_ * 64;
  for (int u = t; u < 2048; u += 256) ((float4*)lmS)[u] = ((const float4*)Lm)[u];
  for (int u = t; u < 512; u += 256) {
    int row = u >> 3, j0 = (u & 7) * 8;
    uint4 pk = *(const uint4*)(Q + (size_t)row * 64 + j0);
    const u16* pu = (const u16*)&pk;
    #pragma unroll
    for (int jj = 0; jj < 8; ++jj) qT[j0 + jj][row] = b2f(pu[jj]);
  }
  __syncthreads();
  const int row = t & 63, ch = t >> 6;
  float qr[64];
  #pragma unroll
  for (int j = 0; j < 64; ++j) qr[j] = qT[j][row];
  float s[32];
  for (int li = 0; li < 32; ++li) {
    const float* lp = lmS + (ch * 32 + li) * 64;
    float a = 0.f;
    #pragma unroll
    for (int j = 0; j < 64; ++j) a += lp[j] * qr[j];
    s[li] = a;
  }
  float mx = -1e30f;
  for (int li = 0; li < 32; ++li) mx = fmaxf(mx, s[li]);
  redA[ch][row] = mx;
  __syncthreads();
  if (t < 64) redB[t] = fmaxf(fmaxf(redA[0][t], redA[1][t]), fmaxf(redA[2][t], redA[3][t]));
  __syncthreads();
  mx = redB[row];
  float sum = 0.f;
  for (int li = 0; li < 32; ++li) { float e = __expf(s[li] - mx); s[li] = e; sum += e; }
  __syncthreads();
  redA[ch][row] = sum;
  __syncthreads();
  if (t < 64) redB[t] = 1.0f / (redA[0][t] + redA[1][t] + redA[2][t] + redA[3][t]);
  __syncthreads();
  const float inv = redB[row];
  u16* out = k1 + ((size_t)bh * N_ + r0 + row) * 128 + ch * 32;
  for (int li = 0; li < 32; ++li) out[li] = f2b(s[li] * inv);
}

// ---------------- kernel_2 per frame + x1 = kernel_2 @ v  (LDS-only, 3-pass) ----------------
// x1 written TRANSPOSED: x1T[bh][n = f*64+dd][l], coalesced per-u across lanes.
__global__ __launch_bounds__(256) void k2x1_k(const float* __restrict__ lm,
                                              const u16* __restrict__ kb,
                                              const u16* __restrict__ vb,
                                              u16* __restrict__ x1)
{
  const int bh = blockIdx.x;
  const int f = blockIdx.y;
  __shared__ u16 kS[P_ * 64];
  __shared__ u16 vS[P_ * 64];
  __shared__ float redM[2][128];
  __shared__ float redS[2][128];
  const int t = threadIdx.x;
  const u16* Kf = kb + ((size_t)bh * N_ + f * P_) * 64;
  const u16* Vf = vb + ((size_t)bh * N_ + f * P_) * 64;
  for (int u = t; u < 1568; u += 256) {
    ((uint4*)kS)[u] = ((const uint4*)Kf)[u];
    ((uint4*)vS)[u] = ((const uint4*)Vf)[u];
  }
  __syncthreads();
  const int l = t & 127, half = t >> 7;
  const float* lp = lm + ((size_t)bh * L_ + l) * 64;
  float lr[64];
  #pragma unroll
  for (int j = 0; j < 64; ++j) lr[j] = lp[j];

  const int p0 = half * 98, p1 = p0 + 98;
  float mx = -1e30f;
  for (int p = p0; p < p1; ++p) {
    const uint4* kp = (const uint4*)(kS + p * 64);
    float s = 0.f;
    #pragma unroll
    for (int q4 = 0; q4 < 8; ++q4) {
      uint4 pk = kp[q4];
      const u32* pu = (const u32*)&pk;
      #pragma unroll
      for (int j2 = 0; j2 < 4; ++j2) {
        u32 u = pu[j2];
        s += lr[q4 * 8 + j2 * 2] * lo16f(u) + lr[q4 * 8 + j2 * 2 + 1] * hi16f(u);
      }
    }
    mx = fmaxf(mx, s);
  }
  redM[half][l] = mx;
  __syncthreads();
  mx = fmaxf(redM[0][l], redM[1][l]);

  float sm = 0.f;
  for (int p = p0; p < p1; ++p) {
    const uint4* kp = (const uint4*)(kS + p * 64);
    float s = 0.f;
    #pragma unroll
    for (int q4 = 0; q4 < 8; ++q4) {
      uint4 pk = kp[q4];
      const u32* pu = (const u32*)&pk;
      #pragma unroll
      for (int j2 = 0; j2 < 4; ++j2) {
        u32 u = pu[j2];
        s += lr[q4 * 8 + j2 * 2] * lo16f(u) + lr[q4 * 8 + j2 * 2 + 1] * hi16f(u);
      }
    }
    sm += __expf(s - mx);
  }
  redS[half][l] = sm;
  __syncthreads();
  const float inv = 1.0f / (redS[0][l] + redS[1][l]);

  const int dd0 = half * 32;
  float acc[32];
  #pragma unroll
  for (int u = 0; u < 32; ++u) acc[u] = 0.f;
  for (int p = 0; p < P_; ++p) {
    const uint4* kp = (const uint4*)(kS + p * 64);
    float s = 0.f;
    #pragma unroll
    for (int q4 = 0; q4 < 8; ++q4) {
      uint4 pk = kp[q4];
      const u32* pu = (const u32*)&pk;
      #pragma unroll
      for (int j2 = 0; j2 < 4; ++j2) {
        u32 u = pu[j2];
        s += lr[q4 * 8 + j2 * 2] * lo16f(u) + lr[q4 * 8 + j2 * 2 + 1] * hi16f(u);
      }
    }
    const float e = __expf(s - mx);
    const uint4* vp = (const uint4*)(vS + p * 64 + dd0);
    #pragma unroll
    for (int q4 = 0; q4 < 4; ++q4) {
      uint4 pv = vp[q4];
      const u32* pu = (const u32*)&pv;
      #pragma unroll
      for (int j2 = 0; j2 < 4; ++j2) {
        u32 u = pu[j2];
        acc[q4 * 8 + j2 * 2]     += e * lo16f(u);
        acc[q4 * 8 + j2 * 2 + 1] += e * hi16f(u);
      }
    }
  }
  // transposed store: x1T[bh][f*64 + dd][l]; per-u the 128 l-lanes are contiguous
  u16* outT = x1 + (size_t)bh * (1024 * 128) + (size_t)(f * 64 + dd0) * 128 + l;
  for (int u = 0; u < 32; ++u) outT[(size_t)u * 128] = f2b(acc[u] * inv);
}

// ---------------- final 16-way frame attention + o = attn @ v2 (chunked) ----------------
__global__ __launch_bounds__(256) void attn_k(const float* __restrict__ q2c,
                                              const u16* __restrict__ k2c,
                                              const u16* __restrict__ v2c,
                                              int n0c, int cn, const int* __restrict__ flagp,
                                              void* __restrict__ outRaw,
                                              u16* __restrict__ o)
{
  const int bh = blockIdx.y;
  const int b = bh / H_, hh = bh - b * H_;
  const int t = threadIdx.x;
  const int f32o = flagp[0];
  __shared__ float aS[64][17];
  const int nl = t >> 2, qi = t & 3;
  const int ln = blockIdx.x * 64 + nl;
  const bool act = ln < cn;
  const int n = n0c + ln;
  float q[64];
  if (act) {
    const float* qr = q2c + ((size_t)bh * cn + ln) * 64;
    #pragma unroll
    for (int j = 0; j < 64; ++j) q[j] = qr[j];
    float lg[4];
    #pragma unroll
    for (int ff = 0; ff < 4; ++ff) {
      const int f = qi * 4 + ff;
      const u16* kp = k2c + (((size_t)bh * cn + ln) * F_ + f) * 64;
      float s = 0.f;
      #pragma unroll
      for (int j8 = 0; j8 < 8; ++j8) {
        uint4 pk = ((const uint4*)kp)[j8];
        const u16* pu = (const u16*)&pk;
        #pragma unroll
        for (int u = 0; u < 8; ++u) s += q[j8 * 8 + u] * b2f(pu[u]);
      }
      lg[ff] = s;
    }
    float mx = fmaxf(fmaxf(lg[0], lg[1]), fmaxf(lg[2], lg[3]));
    mx = fmaxf(mx, __shfl_xor(mx, 1));
    mx = fmaxf(mx, __shfl_xor(mx, 2));
    float e[4], sm = 0.f;
    #pragma unroll
    for (int ff = 0; ff < 4; ++ff) { e[ff] = __expf(lg[ff] - mx); sm += e[ff]; }
    sm += __shfl_xor(sm, 1);
    sm += __shfl_xor(sm, 2);
    const float iv = 1.0f / sm;
    const size_t abase = ((size_t)bh * N_ + n) * F_ + qi * 4;
    #pragma unroll
    for (int ff = 0; ff < 4; ++ff) {
      const float a = e[ff] * iv;
      if (f32o) ((float*)outRaw)[OUTPART_ + abase + ff] = a;
      else      ((u16*)outRaw)[OUTPART_ + abase + ff] = f2b(a);
      aS[nl][qi * 4 + ff] = a;
    }
  }
  __syncthreads();
  if (act) {
    const int dd0 = qi * 16;
    float acc[16];
    #pragma unroll
    for (int u = 0; u < 16; ++u) acc[u] = 0.f;
    for (int f = 0; f < F_; ++f) {
      const float w2 = aS[nl][f];
      const u16* vp = v2c + (((size_t)bh * cn + ln) * F_ + f) * 64 + dd0;
      uint4 pv0 = ((const uint4*)vp)[0], pv1 = ((const uint4*)vp)[1];
      const u16* pu0 = (const u16*)&pv0;
      const u16* pu1 = (const u16*)&pv1;
      #pragma unroll
      for (int u = 0; u < 8; ++u) acc[u] += w2 * b2f(pu0[u]);
      #pragma unroll
      for (int u = 0; u < 8; ++u) acc[8 + u] += w2 * b2f(pu1[u]);
    }
    u16* op = o + ((size_t)(b * N_ + n)) * C_ + hh * 64 + dd0;
    for (int u = 0; u < 16; ++u) op[u] = f2b(acc[u]);
  }
}

extern "C" void kernel_launch(void* const* d_in, const int* in_sizes, int n_in,
                              void* d_out, int out_size, void* d_ws, size_t ws_size,
                              hipStream_t stream)
{
  (void)in_sizes; (void)n_in; (void)out_size;
  const void* x     = d_in[0];
  const void* Wqkv  = d_in[1];
  const void* Wpq   = d_in[2];
  const void* Wpkv  = d_in[3];
  const void* Wproj = d_in[4];
  const void* bproj = d_in[5];

  char* ws = (char*)d_ws;
  size_t off = 0;
  auto alloc = [&](size_t bytes) { void* p = ws + off; off += (bytes + 255) & ~(size_t)255; return p; };
  int*  flagp = (int*)alloc(256);
  u16*  qb  = (u16*)alloc(9633792);     // (bh,N,64) bf16, scaled
  u16*  kb  = (u16*)alloc(9633792);     // scaled; hosts WpkvT/WpqT/WprojT after k2x1
  u16*  vb  = (u16*)alloc(9633792);
  float* lm = (float*)alloc(786432);    // (bh,128,64) f32
  u16*  x1b = (u16*)alloc(6291456);     // (bh,1024,128) bf16 TRANSPOSED
  u16*  ob  = (u16*)alloc(9633792);     // (B,N,C) bf16
  const size_t k1off = off;             // qT f32 starts here (aliases k1b + chunk region)
  u16*  k1b = (u16*)alloc(19267584);    // (bh,N,128) bf16
  const size_t chunk0 = off;

  // qt region (19.27 MB at k1off): qselT/landmarks use it as f32 qT; after
  // landmarks it hosts WqkvT (3.54 MB) + xb (9.63 MB); k1b overwrites later.
  const size_t qtNeed = k1off + 19267584 + 256;

  int Nc = 0;
  {
    const int cands[5] = {3136, 1568, 784, 392, 196};
    for (int i = 0; i < 5; ++i) {
      size_t need = chunk0 + (size_t)156672 * cands[i] + 1024;
      if (need <= ws_size && qtNeed <= ws_size) { Nc = cands[i]; break; }
    }
  }
  if (Nc == 0) return;  // ws floor ~95.7 MB
  const int nchunks = N_ / Nc;
  u16*  xoc = (u16*)(ws + chunk0);                // (B,Nc,F,C) bf16
  u16*  k2c = xoc + (size_t)24576 * Nc;           // (B,h,Nc,F,d) bf16
  u16*  v2c = k2c + (size_t)24576 * Nc;
  u16*  xdc = v2c + (size_t)24576 * Nc;           // (B,Nc,C) bf16
  float* q2c = (float*)(xdc + (size_t)1536 * Nc); // (B,h,Nc,d) f32
  float* qt  = (float*)(ws + k1off);              // selection-grade f32 qT

  // bf16 staging buffers (zero ws growth):
  u16* WqkvT = (u16*)(ws + k1off);                 // [2304][768] bf16, 3538944 B
  u16* xb    = (u16*)(ws + k1off + 3538944);       // [6272][768] bf16, 9633792 B
  u16* WpkvT = kb;                                 // [1536][768] bf16 (kb dead post-k2x1)
  u16* WpqT  = kb + 1179648;                       // [768][768]
  u16* WprojT= kb + 1179648 + 589824;              // [768][768]

  // landmark candidate slots: 24 heads x 16 u64 = 3KB in chunk region (dead until loop)
  u64* cand = (u64*)(ws + chunk0);

  detect_k<<<1, 64, 0, stream>>>((const u32*)Wqkv, flagp);
  zcnt_k<<<1, 512, 0, stream>>>(cand);

  // selection-grade f32 qT (transposed), then register-resident landmarks
  qselT_k<<<dim3(98, 12), 256, 0, stream>>>(x, Wqkv, flagp, qt);
  landmarksR_k<<<dim3(KB_, 24), 512, 0, stream>>>(qt, lm, cand);

  // qt now dead: build bf16 operands in its place
  twT_k<<<dim3(12, 36), 256, 0, stream>>>(Wqkv, 768, 2304, flagp, WqkvT);
  xcvt_k<<<2352, 256, 0, stream>>>(x, flagp, xb);

  // qkv projection -> qb,kb,vb (global_load_lds staging)
  gemm_k<0><<<dim3(49, 18, 1), 256, 0, stream>>>(xb, WqkvT, 6272, 768, 768, 768, 0, 0, flagp,
                                                 nullptr, qb, kb, vb, nullptr, nullptr);
  // kernel_2 + x1 (LDS-only, transposed x1 out)
  k2x1_k<<<dim3(24, 16), 256, 0, stream>>>(lm, kb, vb, x1b);
  // kernel_1 (overwrites qt region — WqkvT/xb dead)
  k1_k<<<dim3(49, 24), 256, 0, stream>>>(qb, lm, k1b);

  // kb dead: build remaining transposed weights in its place
  twT_k<<<dim3(12, 24), 256, 0, stream>>>(Wpkv, 768, 1536, flagp, WpkvT);
  twT_k<<<dim3(12, 12), 256, 0, stream>>>(Wpq, 768, 768, flagp, WpqT);
  twT_k<<<dim3(12, 12), 256, 0, stream>>>(Wproj, 768, 768, flagp, WprojT);

  for (int c = 0; c < nchunks; ++c) {
    const int n0c = c * Nc;
    gemm_k<1><<<dim3((Nc + 127) / 128, 8, 24), 256, 0, stream>>>(
        k1b, x1b, Nc, 128, 128, 128, n0c, Nc, flagp, nullptr, xoc, xdc, nullptr, nullptr, nullptr);
    gemm_k<2><<<dim3((2 * Nc * 16) / 128, 12, 1), 256, 0, stream>>>(
        xoc, WpkvT, 2 * Nc * 16, 768, 768, 768, n0c, Nc, flagp, nullptr, k2c, v2c, nullptr, nullptr, nullptr);
    gemm_k<3><<<dim3((2 * Nc + 127) / 128, 6, 1), 256, 0, stream>>>(
        xdc, WpqT, 2 * Nc, 768, 768, 768, n0c, Nc, flagp, q2c, nullptr, nullptr, nullptr, nullptr, nullptr);
    attn_k<<<dim3((Nc + 63) / 64, 24), 256, 0, stream>>>(
        q2c, k2c, v2c, n0c, Nc, flagp, d_out, ob);
  }
  // out = o @ W_proj + b_proj
  gemm_k<4><<<dim3(49, 6, 1), 256, 0, stream>>>(ob, WprojT, 6272, 768, 768, 768, 0, 0, flagp,
                                                nullptr, nullptr, nullptr, nullptr, bproj, d_out);
}

// Round 6
// 1657.529 us; speedup vs baseline: 2.2201x; 1.0676x over previous
//
#include <hip/hip_runtime.h>

// TrajectoryAttention on MI355X (gfx950), chunked pipeline, dtype-adaptive.
// R14: three independent changes:
//  (1) landmarks grid swapped to (24, KB): linear block id = bh + 24*kb ->
//      XCD = bh%8 (id%8 round-robin), so all 8 blocks of a head share ONE XCD
//      and the cand line stays in their common local L2 -> barrier RTT ~5x
//      lower. Correctness is mapping-independent (agent-scope atomics).
//  (2) qselT: 128x64 tile, 8x4 acc/thread (was 64x64, 4x4) -> 12 LDS reads
//      per 32 FMAs. Per-output sequential-k FMA chain unchanged = bit-identical.
//  (3) chunk loop: gemm<2>+gemm<3> merged into one z-indexed dispatch
//      (runtime mode, identical K-loop); 3 weight transposes merged into one.
// R13 (kept): gemm staging via global_load_lds + both-sides XOR swizzle.
// R12 (kept): all GEMM operands pre-converted bf16 [n][k]; x1b transposed.
// R11 (kept): landmarks qT slice in registers. R10: fence-free packed-u64
//   cross-block sync. R9: 8 blocks/head f64 dots. R8: transposed qT.
// R7  (kept): partitionable threefry idx0; chunked k2/v2.

using u16 = unsigned short;
using u32 = unsigned int;
using u64 = unsigned long long;

typedef short bf16x8 __attribute__((ext_vector_type(8)));
typedef float f32x4 __attribute__((ext_vector_type(4)));

#define N_ 3136
#define C_ 768
#define H_ 12
#define F_ 16
#define P_ 196
#define L_ 128
#define SC_ 0.35355339059327373f   // 64^-0.25
#define OUTPART_ ((size_t)2 * N_ * C_)
#define KB_ 8                      // blocks per head in landmarks
#define RPB_ 392                   // rows per block (3136/8)

__device__ __forceinline__ float b2f(u16 u) {
  u32 x = ((u32)u) << 16; float f; __builtin_memcpy(&f, &x, 4); return f;
}
__device__ __forceinline__ float lo16f(u32 u) {
  u32 x = u << 16; float f; __builtin_memcpy(&f, &x, 4); return f;
}
__device__ __forceinline__ float hi16f(u32 u) {
  u32 x = u & 0xFFFF0000u; float f; __builtin_memcpy(&f, &x, 4); return f;
}
__device__ __forceinline__ u16 f2b(float f) {
  u32 u; __builtin_memcpy(&u, &f, 4);
  u32 r = (u + 0x7FFFu + ((u >> 16) & 1u)) >> 16;
  return (u16)r;
}
__device__ __forceinline__ u64 d2u(double d) { u64 u; __builtin_memcpy(&u, &d, 8); return u; }

// direct global->LDS DMA, 16B per lane; lds base must be wave-uniform.
__device__ __forceinline__ void gll16(const void* g, void* l) {
  __builtin_amdgcn_global_load_lds(
      (__attribute__((address_space(1))) void*)g,
      (__attribute__((address_space(3))) void*)l, 16, 0, 0);
}

// dtype sniffer (bf16 vs f32 inputs) — votes f32 on this dataset (proven R4)
__global__ void detect_k(const u32* __restrict__ w, int* __restrict__ flag) {
  const int t = threadIdx.x;  // 64
  int hits = 0;
  #pragma unroll
  for (int i = 0; i < 16; ++i) {
    u32 word = w[t * 16 + i];
    u32 e = (word >> 7) & 0xFFu;
    if (e >= 110u && e <= 126u) hits++;
  }
  #pragma unroll
  for (int off = 32; off > 0; off >>= 1) hits += __shfl_down(hits, off);
  if (t == 0) flag[0] = (hits >= 512) ? 0 : 1;  // 0=bf16, 1=f32
}

// zero candidate slots (24 heads x 2 parity x 8 blocks = 384 u64).
__global__ void zcnt_k(u64* __restrict__ p) { if (threadIdx.x < 384) p[threadIdx.x] = 0ull; }

// ---- exact JAX threefry2x32-20 core ----
__device__ __forceinline__ void tf2(u32 k0, u32 k1v, u32 c0, u32 c1, u32& o0, u32& o1) {
  u32 ks[3] = {k0, k1v, k0 ^ k1v ^ 0x1BD11BDAu};
  u32 x0 = c0 + ks[0], x1 = c1 + ks[1];
  const u32 rA[4] = {13u, 15u, 26u, 6u}, rB[4] = {17u, 29u, 16u, 24u};
  #pragma unroll
  for (int r = 0; r < 5; ++r) {
    #pragma unroll
    for (int q = 0; q < 4; ++q) {
      u32 rot = (r & 1) ? rB[q] : rA[q];
      x0 += x1; x1 = (x1 << rot) | (x1 >> (32u - rot)); x1 ^= x0;
    }
    x0 += ks[(r + 1) % 3];
    x1 += ks[(r + 2) % 3] + (u32)(r + 1);
  }
  o0 = x0; o1 = x1;
}

// jax.random.randint(key(42), (24,), 0, 3136), partitionable — PROVEN (R7).
__device__ __forceinline__ int tf_idx0(int bh) {
  u32 a0, a1, b0, b1;
  tf2(0u, 42u, 0u, 0u, a0, a1);
  tf2(0u, 42u, 0u, 1u, b0, b1);
  u32 j = (u32)bh;
  u32 h0, h1, l0, l1;
  tf2(a0, a1, 0u, j, h0, h1);
  u32 hi = h0 ^ h1;
  tf2(b0, b1, 0u, j, l0, l1);
  u32 lo = l0 ^ l1;
  return (int)(((hi % 3136u) * 2048u + (lo % 3136u)) % 3136u);
}

// ---------------- selection-grade f32 GEMM -> TRANSPOSED qT[bh][d][n] ----------------
// R14: 128x64 tile, 8x4 acc/thread. Per-output k-chain unchanged (bit-identical).
__global__ __launch_bounds__(256) void qselT_k(const void* __restrict__ xr, const void* __restrict__ wr,
                                               const int* __restrict__ flagp, float* __restrict__ qt)
{
  __shared__ float As[128 * 20];
  __shared__ float Bs[16 * 64];
  const int t = threadIdx.x;
  const int m0 = blockIdx.x * 128;
  const int n0 = blockIdx.y * 64;
  const int f32i = flagp[0];
  const int tx = t & 15, ty = t >> 4;
  float acc[8][4];
  #pragma unroll
  for (int i = 0; i < 8; ++i)
    #pragma unroll
    for (int j = 0; j < 4; ++j) acc[i][j] = 0.f;

  const int alr = t >> 1;               // A tile row (0..127)
  const int alk = (t & 1) * 8;          // A k offset (0 or 8)
  const int bkr = t >> 4;               // B k row (0..15)
  const int bnc = (t & 15) * 4;         // B col offset

  for (int k0 = 0; k0 < 768; k0 += 16) {
    float av[8];
    float4 bv;
    if (f32i) {
      const float* xa = (const float*)xr + (size_t)(m0 + alr) * 768 + k0 + alk;
      float4 a0 = *(const float4*)(xa);
      float4 a1 = *(const float4*)(xa + 4);
      av[0] = a0.x; av[1] = a0.y; av[2] = a0.z; av[3] = a0.w;
      av[4] = a1.x; av[5] = a1.y; av[6] = a1.z; av[7] = a1.w;
      bv = *(const float4*)((const float*)wr + (size_t)(k0 + bkr) * 2304 + n0 + bnc);
    } else {
      const u16* xa = (const u16*)xr + (size_t)(m0 + alr) * 768 + k0 + alk;
      #pragma unroll
      for (int j = 0; j < 8; ++j) av[j] = b2f(xa[j]);
      const u16* wa = (const u16*)wr + (size_t)(k0 + bkr) * 2304 + n0 + bnc;
      bv.x = b2f(wa[0]); bv.y = b2f(wa[1]); bv.z = b2f(wa[2]); bv.w = b2f(wa[3]);
    }
    #pragma unroll
    for (int j = 0; j < 8; ++j) As[alr * 20 + alk + j] = av[j];
    *(float4*)(&Bs[bkr * 64 + bnc]) = bv;
    __syncthreads();
    #pragma unroll
    for (int kk = 0; kk < 16; ++kk) {
      float a[8], b[4];
      #pragma unroll
      for (int i = 0; i < 8; ++i) a[i] = As[(ty * 8 + i) * 20 + kk];
      #pragma unroll
      for (int j = 0; j < 4; ++j) b[j] = Bs[kk * 64 + tx * 4 + j];
      #pragma unroll
      for (int i = 0; i < 8; ++i)
        #pragma unroll
        for (int j = 0; j < 4; ++j) acc[i][j] += a[i] * b[j];
    }
    __syncthreads();
  }
  #pragma unroll
  for (int i = 0; i < 8; ++i) {
    const int m = m0 + ty * 8 + i;
    const int b = m / N_, n = m - b * N_;
    #pragma unroll
    for (int j = 0; j < 4; ++j) {
      const int col = n0 + tx * 4 + j;
      const int hh = col >> 6, dd = col & 63;
      qt[((size_t)(b * H_ + hh) * 64 + dd) * N_ + n] = acc[i][j] * SC_;
    }
  }
}

// ---------------- greedy landmarks: 8 blocks/head (same XCD), register-resident slice ----
// R14 grid: (24, KB) -> linear id = bh + 24*kb -> XCD = bh%8: a head's 8
// blocks co-locate on one XCD; cand line served from their shared local L2.
__global__ __launch_bounds__(512, 1) void landmarksR_k(
    const float* __restrict__ qt, float* __restrict__ lm, u64* __restrict__ cand)
{
  const int kb = blockIdx.y;
  const int bh = blockIdx.x;
  const float* QT = qt + (size_t)bh * 64 * N_;   // [d][n]
  float* LM = lm + (size_t)bh * L_ * 64;
  u64* cd = cand + (size_t)bh * 16;
  __shared__ double curD[64];
  __shared__ u64 redV[8];
  __shared__ int redI[8];
  __shared__ int sW;
  const int t = threadIdx.x;
  const bool act = (t < RPB_);
  const int g = t >> 2, dc = t & 3, d0 = dc * 16;
  const int r0 = kb * RPB_;
  const int myRow = r0 + t;
  const float* base = QT + r0 + 4 * g;

  float4 qreg[16];
  #pragma unroll
  for (int i = 0; i < 16; ++i) qreg[i] = (float4){0.f, 0.f, 0.f, 0.f};
  if (act) {
    #pragma unroll
    for (int i = 0; i < 16; ++i) qreg[i] = *(const float4*)(base + (size_t)(d0 + i) * N_);
  }

  double inv_own = 0.0, ms_own = 0.0;
  if (act) {
    double s0 = 0.0, s1 = 0.0, s2 = 0.0, s3 = 0.0;
    #pragma unroll
    for (int i = 0; i < 16; ++i) {
      const float4 v = qreg[i];
      s0 += (double)v.x * (double)v.x; s1 += (double)v.y * (double)v.y;
      s2 += (double)v.z * (double)v.z; s3 += (double)v.w * (double)v.w;
    }
    s0 += __shfl_xor(s0, 1); s1 += __shfl_xor(s1, 1);
    s2 += __shfl_xor(s2, 1); s3 += __shfl_xor(s3, 1);
    s0 += __shfl_xor(s0, 2); s1 += __shfl_xor(s1, 2);
    s2 += __shfl_xor(s2, 2); s3 += __shfl_xor(s3, 2);
    const double sown = (dc == 0) ? s0 : (dc == 1) ? s1 : (dc == 2) ? s2 : s3;
    inv_own = 1.0 / fmax(sqrt(sown), 1e-12);
  }
  const int idx0 = tf_idx0(bh);
  if (act && myRow == idx0) ms_own = 10.0;

  if (t < 64) {
    const float vf = QT[(size_t)t * N_ + idx0];
    double v = (double)vf;
    double s = v * v;
    #pragma unroll
    for (int off = 32; off; off >>= 1) s += __shfl_xor(s, off);
    curD[t] = v / fmax(sqrt(s), 1e-12);
    if (kb == 0) LM[t] = vf;
  }
  __syncthreads();

  for (int step = 1; step < 128; ++step) {
    u64 bV = d2u(1e30); int bI = 0x7fffffff;
    if (act) {
      double a0 = 0.0, a1 = 0.0, a2 = 0.0, a3 = 0.0;
      #pragma unroll
      for (int i = 0; i < 16; ++i) {
        const float4 v = qreg[i];
        const double c = curD[d0 + i];
        a0 += (double)v.x * c; a1 += (double)v.y * c;
        a2 += (double)v.z * c; a3 += (double)v.w * c;
      }
      a0 += __shfl_xor(a0, 1); a1 += __shfl_xor(a1, 1);
      a2 += __shfl_xor(a2, 1); a3 += __shfl_xor(a3, 1);
      a0 += __shfl_xor(a0, 2); a1 += __shfl_xor(a1, 2);
      a2 += __shfl_xor(a2, 2); a3 += __shfl_xor(a3, 2);
      const double aown = (dc == 0) ? a0 : (dc == 1) ? a1 : (dc == 2) ? a2 : a3;
      ms_own = fmax(ms_own, fabs(aown * inv_own));
      bV = d2u(ms_own); bI = myRow;
    }
    #pragma unroll
    for (int off = 32; off; off >>= 1) {
      const u64 ov = __shfl_xor(bV, off);
      const int oi = __shfl_xor(bI, off);
      if (ov < bV || (ov == bV && oi < bI)) { bV = ov; bI = oi; }
    }
    if ((t & 63) == 0) { redV[t >> 6] = bV; redI[t >> 6] = bI; }
    __syncthreads();
    const int par = step & 1;
    if (t == 0) {
      u64 v = redV[0]; int ix = redI[0];
      #pragma unroll
      for (int w2 = 1; w2 < 8; ++w2)
        if (redV[w2] < v || (redV[w2] == v && redI[w2] < ix)) { v = redV[w2]; ix = redI[w2]; }
      const u64 pk = (v & ~((1ull << 19) - 1ull)) | ((u64)(u32)(step & 127) << 12) | (u64)(u32)ix;
      __hip_atomic_store(&cd[par * KB_ + kb], pk, __ATOMIC_RELAXED, __HIP_MEMORY_SCOPE_AGENT);
    }
    if (t < 64) {
      u64 pv = ~0ull;
      int ok = 1;
      for (;;) {
        if (t < KB_) {
          pv = __hip_atomic_load(&cd[par * KB_ + t], __ATOMIC_RELAXED, __HIP_MEMORY_SCOPE_AGENT);
          ok = ((int)((pv >> 12) & 127u) == step) ? 1 : 0;
        }
        if (__all(ok)) break;
        __builtin_amdgcn_s_sleep(1);
      }
      u64 m = (t < KB_) ? pv : ~0ull;
      #pragma unroll
      for (int off = 1; off < KB_; off <<= 1) {
        const u64 o = __shfl_xor(m, off);
        if (o < m) m = o;
      }
      if (t == 0) sW = (int)(m & 0xFFFu);
    }
    __syncthreads();
    const int w = sW;
    if (act && myRow == w) ms_own = 10.0;
    if (t < 64) {
      const float vf = QT[(size_t)t * N_ + w];
      double v = (double)vf;
      double s = v * v;
      #pragma unroll
      for (int off = 32; off; off >>= 1) s += __shfl_xor(s, off);
      curD[t] = v / fmax(sqrt(s), 1e-12);
      if (kb == 0) LM[(size_t)step * 64 + t] = vf;
    }
    __syncthreads();
  }
}

// ---------------- weight transpose + bf16-ify: W[K][Nn] raw -> WT[Nn][K] bf16 ----------------
__device__ __forceinline__ void twT_body(const void* W, int K, int Nn, int f32i,
                                         u16* WT, int k0, int n0, int t, u16 (&Ts)[64][80])
{
  const int kr = t >> 2, nc = (t & 3) * 16;
  u16 tmp[16];
  if (f32i) {
    const float* p = (const float*)W + (size_t)(k0 + kr) * Nn + n0 + nc;
    #pragma unroll
    for (int j = 0; j < 16; ++j) tmp[j] = f2b(p[j]);
  } else {
    const u16* p = (const u16*)W + (size_t)(k0 + kr) * Nn + n0 + nc;
    #pragma unroll
    for (int j = 0; j < 16; ++j) tmp[j] = p[j];
  }
  #pragma unroll
  for (int j = 0; j < 16; ++j) Ts[kr][nc + j] = tmp[j];
  __syncthreads();
  const int nr = t >> 2, kc = (t & 3) * 16;
  u16 o[16];
  #pragma unroll
  for (int j = 0; j < 16; ++j) o[j] = Ts[kc + j][nr];
  u16* dst = WT + (size_t)(n0 + nr) * K + k0 + kc;
  *(uint4*)(dst) = *(uint4*)(o);
  *(uint4*)(dst + 8) = *(uint4*)(o + 8);
}

__global__ __launch_bounds__(256) void twT_k(const void* __restrict__ W, int K, int Nn,
                                             const int* __restrict__ flagp, u16* __restrict__ WT)
{
  __shared__ u16 Ts[64][80];
  twT_body(W, K, Nn, flagp[0], WT, blockIdx.x * 64, blockIdx.y * 64, threadIdx.x, Ts);
}

// merged: z=0 Wpkv [768][1536], z=1 Wpq [768][768], z=2 Wproj [768][768]
__global__ __launch_bounds__(256) void twT3_k(const void* __restrict__ W0, const void* __restrict__ W1,
                                              const void* __restrict__ W2, const int* __restrict__ flagp,
                                              u16* __restrict__ T0, u16* __restrict__ T1, u16* __restrict__ T2)
{
  __shared__ u16 Ts[64][80];
  const int z = blockIdx.z;
  const void* W = (z == 0) ? W0 : (z == 1) ? W1 : W2;
  u16* WT = (z == 0) ? T0 : (z == 1) ? T1 : T2;
  const int Nn = (z == 0) ? 1536 : 768;
  if (blockIdx.y * 64 >= Nn) return;
  twT_body(W, 768, Nn, flagp[0], WT, blockIdx.x * 64, blockIdx.y * 64, threadIdx.x, Ts);
}

// ---------------- x -> bf16 (elementwise, 8/thread, 4816896 elems) ----------------
__global__ __launch_bounds__(256) void xcvt_k(const void* __restrict__ x,
                                              const int* __restrict__ flagp, u16* __restrict__ xb)
{
  const int i = blockIdx.x * 256 + threadIdx.x;  // 602112 threads exactly
  if (flagp[0]) {
    const float4* p = (const float4*)x + (size_t)i * 2;
    float4 f0 = p[0], f1 = p[1];
    u16 tmp[8] = { f2b(f0.x), f2b(f0.y), f2b(f0.z), f2b(f0.w),
                   f2b(f1.x), f2b(f1.y), f2b(f1.z), f2b(f1.w) };
    *(uint4*)(xb + (size_t)i * 8) = *(uint4*)tmp;
  } else {
    ((uint4*)xb)[i] = ((const uint4*)x)[i];
  }
}

// ---------------- shared GEMM core: global_load_lds staging + swizzled ds_read ----
struct GemmCore {
  const u16 *aP0, *aP1, *bP0, *bP1;
  u16 *lA0, *lA1, *lB0, *lB1;
  int roA[4], roB[4];
  int mw, nw, lr, lk;
};

__device__ __forceinline__ void gemm_core_init(GemmCore& gc, u16* As, u16* Bs,
    const u16* A16, const u16* B16, size_t aOff, size_t bOff,
    int m0, int n0, int lda, int ldb, int M, int t)
{
  const int lane = t & 63;
  const int w = t >> 6;
  gc.mw = (w >> 1) * 64;
  gc.nw = (w & 1) * 64;
  gc.lr = lane & 15;
  gc.lk = lane >> 4;
  const int c0 = w * 2, c1 = c0 + 1;
  const int rl = lane >> 2, sl = lane & 3;
  const int rowA0 = c0 * 16 + rl, rowA1 = c1 * 16 + rl;
  const int segA0 = (sl ^ ((rowA0 ^ (rowA0 >> 2)) & 3)) * 8;
  const int segA1 = (sl ^ ((rowA1 ^ (rowA1 >> 2)) & 3)) * 8;
  int ga0 = m0 + rowA0; if (ga0 >= M) ga0 = M - 1;
  int ga1 = m0 + rowA1; if (ga1 >= M) ga1 = M - 1;
  gc.aP0 = A16 + aOff + (size_t)ga0 * lda + segA0;
  gc.aP1 = A16 + aOff + (size_t)ga1 * lda + segA1;
  gc.bP0 = B16 + bOff + (size_t)(n0 + rowA0) * ldb + segA0;
  gc.bP1 = B16 + bOff + (size_t)(n0 + rowA1) * ldb + segA1;
  gc.lA0 = &As[c0 * 512]; gc.lA1 = &As[c1 * 512];
  gc.lB0 = &Bs[c0 * 512]; gc.lB1 = &Bs[c1 * 512];
  #pragma unroll
  for (int q = 0; q < 4; ++q) {
    const int ra = gc.mw + q * 16 + gc.lr;
    gc.roA[q] = ra * 32 + ((gc.lk ^ ((ra ^ (ra >> 2)) & 3)) * 8);
    const int rb = gc.nw + q * 16 + gc.lr;
    gc.roB[q] = rb * 32 + ((gc.lk ^ ((rb ^ (rb >> 2)) & 3)) * 8);
  }
}

__device__ __forceinline__ void gemm_core_loop(const GemmCore& gc, u16* As, u16* Bs,
                                               int K, f32x4 (&acc)[4][4])
{
  for (int k0 = 0; k0 < K; k0 += 32) {
    gll16(gc.aP0 + k0, gc.lA0);
    gll16(gc.aP1 + k0, gc.lA1);
    gll16(gc.bP0 + k0, gc.lB0);
    gll16(gc.bP1 + k0, gc.lB1);
    __syncthreads();
    bf16x8 af[4], bfv[4];
    #pragma unroll
    for (int mt = 0; mt < 4; ++mt) af[mt] = *(const bf16x8*)(&As[gc.roA[mt]]);
    #pragma unroll
    for (int nt = 0; nt < 4; ++nt) bfv[nt] = *(const bf16x8*)(&Bs[gc.roB[nt]]);
    #pragma unroll
    for (int mt = 0; mt < 4; ++mt)
      #pragma unroll
      for (int nt = 0; nt < 4; ++nt)
        acc[mt][nt] = __builtin_amdgcn_mfma_f32_16x16x32_bf16(af[mt], bfv[nt], acc[mt][nt], 0, 0, 0);
    __syncthreads();
  }
}

// ---------------- generic 128x128 bf16 MFMA GEMM, per-mode epilogues ----
template <int MODE>
__global__ __launch_bounds__(256) void gemm_k(
    const void* __restrict__ Ap, const void* __restrict__ Bp,
    int M, int K, int lda, int ldb, int n0c, int cn, const int* __restrict__ flagp,
    float* __restrict__ of0, u16* __restrict__ ob0, u16* __restrict__ ob1, u16* __restrict__ ob2,
    const void* __restrict__ biasRaw, void* __restrict__ outRaw)
{
  __shared__ u16 As[128 * 32];
  __shared__ u16 Bs[128 * 32];
  const int t = threadIdx.x;
  const int m0 = blockIdx.x * 128;
  const int n0 = blockIdx.y * 128;
  const int rf = (MODE == 4) ? flagp[0] : 0;

  size_t aOff = 0, bOff = 0;
  if constexpr (MODE == 1) {
    const int bh = blockIdx.z;
    aOff = (size_t)bh * ((size_t)N_ * 128) + (size_t)n0c * 128;
    bOff = (size_t)bh * (1024 * 128);
  }
  f32x4 acc[4][4];
  #pragma unroll
  for (int i = 0; i < 4; ++i)
    #pragma unroll
    for (int j = 0; j < 4; ++j) acc[i][j] = (f32x4){0.f, 0.f, 0.f, 0.f};

  GemmCore gc;
  gemm_core_init(gc, As, Bs, (const u16*)Ap, (const u16*)Bp, aOff, bOff, m0, n0, lda, ldb, M, t);
  gemm_core_loop(gc, As, Bs, K, acc);

  const int lr = gc.lr, lk = gc.lk, mw = gc.mw, nw = gc.nw;
  #pragma unroll
  for (int mt = 0; mt < 4; ++mt) {
    #pragma unroll
    for (int nt = 0; nt < 4; ++nt) {
      #pragma unroll
      for (int r = 0; r < 4; ++r) {
        const int grow = m0 + mw + mt * 16 + lk * 4 + r;
        const int gcol = n0 + nw + nt * 16 + lr;
        if (grow >= M) continue;
        float vv = acc[mt][nt][r];
        if constexpr (MODE == 0) {           // qkv -> qb,kb,vb bf16 (bh,N,64)
          int b = (grow >= N_) ? 1 : 0;
          int n = grow - b * N_;
          int t3 = gcol / C_, cc = gcol - t3 * C_;
          int hh = cc >> 6, dd = cc & 63;
          size_t dst = (((size_t)(b * H_ + hh)) * N_ + n) * 64 + dd;
          if (t3 == 0) ob0[dst] = f2b(vv * SC_);
          else if (t3 == 1) ob1[dst] = f2b(vv * SC_);
          else ob2[dst] = f2b(vv);
        } else if constexpr (MODE == 1) {    // xoc (B,cn,F,C) bf16 + xdiag side-write
          const int bh = blockIdx.z;
          int b = bh / H_, hh = bh - b * H_;
          int f = gcol >> 6, dd = gcol & 63;
          u16 wv = f2b(vv);
          ob0[(((size_t)(b * cn + grow)) * F_ + f) * C_ + hh * 64 + dd] = wv;
          int n = n0c + grow;
          if (f == n / P_) ob1[((size_t)(b * cn + grow)) * C_ + hh * 64 + dd] = wv;
        } else {                             // MODE 4: out = o@W_proj + b_proj
          float bvad = rf ? ((const float*)biasRaw)[gcol] : b2f(((const u16*)biasRaw)[gcol]);
          float ov = vv + bvad;
          if (rf) ((float*)outRaw)[(size_t)grow * C_ + gcol] = ov;
          else    ((u16*)outRaw)[(size_t)grow * C_ + gcol] = f2b(ov);
        }
      }
    }
  }
}

// ---------------- merged chunk GEMM: z=0 -> mode2 (k2c,v2c), z=1 -> mode3 (q2c) ----
__global__ __launch_bounds__(256) void gemm23_k(
    const u16* __restrict__ xoc, const u16* __restrict__ xdc,
    const u16* __restrict__ WpkvT, const u16* __restrict__ WpqT,
    int cn, float* __restrict__ q2c, u16* __restrict__ k2c, u16* __restrict__ v2c)
{
  __shared__ u16 As[128 * 32];
  __shared__ u16 Bs[128 * 32];
  const int t = threadIdx.x;
  const int z = blockIdx.z;
  const int m0 = blockIdx.x * 128;
  const int n0 = blockIdx.y * 128;
  const int M = z ? (2 * cn) : (2 * cn * F_);
  const int NN = z ? 768 : 1536;
  if (m0 >= M || n0 >= NN) return;
  const u16* Ap = z ? xdc : xoc;
  const u16* Bp = z ? WpqT : WpkvT;

  f32x4 acc[4][4];
  #pragma unroll
  for (int i = 0; i < 4; ++i)
    #pragma unroll
    for (int j = 0; j < 4; ++j) acc[i][j] = (f32x4){0.f, 0.f, 0.f, 0.f};

  GemmCore gc;
  gemm_core_init(gc, As, Bs, Ap, Bp, 0, 0, m0, n0, 768, 768, M, t);
  gemm_core_loop(gc, As, Bs, 768, acc);

  const int lr = gc.lr, lk = gc.lk, mw = gc.mw, nw = gc.nw;
  #pragma unroll
  for (int mt = 0; mt < 4; ++mt) {
    #pragma unroll
    for (int nt = 0; nt < 4; ++nt) {
      #pragma unroll
      for (int r = 0; r < 4; ++r) {
        const int grow = m0 + mw + mt * 16 + lk * 4 + r;
        const int gcol = n0 + nw + nt * 16 + lr;
        if (grow >= M) continue;
        float vv = acc[mt][nt][r];
        if (z == 0) {                        // k2c,v2c (B,h,cn,F,d) bf16
          const int cn16 = cn * F_;
          int b = (grow >= cn16) ? 1 : 0;
          int r2 = grow - b * cn16;
          int ln = r2 >> 4, f = r2 & 15;
          int t2 = (gcol >= C_) ? 1 : 0, cc = gcol - t2 * C_;
          int hh = cc >> 6, dd = cc & 63;
          size_t dst = ((((size_t)(b * H_ + hh)) * cn + ln) * F_ + f) * 64 + dd;
          if (t2) v2c[dst] = f2b(vv); else k2c[dst] = f2b(vv);
        } else {                             // q2c (B,h,cn,d) f32, * 0.125
          int b = (grow >= cn) ? 1 : 0;
          int ln = grow - b * cn;
          int hh = gcol >> 6, dd = gcol & 63;
          q2c[(((size_t)(b * H_ + hh)) * cn + ln) * 64 + dd] = vv * 0.125f;
        }
      }
    }
  }
}

// ---------------- kernel_1 = softmax_l(q . lm^T), bf16 out ----------------
__global__ __launch_bounds__(256) void k1_k(const u16* __restrict__ qb,
                                            const float* __restrict__ lm,
                                            u16* __restrict__ k1)
{
  const int bh = blockIdx.y;
  const int r0 = blockIdx.x * 64;
  __shared__ float qT[64][65];
  __shared__ float lmS[128 * 64];
  __shared__ float redA[4][64];
  __shared__ float redB[64];
  const int t = threadIdx.x;
  const u16* Q = qb + ((size_t)bh * N_ + r0) * 64;
  const float* Lm = lm + (size_t)bh * L_ * 64;
  for (int u = t; u < 2048; u += 256) ((float4*)lmS)[u] = ((const float4*)Lm)[u];
  for (int u = t; u < 512; u += 256) {
    int row = u >> 3, j0 = (u & 7) * 8;
    uint4 pk = *(const uint4*)(Q + (size_t)row * 64 + j0);
    const u16* pu = (const u16*)&pk;
    #pragma unroll
    for (int jj = 0; jj < 8; ++jj) qT[j0 + jj][row] = b2f(pu[jj]);
  }
  __syncthreads();
  const int row = t & 63, ch = t >> 6;
  float qr[64];
  #pragma unroll
  for (int j = 0; j < 64; ++j) qr[j] = qT[j][row];
  float s[32];
  for (int li = 0; li < 32; ++li) {
    const float* lp = lmS + (ch * 32 + li) * 64;
    float a = 0.f;
    #pragma unroll
    for (int j = 0; j < 64; ++j) a += lp[j] * qr[j];
    s[li] = a;
  }
  float mx = -1e30f;
  for (int li = 0; li < 32; ++li) mx = fmaxf(mx, s[li]);
  redA[ch][row] = mx;
  __syncthreads();
  if (t < 64) redB[t] = fmaxf(fmaxf(redA[0][t], redA[1][t]), fmaxf(redA[2][t], redA[3][t]));
  __syncthreads();
  mx = redB[row];
  float sum = 0.f;
  for (int li = 0; li < 32; ++li) { float e = __expf(s[li] - mx); s[li] = e; sum += e; }
  __syncthreads();
  redA[ch][row] = sum;
  __syncthreads();
  if (t < 64) redB[t] = 1.0f / (redA[0][t] + redA[1][t] + redA[2][t] + redA[3][t]);
  __syncthreads();
  const float inv = redB[row];
  u16* out = k1 + ((size_t)bh * N_ + r0 + row) * 128 + ch * 32;
  for (int li = 0; li < 32; ++li) out[li] = f2b(s[li] * inv);
}

// ---------------- kernel_2 per frame + x1 = kernel_2 @ v  (LDS-only, 3-pass) ----------------
// x1 written TRANSPOSED: x1T[bh][n = f*64+dd][l], coalesced per-u across lanes.
__global__ __launch_bounds__(256) void k2x1_k(const float* __restrict__ lm,
                                              const u16* __restrict__ kb,
                                              const u16* __restrict__ vb,
                                              u16* __restrict__ x1)
{
  const int bh = blockIdx.x;
  const int f = blockIdx.y;
  __shared__ u16 kS[P_ * 64];
  __shared__ u16 vS[P_ * 64];
  __shared__ float redM[2][128];
  __shared__ float redS[2][128];
  const int t = threadIdx.x;
  const u16* Kf = kb + ((size_t)bh * N_ + f * P_) * 64;
  const u16* Vf = vb + ((size_t)bh * N_ + f * P_) * 64;
  for (int u = t; u < 1568; u += 256) {
    ((uint4*)kS)[u] = ((const uint4*)Kf)[u];
    ((uint4*)vS)[u] = ((const uint4*)Vf)[u];
  }
  __syncthreads();
  const int l = t & 127, half = t >> 7;
  const float* lp = lm + ((size_t)bh * L_ + l) * 64;
  float lr[64];
  #pragma unroll
  for (int j = 0; j < 64; ++j) lr[j] = lp[j];

  const int p0 = half * 98, p1 = p0 + 98;
  float mx = -1e30f;
  for (int p = p0; p < p1; ++p) {
    const uint4* kp = (const uint4*)(kS + p * 64);
    float s = 0.f;
    #pragma unroll
    for (int q4 = 0; q4 < 8; ++q4) {
      uint4 pk = kp[q4];
      const u32* pu = (const u32*)&pk;
      #pragma unroll
      for (int j2 = 0; j2 < 4; ++j2) {
        u32 u = pu[j2];
        s += lr[q4 * 8 + j2 * 2] * lo16f(u) + lr[q4 * 8 + j2 * 2 + 1] * hi16f(u);
      }
    }
    mx = fmaxf(mx, s);
  }
  redM[half][l] = mx;
  __syncthreads();
  mx = fmaxf(redM[0][l], redM[1][l]);

  float sm = 0.f;
  for (int p = p0; p < p1; ++p) {
    const uint4* kp = (const uint4*)(kS + p * 64);
    float s = 0.f;
    #pragma unroll
    for (int q4 = 0; q4 < 8; ++q4) {
      uint4 pk = kp[q4];
      const u32* pu = (const u32*)&pk;
      #pragma unroll
      for (int j2 = 0; j2 < 4; ++j2) {
        u32 u = pu[j2];
        s += lr[q4 * 8 + j2 * 2] * lo16f(u) + lr[q4 * 8 + j2 * 2 + 1] * hi16f(u);
      }
    }
    sm += __expf(s - mx);
  }
  redS[half][l] = sm;
  __syncthreads();
  const float inv = 1.0f / (redS[0][l] + redS[1][l]);

  const int dd0 = half * 32;
  float acc[32];
  #pragma unroll
  for (int u = 0; u < 32; ++u) acc[u] = 0.f;
  for (int p = 0; p < P_; ++p) {
    const uint4* kp = (const uint4*)(kS + p * 64);
    float s = 0.f;
    #pragma unroll
    for (int q4 = 0; q4 < 8; ++q4) {
      uint4 pk = kp[q4];
      const u32* pu = (const u32*)&pk;
      #pragma unroll
      for (int j2 = 0; j2 < 4; ++j2) {
        u32 u = pu[j2];
        s += lr[q4 * 8 + j2 * 2] * lo16f(u) + lr[q4 * 8 + j2 * 2 + 1] * hi16f(u);
      }
    }
    const float e = __expf(s - mx);
    const uint4* vp = (const uint4*)(vS + p * 64 + dd0);
    #pragma unroll
    for (int q4 = 0; q4 < 4; ++q4) {
      uint4 pv = vp[q4];
      const u32* pu = (const u32*)&pv;
      #pragma unroll
      for (int j2 = 0; j2 < 4; ++j2) {
        u32 u = pu[j2];
        acc[q4 * 8 + j2 * 2]     += e * lo16f(u);
        acc[q4 * 8 + j2 * 2 + 1] += e * hi16f(u);
      }
    }
  }
  // transposed store: x1T[bh][f*64 + dd][l]; per-u the 128 l-lanes are contiguous
  u16* outT = x1 + (size_t)bh * (1024 * 128) + (size_t)(f * 64 + dd0) * 128 + l;
  for (int u = 0; u < 32; ++u) outT[(size_t)u * 128] = f2b(acc[u] * inv);
}

// ---------------- final 16-way frame attention + o = attn @ v2 (chunked) ----------------
__global__ __launch_bounds__(256) void attn_k(const float* __restrict__ q2c,
                                              const u16* __restrict__ k2c,
                                              const u16* __restrict__ v2c,
                                              int n0c, int cn, const int* __restrict__ flagp,
                                              void* __restrict__ outRaw,
                                              u16* __restrict__ o)
{
  const int bh = blockIdx.y;
  const int b = bh / H_, hh = bh - b * H_;
  const int t = threadIdx.x;
  const int f32o = flagp[0];
  __shared__ float aS[64][17];
  const int nl = t >> 2, qi = t & 3;
  const int ln = blockIdx.x * 64 + nl;
  const bool act = ln < cn;
  const int n = n0c + ln;
  float q[64];
  if (act) {
    const float* qr = q2c + ((size_t)bh * cn + ln) * 64;
    #pragma unroll
    for (int j = 0; j < 64; ++j) q[j] = qr[j];
    float lg[4];
    #pragma unroll
    for (int ff = 0; ff < 4; ++ff) {
      const int f = qi * 4 + ff;
      const u16* kp = k2c + (((size_t)bh * cn + ln) * F_ + f) * 64;
      float s = 0.f;
      #pragma unroll
      for (int j8 = 0; j8 < 8; ++j8) {
        uint4 pk = ((const uint4*)kp)[j8];
        const u16* pu = (const u16*)&pk;
        #pragma unroll
        for (int u = 0; u < 8; ++u) s += q[j8 * 8 + u] * b2f(pu[u]);
      }
      lg[ff] = s;
    }
    float mx = fmaxf(fmaxf(lg[0], lg[1]), fmaxf(lg[2], lg[3]));
    mx = fmaxf(mx, __shfl_xor(mx, 1));
    mx = fmaxf(mx, __shfl_xor(mx, 2));
    float e[4], sm = 0.f;
    #pragma unroll
    for (int ff = 0; ff < 4; ++ff) { e[ff] = __expf(lg[ff] - mx); sm += e[ff]; }
    sm += __shfl_xor(sm, 1);
    sm += __shfl_xor(sm, 2);
    const float iv = 1.0f / sm;
    const size_t abase = ((size_t)bh * N_ + n) * F_ + qi * 4;
    #pragma unroll
    for (int ff = 0; ff < 4; ++ff) {
      const float a = e[ff] * iv;
      if (f32o) ((float*)outRaw)[OUTPART_ + abase + ff] = a;
      else      ((u16*)outRaw)[OUTPART_ + abase + ff] = f2b(a);
      aS[nl][qi * 4 + ff] = a;
    }
  }
  __syncthreads();
  if (act) {
    const int dd0 = qi * 16;
    float acc[16];
    #pragma unroll
    for (int u = 0; u < 16; ++u) acc[u] = 0.f;
    for (int f = 0; f < F_; ++f) {
      const float w2 = aS[nl][f];
      const u16* vp = v2c + (((size_t)bh * cn + ln) * F_ + f) * 64 + dd0;
      uint4 pv0 = ((const uint4*)vp)[0], pv1 = ((const uint4*)vp)[1];
      const u16* pu0 = (const u16*)&pv0;
      const u16* pu1 = (const u16*)&pv1;
      #pragma unroll
      for (int u = 0; u < 8; ++u) acc[u] += w2 * b2f(pu0[u]);
      #pragma unroll
      for (int u = 0; u < 8; ++u) acc[8 + u] += w2 * b2f(pu1[u]);
    }
    u16* op = o + ((size_t)(b * N_ + n)) * C_ + hh * 64 + dd0;
    for (int u = 0; u < 16; ++u) op[u] = f2b(acc[u]);
  }
}

extern "C" void kernel_launch(void* const* d_in, const int* in_sizes, int n_in,
                              void* d_out, int out_size, void* d_ws, size_t ws_size,
                              hipStream_t stream)
{
  (void)in_sizes; (void)n_in; (void)out_size;
  const void* x     = d_in[0];
  const void* Wqkv  = d_in[1];
  const void* Wpq   = d_in[2];
  const void* Wpkv  = d_in[3];
  const void* Wproj = d_in[4];
  const void* bproj = d_in[5];

  char* ws = (char*)d_ws;
  size_t off = 0;
  auto alloc = [&](size_t bytes) { void* p = ws + off; off += (bytes + 255) & ~(size_t)255; return p; };
  int*  flagp = (int*)alloc(256);
  u16*  qb  = (u16*)alloc(9633792);     // (bh,N,64) bf16, scaled
  u16*  kb  = (u16*)alloc(9633792);     // scaled; hosts WpkvT/WpqT/WprojT after k2x1
  u16*  vb  = (u16*)alloc(9633792);
  float* lm = (float*)alloc(786432);    // (bh,128,64) f32
  u16*  x1b = (u16*)alloc(6291456);     // (bh,1024,128) bf16 TRANSPOSED
  u16*  ob  = (u16*)alloc(9633792);     // (B,N,C) bf16
  const size_t k1off = off;             // qT f32 starts here (aliases k1b + chunk region)
  u16*  k1b = (u16*)alloc(19267584);    // (bh,N,128) bf16
  const size_t chunk0 = off;

  // qt region (19.27 MB at k1off): qselT/landmarks use it as f32 qT; after
  // landmarks it hosts WqkvT (3.54 MB) + xb (9.63 MB); k1b overwrites later.
  const size_t qtNeed = k1off + 19267584 + 256;

  int Nc = 0;
  {
    const int cands[5] = {3136, 1568, 784, 392, 196};
    for (int i = 0; i < 5; ++i) {
      size_t need = chunk0 + (size_t)156672 * cands[i] + 1024;
      if (need <= ws_size && qtNeed <= ws_size) { Nc = cands[i]; break; }
    }
  }
  if (Nc == 0) return;  // ws floor ~95.7 MB
  const int nchunks = N_ / Nc;
  u16*  xoc = (u16*)(ws + chunk0);                // (B,Nc,F,C) bf16
  u16*  k2c = xoc + (size_t)24576 * Nc;           // (B,h,Nc,F,d) bf16
  u16*  v2c = k2c + (size_t)24576 * Nc;
  u16*  xdc = v2c + (size_t)24576 * Nc;           // (B,Nc,C) bf16
  float* q2c = (float*)(xdc + (size_t)1536 * Nc); // (B,h,Nc,d) f32
  float* qt  = (float*)(ws + k1off);              // selection-grade f32 qT

  // bf16 staging buffers (zero ws growth):
  u16* WqkvT = (u16*)(ws + k1off);                 // [2304][768] bf16, 3538944 B
  u16* xb    = (u16*)(ws + k1off + 3538944);       // [6272][768] bf16, 9633792 B
  u16* WpkvT = kb;                                 // [1536][768] bf16 (kb dead post-k2x1)
  u16* WpqT  = kb + 1179648;                       // [768][768]
  u16* WprojT= kb + 1179648 + 589824;              // [768][768]

  // landmark candidate slots: 24 heads x 16 u64 = 3KB in chunk region (dead until loop)
  u64* cand = (u64*)(ws + chunk0);

  detect_k<<<1, 64, 0, stream>>>((const u32*)Wqkv, flagp);
  zcnt_k<<<1, 512, 0, stream>>>(cand);

  // selection-grade f32 qT (transposed), then register-resident landmarks
  qselT_k<<<dim3(49, 12), 256, 0, stream>>>(x, Wqkv, flagp, qt);
  landmarksR_k<<<dim3(24, KB_), 512, 0, stream>>>(qt, lm, cand);

  // qt now dead: build bf16 operands in its place
  twT_k<<<dim3(12, 36), 256, 0, stream>>>(Wqkv, 768, 2304, flagp, WqkvT);
  xcvt_k<<<2352, 256, 0, stream>>>(x, flagp, xb);

  // qkv projection -> qb,kb,vb (global_load_lds staging)
  gemm_k<0><<<dim3(49, 18, 1), 256, 0, stream>>>(xb, WqkvT, 6272, 768, 768, 768, 0, 0, flagp,
                                                 nullptr, qb, kb, vb, nullptr, nullptr);
  // kernel_2 + x1 (LDS-only, transposed x1 out)
  k2x1_k<<<dim3(24, 16), 256, 0, stream>>>(lm, kb, vb, x1b);
  // kernel_1 (overwrites qt region — WqkvT/xb dead)
  k1_k<<<dim3(49, 24), 256, 0, stream>>>(qb, lm, k1b);

  // kb dead: build remaining transposed weights in its place (one merged dispatch)
  twT3_k<<<dim3(12, 24, 3), 256, 0, stream>>>(Wpkv, Wpq, Wproj, flagp, WpkvT, WpqT, WprojT);

  for (int c = 0; c < nchunks; ++c) {
    const int n0c = c * Nc;
    gemm_k<1><<<dim3((Nc + 127) / 128, 8, 24), 256, 0, stream>>>(
        k1b, x1b, Nc, 128, 128, 128, n0c, Nc, flagp, nullptr, xoc, xdc, nullptr, nullptr, nullptr);
    gemm23_k<<<dim3(Nc / 4, 12, 2), 256, 0, stream>>>(
        xoc, xdc, WpkvT, WpqT, Nc, q2c, k2c, v2c);
    attn_k<<<dim3((Nc + 63) / 64, 24), 256, 0, stream>>>(
        q2c, k2c, v2c, n0c, Nc, flagp, d_out, ob);
  }
  // out = o @ W_proj + b_proj
  gemm_k<4><<<dim3(49, 6, 1), 256, 0, stream>>>(ob, WprojT, 6272, 768, 768, 768, 0, 0, flagp,
                                                nullptr, nullptr, nullptr, nullptr, bproj, d_out);
}

// Round 7
// 1531.366 us; speedup vs baseline: 2.4030x; 1.0824x over previous
//
#include <hip/hip_runtime.h>

// TrajectoryAttention on MI355X (gfx950), chunked pipeline, dtype-adaptive.
// R15: attention REASSOCIATED — kills the 237-GFLOP xo@Wpkv GEMM (80% of
//   pipeline FLOPs). logits = q2.k2 = (q2@Wpkv_k^T).xo  -> g (7.4 GF, K=64);
//   out = attn@v2 = (attn@xo)@Wpkv_v -> wc (1.85 GF VALU) + GEMM (7.4 GF).
//   k2c/v2c never materialized. Per chunk: gemm1 -> q2b(M3) -> g(M5) ->
//   attn2 (per-token: logits from g.Xo, softmax, w=attn.Xo) -> ob(M6).
//   2 extra bf16 roundings on logits path (q2b, g) ~ same scale as the
//   k2c-bf16 rounding they replace.
// R14 (kept): landmarks 8 blocks/head co-located per XCD (grid 24,KB);
//   qselT 128x64 tile; merged transposes.
// R13 (kept): gemm staging via global_load_lds + both-sides XOR swizzle.
// R12 (kept): all GEMM operands pre-converted bf16 [n][k]; x1b transposed.
// R11 (kept): landmarks qT slice in registers. R10: fence-free packed-u64
//   cross-block sync. R9: 8 blocks/head f64 dots. R8: transposed qT.
// R7  (kept): partitionable threefry idx0.

using u16 = unsigned short;
using u32 = unsigned int;
using u64 = unsigned long long;

typedef short bf16x8 __attribute__((ext_vector_type(8)));
typedef float f32x4 __attribute__((ext_vector_type(4)));

#define N_ 3136
#define C_ 768
#define H_ 12
#define F_ 16
#define P_ 196
#define L_ 128
#define SC_ 0.35355339059327373f   // 64^-0.25
#define OUTPART_ ((size_t)2 * N_ * C_)
#define KB_ 8                      // blocks per head in landmarks
#define RPB_ 392                   // rows per block (3136/8)

__device__ __forceinline__ float b2f(u16 u) {
  u32 x = ((u32)u) << 16; float f; __builtin_memcpy(&f, &x, 4); return f;
}
__device__ __forceinline__ float lo16f(u32 u) {
  u32 x = u << 16; float f; __builtin_memcpy(&f, &x, 4); return f;
}
__device__ __forceinline__ float hi16f(u32 u) {
  u32 x = u & 0xFFFF0000u; float f; __builtin_memcpy(&f, &x, 4); return f;
}
__device__ __forceinline__ u16 f2b(float f) {
  u32 u; __builtin_memcpy(&u, &f, 4);
  u32 r = (u + 0x7FFFu + ((u >> 16) & 1u)) >> 16;
  return (u16)r;
}
__device__ __forceinline__ u64 d2u(double d) { u64 u; __builtin_memcpy(&u, &d, 8); return u; }

// direct global->LDS DMA, 16B per lane; lds base must be wave-uniform.
__device__ __forceinline__ void gll16(const void* g, void* l) {
  __builtin_amdgcn_global_load_lds(
      (__attribute__((address_space(1))) void*)g,
      (__attribute__((address_space(3))) void*)l, 16, 0, 0);
}

// dtype sniffer (bf16 vs f32 inputs) — votes f32 on this dataset (proven R4)
__global__ void detect_k(const u32* __restrict__ w, int* __restrict__ flag) {
  const int t = threadIdx.x;  // 64
  int hits = 0;
  #pragma unroll
  for (int i = 0; i < 16; ++i) {
    u32 word = w[t * 16 + i];
    u32 e = (word >> 7) & 0xFFu;
    if (e >= 110u && e <= 126u) hits++;
  }
  #pragma unroll
  for (int off = 32; off > 0; off >>= 1) hits += __shfl_down(hits, off);
  if (t == 0) flag[0] = (hits >= 512) ? 0 : 1;  // 0=bf16, 1=f32
}

// zero candidate slots (24 heads x 2 parity x 8 blocks = 384 u64).
__global__ void zcnt_k(u64* __restrict__ p) { if (threadIdx.x < 384) p[threadIdx.x] = 0ull; }

// ---- exact JAX threefry2x32-20 core ----
__device__ __forceinline__ void tf2(u32 k0, u32 k1v, u32 c0, u32 c1, u32& o0, u32& o1) {
  u32 ks[3] = {k0, k1v, k0 ^ k1v ^ 0x1BD11BDAu};
  u32 x0 = c0 + ks[0], x1 = c1 + ks[1];
  const u32 rA[4] = {13u, 15u, 26u, 6u}, rB[4] = {17u, 29u, 16u, 24u};
  #pragma unroll
  for (int r = 0; r < 5; ++r) {
    #pragma unroll
    for (int q = 0; q < 4; ++q) {
      u32 rot = (r & 1) ? rB[q] : rA[q];
      x0 += x1; x1 = (x1 << rot) | (x1 >> (32u - rot)); x1 ^= x0;
    }
    x0 += ks[(r + 1) % 3];
    x1 += ks[(r + 2) % 3] + (u32)(r + 1);
  }
  o0 = x0; o1 = x1;
}

// jax.random.randint(key(42), (24,), 0, 3136), partitionable — PROVEN (R7).
__device__ __forceinline__ int tf_idx0(int bh) {
  u32 a0, a1, b0, b1;
  tf2(0u, 42u, 0u, 0u, a0, a1);
  tf2(0u, 42u, 0u, 1u, b0, b1);
  u32 j = (u32)bh;
  u32 h0, h1, l0, l1;
  tf2(a0, a1, 0u, j, h0, h1);
  u32 hi = h0 ^ h1;
  tf2(b0, b1, 0u, j, l0, l1);
  u32 lo = l0 ^ l1;
  return (int)(((hi % 3136u) * 2048u + (lo % 3136u)) % 3136u);
}

// ---------------- selection-grade f32 GEMM -> TRANSPOSED qT[bh][d][n] ----------------
__global__ __launch_bounds__(256) void qselT_k(const void* __restrict__ xr, const void* __restrict__ wr,
                                               const int* __restrict__ flagp, float* __restrict__ qt)
{
  __shared__ float As[128 * 20];
  __shared__ float Bs[16 * 64];
  const int t = threadIdx.x;
  const int m0 = blockIdx.x * 128;
  const int n0 = blockIdx.y * 64;
  const int f32i = flagp[0];
  const int tx = t & 15, ty = t >> 4;
  float acc[8][4];
  #pragma unroll
  for (int i = 0; i < 8; ++i)
    #pragma unroll
    for (int j = 0; j < 4; ++j) acc[i][j] = 0.f;

  const int alr = t >> 1;               // A tile row (0..127)
  const int alk = (t & 1) * 8;          // A k offset (0 or 8)
  const int bkr = t >> 4;               // B k row (0..15)
  const int bnc = (t & 15) * 4;         // B col offset

  for (int k0 = 0; k0 < 768; k0 += 16) {
    float av[8];
    float4 bv;
    if (f32i) {
      const float* xa = (const float*)xr + (size_t)(m0 + alr) * 768 + k0 + alk;
      float4 a0 = *(const float4*)(xa);
      float4 a1 = *(const float4*)(xa + 4);
      av[0] = a0.x; av[1] = a0.y; av[2] = a0.z; av[3] = a0.w;
      av[4] = a1.x; av[5] = a1.y; av[6] = a1.z; av[7] = a1.w;
      bv = *(const float4*)((const float*)wr + (size_t)(k0 + bkr) * 2304 + n0 + bnc);
    } else {
      const u16* xa = (const u16*)xr + (size_t)(m0 + alr) * 768 + k0 + alk;
      #pragma unroll
      for (int j = 0; j < 8; ++j) av[j] = b2f(xa[j]);
      const u16* wa = (const u16*)wr + (size_t)(k0 + bkr) * 2304 + n0 + bnc;
      bv.x = b2f(wa[0]); bv.y = b2f(wa[1]); bv.z = b2f(wa[2]); bv.w = b2f(wa[3]);
    }
    #pragma unroll
    for (int j = 0; j < 8; ++j) As[alr * 20 + alk + j] = av[j];
    *(float4*)(&Bs[bkr * 64 + bnc]) = bv;
    __syncthreads();
    #pragma unroll
    for (int kk = 0; kk < 16; ++kk) {
      float a[8], b[4];
      #pragma unroll
      for (int i = 0; i < 8; ++i) a[i] = As[(ty * 8 + i) * 20 + kk];
      #pragma unroll
      for (int j = 0; j < 4; ++j) b[j] = Bs[kk * 64 + tx * 4 + j];
      #pragma unroll
      for (int i = 0; i < 8; ++i)
        #pragma unroll
        for (int j = 0; j < 4; ++j) acc[i][j] += a[i] * b[j];
    }
    __syncthreads();
  }
  #pragma unroll
  for (int i = 0; i < 8; ++i) {
    const int m = m0 + ty * 8 + i;
    const int b = m / N_, n = m - b * N_;
    #pragma unroll
    for (int j = 0; j < 4; ++j) {
      const int col = n0 + tx * 4 + j;
      const int hh = col >> 6, dd = col & 63;
      qt[((size_t)(b * H_ + hh) * 64 + dd) * N_ + n] = acc[i][j] * SC_;
    }
  }
}

// ---------------- greedy landmarks: 8 blocks/head (same XCD), register-resident slice ----
__global__ __launch_bounds__(512, 1) void landmarksR_k(
    const float* __restrict__ qt, float* __restrict__ lm, u64* __restrict__ cand)
{
  const int kb = blockIdx.y;
  const int bh = blockIdx.x;
  const float* QT = qt + (size_t)bh * 64 * N_;   // [d][n]
  float* LM = lm + (size_t)bh * L_ * 64;
  u64* cd = cand + (size_t)bh * 16;
  __shared__ double curD[64];
  __shared__ u64 redV[8];
  __shared__ int redI[8];
  __shared__ int sW;
  const int t = threadIdx.x;
  const bool act = (t < RPB_);
  const int g = t >> 2, dc = t & 3, d0 = dc * 16;
  const int r0 = kb * RPB_;
  const int myRow = r0 + t;
  const float* base = QT + r0 + 4 * g;

  float4 qreg[16];
  #pragma unroll
  for (int i = 0; i < 16; ++i) qreg[i] = (float4){0.f, 0.f, 0.f, 0.f};
  if (act) {
    #pragma unroll
    for (int i = 0; i < 16; ++i) qreg[i] = *(const float4*)(base + (size_t)(d0 + i) * N_);
  }

  double inv_own = 0.0, ms_own = 0.0;
  if (act) {
    double s0 = 0.0, s1 = 0.0, s2 = 0.0, s3 = 0.0;
    #pragma unroll
    for (int i = 0; i < 16; ++i) {
      const float4 v = qreg[i];
      s0 += (double)v.x * (double)v.x; s1 += (double)v.y * (double)v.y;
      s2 += (double)v.z * (double)v.z; s3 += (double)v.w * (double)v.w;
    }
    s0 += __shfl_xor(s0, 1); s1 += __shfl_xor(s1, 1);
    s2 += __shfl_xor(s2, 1); s3 += __shfl_xor(s3, 1);
    s0 += __shfl_xor(s0, 2); s1 += __shfl_xor(s1, 2);
    s0 = s0; s1 = s1;
    s2 += __shfl_xor(s2, 2); s3 += __shfl_xor(s3, 2);
    const double sown = (dc == 0) ? s0 : (dc == 1) ? s1 : (dc == 2) ? s2 : s3;
    inv_own = 1.0 / fmax(sqrt(sown), 1e-12);
  }
  const int idx0 = tf_idx0(bh);
  if (act && myRow == idx0) ms_own = 10.0;

  if (t < 64) {
    const float vf = QT[(size_t)t * N_ + idx0];
    double v = (double)vf;
    double s = v * v;
    #pragma unroll
    for (int off = 32; off; off >>= 1) s += __shfl_xor(s, off);
    curD[t] = v / fmax(sqrt(s), 1e-12);
    if (kb == 0) LM[t] = vf;
  }
  __syncthreads();

  for (int step = 1; step < 128; ++step) {
    u64 bV = d2u(1e30); int bI = 0x7fffffff;
    if (act) {
      double a0 = 0.0, a1 = 0.0, a2 = 0.0, a3 = 0.0;
      #pragma unroll
      for (int i = 0; i < 16; ++i) {
        const float4 v = qreg[i];
        const double c = curD[d0 + i];
        a0 += (double)v.x * c; a1 += (double)v.y * c;
        a2 += (double)v.z * c; a3 += (double)v.w * c;
      }
      a0 += __shfl_xor(a0, 1); a1 += __shfl_xor(a1, 1);
      a2 += __shfl_xor(a2, 1); a3 += __shfl_xor(a3, 1);
      a0 += __shfl_xor(a0, 2); a1 += __shfl_xor(a1, 2);
      a2 += __shfl_xor(a2, 2); a3 += __shfl_xor(a3, 2);
      const double aown = (dc == 0) ? a0 : (dc == 1) ? a1 : (dc == 2) ? a2 : a3;
      ms_own = fmax(ms_own, fabs(aown * inv_own));
      bV = d2u(ms_own); bI = myRow;
    }
    #pragma unroll
    for (int off = 32; off; off >>= 1) {
      const u64 ov = __shfl_xor(bV, off);
      const int oi = __shfl_xor(bI, off);
      if (ov < bV || (ov == bV && oi < bI)) { bV = ov; bI = oi; }
    }
    if ((t & 63) == 0) { redV[t >> 6] = bV; redI[t >> 6] = bI; }
    __syncthreads();
    const int par = step & 1;
    if (t == 0) {
      u64 v = redV[0]; int ix = redI[0];
      #pragma unroll
      for (int w2 = 1; w2 < 8; ++w2)
        if (redV[w2] < v || (redV[w2] == v && redI[w2] < ix)) { v = redV[w2]; ix = redI[w2]; }
      const u64 pk = (v & ~((1ull << 19) - 1ull)) | ((u64)(u32)(step & 127) << 12) | (u64)(u32)ix;
      __hip_atomic_store(&cd[par * KB_ + kb], pk, __ATOMIC_RELAXED, __HIP_MEMORY_SCOPE_AGENT);
    }
    if (t < 64) {
      u64 pv = ~0ull;
      int ok = 1;
      for (;;) {
        if (t < KB_) {
          pv = __hip_atomic_load(&cd[par * KB_ + t], __ATOMIC_RELAXED, __HIP_MEMORY_SCOPE_AGENT);
          ok = ((int)((pv >> 12) & 127u) == step) ? 1 : 0;
        }
        if (__all(ok)) break;
        __builtin_amdgcn_s_sleep(1);
      }
      u64 m = (t < KB_) ? pv : ~0ull;
      #pragma unroll
      for (int off = 1; off < KB_; off <<= 1) {
        const u64 o = __shfl_xor(m, off);
        if (o < m) m = o;
      }
      if (t == 0) sW = (int)(m & 0xFFFu);
    }
    __syncthreads();
    const int w = sW;
    if (act && myRow == w) ms_own = 10.0;
    if (t < 64) {
      const float vf = QT[(size_t)t * N_ + w];
      double v = (double)vf;
      double s = v * v;
      #pragma unroll
      for (int off = 32; off; off >>= 1) s += __shfl_xor(s, off);
      curD[t] = v / fmax(sqrt(s), 1e-12);
      if (kb == 0) LM[(size_t)step * 64 + t] = vf;
    }
    __syncthreads();
  }
}

// ---------------- weight transpose + bf16-ify: W[K][Nn] raw -> WT[Nn][K] bf16 ----------------
__device__ __forceinline__ void twT_body(const void* W, int K, int Nn, int f32i,
                                         u16* WT, int k0, int n0, int t, u16 (&Ts)[64][80])
{
  const int kr = t >> 2, nc = (t & 3) * 16;
  u16 tmp[16];
  if (f32i) {
    const float* p = (const float*)W + (size_t)(k0 + kr) * Nn + n0 + nc;
    #pragma unroll
    for (int j = 0; j < 16; ++j) tmp[j] = f2b(p[j]);
  } else {
    const u16* p = (const u16*)W + (size_t)(k0 + kr) * Nn + n0 + nc;
    #pragma unroll
    for (int j = 0; j < 16; ++j) tmp[j] = p[j];
  }
  #pragma unroll
  for (int j = 0; j < 16; ++j) Ts[kr][nc + j] = tmp[j];
  __syncthreads();
  const int nr = t >> 2, kc = (t & 3) * 16;
  u16 o[16];
  #pragma unroll
  for (int j = 0; j < 16; ++j) o[j] = Ts[kc + j][nr];
  u16* dst = WT + (size_t)(n0 + nr) * K + k0 + kc;
  *(uint4*)(dst) = *(uint4*)(o);
  *(uint4*)(dst + 8) = *(uint4*)(o + 8);
}

__global__ __launch_bounds__(256) void twT_k(const void* __restrict__ W, int K, int Nn,
                                             const int* __restrict__ flagp, u16* __restrict__ WT)
{
  __shared__ u16 Ts[64][80];
  twT_body(W, K, Nn, flagp[0], WT, blockIdx.x * 64, blockIdx.y * 64, threadIdx.x, Ts);
}

// merged: z=0 Wpkv^T, z=1 Wpq^T, z=2 Wproj^T, z=3 Wpkv plain bf16 copy (original layout)
__global__ __launch_bounds__(256) void twT3_k(const void* __restrict__ W0, const void* __restrict__ W1,
                                              const void* __restrict__ W2, const int* __restrict__ flagp,
                                              u16* __restrict__ T0, u16* __restrict__ T1, u16* __restrict__ T2,
                                              u16* __restrict__ Wb)
{
  __shared__ u16 Ts[64][80];
  const int z = blockIdx.z;
  const int t = threadIdx.x;
  if (z == 3) {                       // plain convert Wpkv [768][1536] -> bf16
    const int k0 = blockIdx.x * 64, n0 = blockIdx.y * 64;
    const int kr = t >> 2, nc = (t & 3) * 16;
    u16 tmp[16];
    if (flagp[0]) {
      const float* p = (const float*)W0 + (size_t)(k0 + kr) * 1536 + n0 + nc;
      #pragma unroll
      for (int j = 0; j < 16; ++j) tmp[j] = f2b(p[j]);
    } else {
      const u16* p = (const u16*)W0 + (size_t)(k0 + kr) * 1536 + n0 + nc;
      #pragma unroll
      for (int j = 0; j < 16; ++j) tmp[j] = p[j];
    }
    u16* dst = Wb + (size_t)(k0 + kr) * 1536 + n0 + nc;
    *(uint4*)(dst) = *(uint4*)(tmp);
    *(uint4*)(dst + 8) = *(uint4*)(tmp + 8);
    return;
  }
  const void* W = (z == 0) ? W0 : (z == 1) ? W1 : W2;
  u16* WT = (z == 0) ? T0 : (z == 1) ? T1 : T2;
  const int Nn = (z == 0) ? 1536 : 768;
  if (blockIdx.y * 64 >= Nn) return;
  twT_body(W, 768, Nn, flagp[0], WT, blockIdx.x * 64, blockIdx.y * 64, t, Ts);
}

// ---------------- x -> bf16 (elementwise, 8/thread, 4816896 elems) ----------------
__global__ __launch_bounds__(256) void xcvt_k(const void* __restrict__ x,
                                              const int* __restrict__ flagp, u16* __restrict__ xb)
{
  const int i = blockIdx.x * 256 + threadIdx.x;  // 602112 threads exactly
  if (flagp[0]) {
    const float4* p = (const float4*)x + (size_t)i * 2;
    float4 f0 = p[0], f1 = p[1];
    u16 tmp[8] = { f2b(f0.x), f2b(f0.y), f2b(f0.z), f2b(f0.w),
                   f2b(f1.x), f2b(f1.y), f2b(f1.z), f2b(f1.w) };
    *(uint4*)(xb + (size_t)i * 8) = *(uint4*)tmp;
  } else {
    ((uint4*)xb)[i] = ((const uint4*)x)[i];
  }
}

// ---------------- shared GEMM core: global_load_lds staging + swizzled ds_read ----
struct GemmCore {
  const u16 *aP0, *aP1, *bP0, *bP1;
  u16 *lA0, *lA1, *lB0, *lB1;
  int roA[4], roB[4];
  int mw, nw, lr, lk;
};

__device__ __forceinline__ void gemm_core_init(GemmCore& gc, u16* As, u16* Bs,
    const u16* A16, const u16* B16, size_t aOff, size_t bOff,
    int m0, int n0, int lda, int ldb, int M, int t)
{
  const int lane = t & 63;
  const int w = t >> 6;
  gc.mw = (w >> 1) * 64;
  gc.nw = (w & 1) * 64;
  gc.lr = lane & 15;
  gc.lk = lane >> 4;
  const int c0 = w * 2, c1 = c0 + 1;
  const int rl = lane >> 2, sl = lane & 3;
  const int rowA0 = c0 * 16 + rl, rowA1 = c1 * 16 + rl;
  const int segA0 = (sl ^ ((rowA0 ^ (rowA0 >> 2)) & 3)) * 8;
  const int segA1 = (sl ^ ((rowA1 ^ (rowA1 >> 2)) & 3)) * 8;
  int ga0 = m0 + rowA0; if (ga0 >= M) ga0 = M - 1;
  int ga1 = m0 + rowA1; if (ga1 >= M) ga1 = M - 1;
  gc.aP0 = A16 + aOff + (size_t)ga0 * lda + segA0;
  gc.aP1 = A16 + aOff + (size_t)ga1 * lda + segA1;
  gc.bP0 = B16 + bOff + (size_t)(n0 + rowA0) * ldb + segA0;
  gc.bP1 = B16 + bOff + (size_t)(n0 + rowA1) * ldb + segA1;
  gc.lA0 = &As[c0 * 512]; gc.lA1 = &As[c1 * 512];
  gc.lB0 = &Bs[c0 * 512]; gc.lB1 = &Bs[c1 * 512];
  #pragma unroll
  for (int q = 0; q < 4; ++q) {
    const int ra = gc.mw + q * 16 + gc.lr;
    gc.roA[q] = ra * 32 + ((gc.lk ^ ((ra ^ (ra >> 2)) & 3)) * 8);
    const int rb = gc.nw + q * 16 + gc.lr;
    gc.roB[q] = rb * 32 + ((gc.lk ^ ((rb ^ (rb >> 2)) & 3)) * 8);
  }
}

__device__ __forceinline__ void gemm_core_loop(const GemmCore& gc, u16* As, u16* Bs,
                                               int K, f32x4 (&acc)[4][4])
{
  for (int k0 = 0; k0 < K; k0 += 32) {
    gll16(gc.aP0 + k0, gc.lA0);
    gll16(gc.aP1 + k0, gc.lA1);
    gll16(gc.bP0 + k0, gc.lB0);
    gll16(gc.bP1 + k0, gc.lB1);
    __syncthreads();
    bf16x8 af[4], bfv[4];
    #pragma unroll
    for (int mt = 0; mt < 4; ++mt) af[mt] = *(const bf16x8*)(&As[gc.roA[mt]]);
    #pragma unroll
    for (int nt = 0; nt < 4; ++nt) bfv[nt] = *(const bf16x8*)(&Bs[gc.roB[nt]]);
    #pragma unroll
    for (int mt = 0; mt < 4; ++mt)
      #pragma unroll
      for (int nt = 0; nt < 4; ++nt)
        acc[mt][nt] = __builtin_amdgcn_mfma_f32_16x16x32_bf16(af[mt], bfv[nt], acc[mt][nt], 0, 0, 0);
    __syncthreads();
  }
}

// ---------------- generic 128x128 bf16 MFMA GEMM, per-mode epilogues ----
// MODE 0: qkv->qb,kb,vb | 1: xoc+xdc | 3: q2b | 4: final out | 5: g | 6: ob part
template <int MODE>
__global__ __launch_bounds__(256) void gemm_k(
    const void* __restrict__ Ap, const void* __restrict__ Bp,
    int M, int K, int lda, int ldb, int n0c, int cn, const int* __restrict__ flagp,
    float* __restrict__ of0, u16* __restrict__ ob0, u16* __restrict__ ob1, u16* __restrict__ ob2,
    const void* __restrict__ biasRaw, void* __restrict__ outRaw)
{
  __shared__ u16 As[128 * 32];
  __shared__ u16 Bs[128 * 32];
  const int t = threadIdx.x;
  const int m0 = blockIdx.x * 128;
  const int n0 = blockIdx.y * 128;
  const int rf = (MODE == 4) ? flagp[0] : 0;

  size_t aOff = 0, bOff = 0;
  if constexpr (MODE == 1) {
    const int bh = blockIdx.z;
    aOff = (size_t)bh * ((size_t)N_ * 128) + (size_t)n0c * 128;
    bOff = (size_t)bh * (1024 * 128);
  }
  if constexpr (MODE == 5) {
    const int h = blockIdx.z;
    aOff = (size_t)h * (2 * cn) * 64;
    bOff = (size_t)h * 64;
  }
  if constexpr (MODE == 6) {
    const int h = blockIdx.z;
    aOff = (size_t)h * (2 * cn) * 768;
    bOff = (size_t)(768 + h * 64) * 768;
  }
  f32x4 acc[4][4];
  #pragma unroll
  for (int i = 0; i < 4; ++i)
    #pragma unroll
    for (int j = 0; j < 4; ++j) acc[i][j] = (f32x4){0.f, 0.f, 0.f, 0.f};

  GemmCore gc;
  gemm_core_init(gc, As, Bs, (const u16*)Ap, (const u16*)Bp, aOff, bOff, m0, n0, lda, ldb, M, t);
  gemm_core_loop(gc, As, Bs, K, acc);

  const int lr = gc.lr, lk = gc.lk, mw = gc.mw, nw = gc.nw;
  #pragma unroll
  for (int mt = 0; mt < 4; ++mt) {
    #pragma unroll
    for (int nt = 0; nt < 4; ++nt) {
      #pragma unroll
      for (int r = 0; r < 4; ++r) {
        const int grow = m0 + mw + mt * 16 + lk * 4 + r;
        const int gcol = n0 + nw + nt * 16 + lr;
        if (grow >= M) continue;
        float vv = acc[mt][nt][r];
        if constexpr (MODE == 0) {           // qkv -> qb,kb,vb bf16 (bh,N,64)
          int b = (grow >= N_) ? 1 : 0;
          int n = grow - b * N_;
          int t3 = gcol / C_, cc = gcol - t3 * C_;
          int hh = cc >> 6, dd = cc & 63;
          size_t dst = (((size_t)(b * H_ + hh)) * N_ + n) * 64 + dd;
          if (t3 == 0) ob0[dst] = f2b(vv * SC_);
          else if (t3 == 1) ob1[dst] = f2b(vv * SC_);
          else ob2[dst] = f2b(vv);
        } else if constexpr (MODE == 1) {    // xoc (B,cn,F,C) bf16 + xdiag side-write
          const int bh = blockIdx.z;
          int b = bh / H_, hh = bh - b * H_;
          int f = gcol >> 6, dd = gcol & 63;
          u16 wv = f2b(vv);
          ob0[(((size_t)(b * cn + grow)) * F_ + f) * C_ + hh * 64 + dd] = wv;
          int n = n0c + grow;
          if (f == n / P_) ob1[((size_t)(b * cn + grow)) * C_ + hh * 64 + dd] = wv;
        } else if constexpr (MODE == 3) {    // q2b [h][2cn][64] bf16, * 0.125
          int hh = gcol >> 6, dd = gcol & 63;
          ob0[((size_t)hh * (2 * cn) + grow) * 64 + dd] = f2b(vv * 0.125f);
        } else if constexpr (MODE == 5) {    // g [h][2cn][768] bf16
          ob0[((size_t)blockIdx.z * (2 * cn) + grow) * 768 + gcol] = f2b(vv);
        } else if constexpr (MODE == 6) {    // ob part: out_h = wc_h @ Wpkv_v_h
          if (gcol < 64) {
            int b2 = (grow >= cn) ? 1 : 0;
            int ln = grow - b2 * cn;
            ob0[((size_t)(b2 * N_ + n0c + ln)) * 768 + blockIdx.z * 64 + gcol] = f2b(vv);
          }
        } else {                             // MODE 4: out = o@W_proj + b_proj
          float bvad = rf ? ((const float*)biasRaw)[gcol] : b2f(((const u16*)biasRaw)[gcol]);
          float ov = vv + bvad;
          if (rf) ((float*)outRaw)[(size_t)grow * C_ + gcol] = ov;
          else    ((u16*)outRaw)[(size_t)grow * C_ + gcol] = f2b(ov);
        }
      }
    }
  }
}

// ---------------- kernel_1 = softmax_l(q . lm^T), bf16 out ----------------
__global__ __launch_bounds__(256) void k1_k(const u16* __restrict__ qb,
                                            const float* __restrict__ lm,
                                            u16* __restrict__ k1)
{
  const int bh = blockIdx.y;
  const int r0 = blockIdx.x * 64;
  __shared__ float qT[64][65];
  __shared__ float lmS[128 * 64];
  __shared__ float redA[4][64];
  __shared__ float redB[64];
  const int t = threadIdx.x;
  const u16* Q = qb + ((size_t)bh * N_ + r0) * 64;
  const float* Lm = lm + (size_t)bh * L_ * 64;
  for (int u = t; u < 2048; u += 256) ((float4*)lmS)[u] = ((const float4*)Lm)[u];
  for (int u = t; u < 512; u += 256) {
    int row = u >> 3, j0 = (u & 7) * 8;
    uint4 pk = *(const uint4*)(Q + (size_t)row * 64 + j0);
    const u16* pu = (const u16*)&pk;
    #pragma unroll
    for (int jj = 0; jj < 8; ++jj) qT[j0 + jj][row] = b2f(pu[jj]);
  }
  __syncthreads();
  const int row = t & 63, ch = t >> 6;
  float qr[64];
  #pragma unroll
  for (int j = 0; j < 64; ++j) qr[j] = qT[j][row];
  float s[32];
  for (int li = 0; li < 32; ++li) {
    const float* lp = lmS + (ch * 32 + li) * 64;
    float a = 0.f;
    #pragma unroll
    for (int j = 0; j < 64; ++j) a += lp[j] * qr[j];
    s[li] = a;
  }
  float mx = -1e30f;
  for (int li = 0; li < 32; ++li) mx = fmaxf(mx, s[li]);
  redA[ch][row] = mx;
  __syncthreads();
  if (t < 64) redB[t] = fmaxf(fmaxf(redA[0][t], redA[1][t]), fmaxf(redA[2][t], redA[3][t]));
  __syncthreads();
  mx = redB[row];
  float sum = 0.f;
  for (int li = 0; li < 32; ++li) { float e = __expf(s[li] - mx); s[li] = e; sum += e; }
  __syncthreads();
  redA[ch][row] = sum;
  __syncthreads();
  if (t < 64) redB[t] = 1.0f / (redA[0][t] + redA[1][t] + redA[2][t] + redA[3][t]);
  __syncthreads();
  const float inv = redB[row];
  u16* out = k1 + ((size_t)bh * N_ + r0 + row) * 128 + ch * 32;
  for (int li = 0; li < 32; ++li) out[li] = f2b(s[li] * inv);
}

// ---------------- kernel_2 per frame + x1 = kernel_2 @ v  (LDS-only, 3-pass) ----------------
// x1 written TRANSPOSED: x1T[bh][n = f*64+dd][l], coalesced per-u across lanes.
__global__ __launch_bounds__(256) void k2x1_k(const float* __restrict__ lm,
                                              const u16* __restrict__ kb,
                                              const u16* __restrict__ vb,
                                              u16* __restrict__ x1)
{
  const int bh = blockIdx.x;
  const int f = blockIdx.y;
  __shared__ u16 kS[P_ * 64];
  __shared__ u16 vS[P_ * 64];
  __shared__ float redM[2][128];
  __shared__ float redS[2][128];
  const int t = threadIdx.x;
  const u16* Kf = kb + ((size_t)bh * N_ + f * P_) * 64;
  const u16* Vf = vb + ((size_t)bh * N_ + f * P_) * 64;
  for (int u = t; u < 1568; u += 256) {
    ((uint4*)kS)[u] = ((const uint4*)Kf)[u];
    ((uint4*)vS)[u] = ((const uint4*)Vf)[u];
  }
  __syncthreads();
  const int l = t & 127, half = t >> 7;
  const float* lp = lm + ((size_t)bh * L_ + l) * 64;
  float lr[64];
  #pragma unroll
  for (int j = 0; j < 64; ++j) lr[j] = lp[j];

  const int p0 = half * 98, p1 = p0 + 98;
  float mx = -1e30f;
  for (int p = p0; p < p1; ++p) {
    const uint4* kp = (const uint4*)(kS + p * 64);
    float s = 0.f;
    #pragma unroll
    for (int q4 = 0; q4 < 8; ++q4) {
      uint4 pk = kp[q4];
      const u32* pu = (const u32*)&pk;
      #pragma unroll
      for (int j2 = 0; j2 < 4; ++j2) {
        u32 u = pu[j2];
        s += lr[q4 * 8 + j2 * 2] * lo16f(u) + lr[q4 * 8 + j2 * 2 + 1] * hi16f(u);
      }
    }
    mx = fmaxf(mx, s);
  }
  redM[half][l] = mx;
  __syncthreads();
  mx = fmaxf(redM[0][l], redM[1][l]);

  float sm = 0.f;
  for (int p = p0; p < p1; ++p) {
    const uint4* kp = (const uint4*)(kS + p * 64);
    float s = 0.f;
    #pragma unroll
    for (int q4 = 0; q4 < 8; ++q4) {
      uint4 pk = kp[q4];
      const u32* pu = (const u32*)&pk;
      #pragma unroll
      for (int j2 = 0; j2 < 4; ++j2) {
        u32 u = pu[j2];
        s += lr[q4 * 8 + j2 * 2] * lo16f(u) + lr[q4 * 8 + j2 * 2 + 1] * hi16f(u);
      }
    }
    sm += __expf(s - mx);
  }
  redS[half][l] = sm;
  __syncthreads();
  const float inv = 1.0f / (redS[0][l] + redS[1][l]);

  const int dd0 = half * 32;
  float acc[32];
  #pragma unroll
  for (int u = 0; u < 32; ++u) acc[u] = 0.f;
  for (int p = 0; p < P_; ++p) {
    const uint4* kp = (const uint4*)(kS + p * 64);
    float s = 0.f;
    #pragma unroll
    for (int q4 = 0; q4 < 8; ++q4) {
      uint4 pk = kp[q4];
      const u32* pu = (const u32*)&pk;
      #pragma unroll
      for (int j2 = 0; j2 < 4; ++j2) {
        u32 u = pu[j2];
        s += lr[q4 * 8 + j2 * 2] * lo16f(u) + lr[q4 * 8 + j2 * 2 + 1] * hi16f(u);
      }
    }
    const float e = __expf(s - mx);
    const uint4* vp = (const uint4*)(vS + p * 64 + dd0);
    #pragma unroll
    for (int q4 = 0; q4 < 4; ++q4) {
      uint4 pv = vp[q4];
      const u32* pu = (const u32*)&pv;
      #pragma unroll
      for (int j2 = 0; j2 < 4; ++j2) {
        u32 u = pu[j2];
        acc[q4 * 8 + j2 * 2]     += e * lo16f(u);
        acc[q4 * 8 + j2 * 2 + 1] += e * hi16f(u);
      }
    }
  }
  // transposed store: x1T[bh][f*64 + dd][l]; per-u the 128 l-lanes are contiguous
  u16* outT = x1 + (size_t)bh * (1024 * 128) + (size_t)(f * 64 + dd0) * 128 + l;
  for (int u = 0; u < 32; ++u) outT[(size_t)u * 128] = f2b(acc[u] * inv);
}

// ---------------- reassociated attention: logits = g.Xo, softmax, w = attn.Xo ----------------
// one block per token m=(b,ln). Phase 1: threads 0..191 = (h,f) compute
// logits[h][f] = sum_c Xo[f][c]*g[h][m][c], 16-lane-group softmax, write attn.
// Phase 2: threads 0..191 = (cg 0..95, sh 0..1): w[h][c0..c0+7] for 6 heads.
__global__ __launch_bounds__(256) void attn2_k(const u16* __restrict__ xoc,
                                               const u16* __restrict__ g,
                                               int n0c, int cn, const int* __restrict__ flagp,
                                               void* __restrict__ outRaw, u16* __restrict__ wc)
{
  __shared__ float aS[12][16];
  const int t = threadIdx.x;
  const int m = blockIdx.x;
  const int b = (m >= cn) ? 1 : 0;
  const int ln = m - b * cn;
  const int n = n0c + ln;
  const int f32o = flagp[0];
  const u16* Xo = xoc + ((size_t)(b * cn + ln) * 16) * 768;
  const size_t hstr = (size_t)(2 * cn) * 768;

  if (t < 192) {
    const int h = t >> 4, f = t & 15;
    const uint4* xp = (const uint4*)(Xo + (size_t)f * 768);
    const uint4* gp = (const uint4*)(g + (size_t)h * hstr + (size_t)m * 768);
    float lg = 0.f;
    #pragma unroll 4
    for (int q = 0; q < 96; ++q) {
      uint4 xv = xp[q], gv = gp[q];
      const u32* xu = (const u32*)&xv;
      const u32* gu = (const u32*)&gv;
      #pragma unroll
      for (int j = 0; j < 4; ++j)
        lg += lo16f(xu[j]) * lo16f(gu[j]) + hi16f(xu[j]) * hi16f(gu[j]);
    }
    float mx = lg;
    mx = fmaxf(mx, __shfl_xor(mx, 1));
    mx = fmaxf(mx, __shfl_xor(mx, 2));
    mx = fmaxf(mx, __shfl_xor(mx, 4));
    mx = fmaxf(mx, __shfl_xor(mx, 8));
    float e = __expf(lg - mx);
    float sm = e;
    sm += __shfl_xor(sm, 1);
    sm += __shfl_xor(sm, 2);
    sm += __shfl_xor(sm, 4);
    sm += __shfl_xor(sm, 8);
    const float a = e / sm;
    const size_t abase = ((size_t)(b * H_ + h) * N_ + n) * F_ + f;
    if (f32o) ((float*)outRaw)[OUTPART_ + abase] = a;
    else      ((u16*)outRaw)[OUTPART_ + abase] = f2b(a);
    aS[h][f] = a;
  }
  __syncthreads();
  if (t < 192) {
    const int cg = t >> 1, sh = t & 1;
    const int c0 = cg * 8;
    float acc[6][8];
    #pragma unroll
    for (int j = 0; j < 6; ++j)
      #pragma unroll
      for (int k = 0; k < 8; ++k) acc[j][k] = 0.f;
    for (int f = 0; f < 16; ++f) {
      uint4 xv = *(const uint4*)(Xo + (size_t)f * 768 + c0);
      const u32* xu = (const u32*)&xv;
      float xf[8];
      #pragma unroll
      for (int j = 0; j < 4; ++j) { xf[2 * j] = lo16f(xu[j]); xf[2 * j + 1] = hi16f(xu[j]); }
      #pragma unroll
      for (int j = 0; j < 6; ++j) {
        const float a = aS[sh * 6 + j][f];
        #pragma unroll
        for (int k = 0; k < 8; ++k) acc[j][k] += a * xf[k];
      }
    }
    #pragma unroll
    for (int j = 0; j < 6; ++j) {
      u16 pk[8];
      #pragma unroll
      for (int k = 0; k < 8; ++k) pk[k] = f2b(acc[j][k]);
      *(uint4*)(wc + (size_t)(sh * 6 + j) * hstr + (size_t)m * 768 + c0) = *(uint4*)pk;
    }
  }
}

extern "C" void kernel_launch(void* const* d_in, const int* in_sizes, int n_in,
                              void* d_out, int out_size, void* d_ws, size_t ws_size,
                              hipStream_t stream)
{
  (void)in_sizes; (void)n_in; (void)out_size;
  const void* x     = d_in[0];
  const void* Wqkv  = d_in[1];
  const void* Wpq   = d_in[2];
  const void* Wpkv  = d_in[3];
  const void* Wproj = d_in[4];
  const void* bproj = d_in[5];

  char* ws = (char*)d_ws;
  size_t off = 0;
  auto alloc = [&](size_t bytes) { void* p = ws + off; off += (bytes + 255) & ~(size_t)255; return p; };
  int*  flagp = (int*)alloc(256);
  u16*  qb  = (u16*)alloc(9633792);     // (bh,N,64) bf16, scaled
  u16*  kb  = (u16*)alloc(9633792);     // scaled; hosts WpkvT/WpqT/WprojT/Wpkvb after k2x1
  u16*  vb  = (u16*)alloc(9633792);
  float* lm = (float*)alloc(786432);    // (bh,128,64) f32
  u16*  x1b = (u16*)alloc(6291456);     // (bh,1024,128) bf16 TRANSPOSED
  u16*  ob  = (u16*)alloc(9633792);     // (B,N,C) bf16
  const size_t k1off = off;             // qT f32 starts here (aliases k1b + chunk region)
  u16*  k1b = (u16*)alloc(19267584);    // (bh,N,128) bf16
  const size_t chunk0 = off;

  // qt region (19.27 MB at k1off): qselT/landmarks use it as f32 qT; after
  // landmarks it hosts WqkvT (3.54 MB) + xb (9.63 MB); k1b overwrites later.
  const size_t qtNeed = k1off + 19267584 + 256;

  // new chunk layout: xoc(24576) + xdc(1536) + q2b(1536) + g(18432) + wc(18432)
  // = 64512 u16/Nc = 129024 B/Nc
  int Nc = 0;
  {
    const int cands[5] = {3136, 1568, 784, 392, 196};
    for (int i = 0; i < 5; ++i) {
      size_t need = chunk0 + (size_t)129024 * cands[i] + 1024;
      if (need <= ws_size && qtNeed <= ws_size) { Nc = cands[i]; break; }
    }
  }
  if (Nc == 0) return;  // ws floor ~90 MB
  const int nchunks = N_ / Nc;
  u16*  xoc = (u16*)(ws + chunk0);                // (B,Nc,F,C) bf16
  u16*  xdc = xoc + (size_t)24576 * Nc;           // (B,Nc,C) bf16
  u16*  q2b = xdc + (size_t)1536 * Nc;            // [h][2Nc][64] bf16
  u16*  gbf = q2b + (size_t)1536 * Nc;            // [h][2Nc][768] bf16
  u16*  wcb = gbf + (size_t)18432 * Nc;           // [h][2Nc][768] bf16
  float* qt = (float*)(ws + k1off);               // selection-grade f32 qT

  // bf16 staging buffers (zero ws growth):
  u16* WqkvT  = (u16*)(ws + k1off);               // [2304][768] bf16, 3538944 B
  u16* xb     = (u16*)(ws + k1off + 3538944);     // [6272][768] bf16, 9633792 B
  u16* WpkvT  = kb;                               // [1536][768] bf16 (kb dead post-k2x1)
  u16* WpqT   = kb + 1179648;                     // [768][768]
  u16* WprojT = kb + 1179648 + 589824;            // [768][768]
  u16* Wpkvb  = kb + 1179648 + 589824 + 589824;   // [768][1536] bf16, original layout

  // landmark candidate slots: 24 heads x 16 u64 = 3KB in chunk region (dead until loop)
  u64* cand = (u64*)(ws + chunk0);

  detect_k<<<1, 64, 0, stream>>>((const u32*)Wqkv, flagp);
  zcnt_k<<<1, 512, 0, stream>>>(cand);

  // selection-grade f32 qT (transposed), then register-resident landmarks
  qselT_k<<<dim3(49, 12), 256, 0, stream>>>(x, Wqkv, flagp, qt);
  landmarksR_k<<<dim3(24, KB_), 512, 0, stream>>>(qt, lm, cand);

  // qt now dead: build bf16 operands in its place
  twT_k<<<dim3(12, 36), 256, 0, stream>>>(Wqkv, 768, 2304, flagp, WqkvT);
  xcvt_k<<<2352, 256, 0, stream>>>(x, flagp, xb);

  // qkv projection -> qb,kb,vb (global_load_lds staging)
  gemm_k<0><<<dim3(49, 18, 1), 256, 0, stream>>>(xb, WqkvT, 6272, 768, 768, 768, 0, 0, flagp,
                                                 nullptr, qb, kb, vb, nullptr, nullptr);
  // kernel_2 + x1 (LDS-only, transposed x1 out)
  k2x1_k<<<dim3(24, 16), 256, 0, stream>>>(lm, kb, vb, x1b);
  // kernel_1 (overwrites qt region — WqkvT/xb dead)
  k1_k<<<dim3(49, 24), 256, 0, stream>>>(qb, lm, k1b);

  // kb dead: transposed weights + plain bf16 Wpkv (one merged dispatch)
  twT3_k<<<dim3(12, 24, 4), 256, 0, stream>>>(Wpkv, Wpq, Wproj, flagp,
                                              WpkvT, WpqT, WprojT, Wpkvb);

  const int gx = (2 * Nc + 127) / 128;
  for (int c = 0; c < nchunks; ++c) {
    const int n0c = c * Nc;
    // xo = k1 @ x1 (+ xdiag side-write)
    gemm_k<1><<<dim3((Nc + 127) / 128, 8, 24), 256, 0, stream>>>(
        k1b, x1b, Nc, 128, 128, 128, n0c, Nc, flagp, nullptr, xoc, xdc, nullptr, nullptr, nullptr);
    // q2b = bf16(xdiag @ Wpq * 0.125), [h][2Nc][64]
    gemm_k<3><<<dim3(gx, 6, 1), 256, 0, stream>>>(
        xdc, WpqT, 2 * Nc, 768, 768, 768, n0c, Nc, flagp, nullptr, q2b, nullptr, nullptr, nullptr, nullptr);
    // g = bf16(q2b @ Wpkv_k^T), K=64, per-head
    gemm_k<5><<<dim3(gx, 6, 12), 256, 0, stream>>>(
        q2b, Wpkvb, 2 * Nc, 64, 64, 1536, n0c, Nc, flagp, nullptr, gbf, nullptr, nullptr, nullptr, nullptr);
    // logits = g.Xo -> softmax -> attn out + w = attn.Xo
    attn2_k<<<dim3(2 * Nc), 256, 0, stream>>>(xoc, gbf, n0c, Nc, flagp, d_out, wcb);
    // ob_h = wc_h @ Wpkv_v_h (N=64 masked)
    gemm_k<6><<<dim3(gx, 1, 12), 256, 0, stream>>>(
        wcb, WpkvT, 2 * Nc, 768, 768, 768, n0c, Nc, flagp, nullptr, ob, nullptr, nullptr, nullptr, nullptr);
  }
  // out = o @ W_proj + b_proj
  gemm_k<4><<<dim3(49, 6, 1), 256, 0, stream>>>(ob, WprojT, 6272, 768, 768, 768, 0, 0, flagp,
                                                nullptr, nullptr, nullptr, nullptr, bproj, d_out);
}